// Round 3
// baseline (119.019 us; speedup 1.0000x reference)
//
#include <hip/hip_runtime.h>
#include <math.h>

typedef __attribute__((ext_vector_type(8))) short bf16x8;
typedef __attribute__((ext_vector_type(4))) float f32x4;

namespace {
constexpr int Bb  = 4;
constexpr int Tt  = 2048;
constexpr int DM  = 768;
constexpr int Hh  = 4;
constexpr int Dd  = 64;
constexpr int DIM = 256;          // H*D
constexpr int BT  = Bb * Tt;      // 8192
constexpr int CH  = 64;           // chunk length
constexpr int NC  = Tt / CH;      // 32 chunks
constexpr int NQKVG = 1536;       // QKV (768) + gate (768) output cols
}

__device__ __forceinline__ float elu1(float x) { return x > 0.f ? x + 1.f : expf(x); }

// fp32 -> bf16, round-to-nearest-even
__device__ __forceinline__ unsigned short f2bf(float f) {
  unsigned int x = __float_as_uint(f);
  unsigned int r = (x + 0x7fffu + ((x >> 16) & 1u)) >> 16;
  return (unsigned short)r;
}
__device__ __forceinline__ float bf2f(unsigned short u) {
  return __uint_as_float((unsigned int)u << 16);
}

__device__ __forceinline__ void gload16(const void* g, void* l) {
  __builtin_amdgcn_global_load_lds(
      (const __attribute__((address_space(1))) void*)g,
      (__attribute__((address_space(3))) void*)l, 16, 0, 0);
}

// stage a 128x64 bf16 tile (row-major, ld elems per src row) into linear lds.
__device__ __forceinline__ void stage_tile(const short* __restrict__ gbase,
                                           size_t ld, int k0,
                                           short* lds, int w, int l) {
#pragma unroll
  for (int i = 0; i < 4; ++i) {
    int seg = w * 4 + i;
    int row = seg * 8 + (l >> 3);
    int kk  = (l & 7) * 8;
    gload16(gbase + (size_t)row * ld + k0 + kk, (char*)lds + seg * 1024);
  }
}

// bijective XCD swizzle (nwg % 8 == 0)
__device__ __forceinline__ int xcd_swz(int orig, int nwg) {
  int q = nwg >> 3;
  return (orig & 7) * q + (orig >> 3);
}

// ---------------------------------------------------------------------------
// cast fp32 -> bf16, 8 elements/thread
// ---------------------------------------------------------------------------
__global__ __launch_bounds__(256) void k_cast(const float* __restrict__ in,
                                              unsigned short* __restrict__ out,
                                              int n8) {
  int i = blockIdx.x * 256 + threadIdx.x;
  if (i >= n8) return;
  const float4* p = (const float4*)(in + (size_t)i * 8);
  float4 a = p[0], b = p[1];
  union { unsigned short u[8]; uint4 v; } r;
  r.u[0] = f2bf(a.x); r.u[1] = f2bf(a.y); r.u[2] = f2bf(a.z); r.u[3] = f2bf(a.w);
  r.u[4] = f2bf(b.x); r.u[5] = f2bf(b.y); r.u[6] = f2bf(b.z); r.u[7] = f2bf(b.w);
  *(uint4*)(out + (size_t)i * 8) = r.v;
}

// ---------------------------------------------------------------------------
// all weight transposes in ONE launch.
// WT rows: [0,256)=Wq^T [256,512)=Wk^T [512,768)=Wv^T [768,1536)=Wg^T, ld=768
// WoT: Wo^T [768][256], ld=256
// ---------------------------------------------------------------------------
__global__ __launch_bounds__(256) void k_convAll(
    const float* __restrict__ Wq, const float* __restrict__ Wk,
    const float* __restrict__ Wv, const float* __restrict__ Wg,
    const float* __restrict__ Wo, unsigned short* __restrict__ WT,
    unsigned short* __restrict__ WoT) {
  __shared__ float t[32][33];
  int idx = blockIdx.x;
  const float* src;
  unsigned short* out;
  int K, N, n_off, ldo;
  if (idx < 576) {               // Wq/Wk/Wv: [768][256], 192 tiles each
    int z = idx / 192;
    idx %= 192;
    src = (z == 0) ? Wq : (z == 1) ? Wk : Wv;
    out = WT; K = 768; N = 256; n_off = z * 256; ldo = 768;
  } else if (idx < 1152) {       // Wg: [768][768], 576 tiles
    idx -= 576;
    src = Wg; out = WT; K = 768; N = 768; n_off = 768; ldo = 768;
  } else {                       // Wo: [256][768], 192 tiles
    idx -= 1152;
    src = Wo; out = WoT; K = 256; N = 768; n_off = 0; ldo = 256;
  }
  int kt = idx % (K / 32), nt = idx / (K / 32);
  int k0 = kt * 32, n0 = nt * 32;
  const int tx = threadIdx.x, ty = threadIdx.y;
  for (int i = ty; i < 32; i += 8)
    t[i][tx] = src[(size_t)(k0 + i) * N + n0 + tx];
  __syncthreads();
  for (int i = ty; i < 32; i += 8)
    out[(size_t)(n_off + n0 + i) * ldo + k0 + tx] = f2bf(t[tx][i]);
}

// ---------------------------------------------------------------------------
// GEMM1: [QKVG] = x @ [Wq|Wk|Wv|Wg]^T.  M=8192, K=768, N=1536 (B^T input).
// 128x128 tile, 4 waves (2x2), 4x4 fragments of 16x16x32 per wave.
// Epilogue: cols<512 -> elu+1 -> Q/K bf16; <768 -> V bf16; else sigmoid -> G.
// ---------------------------------------------------------------------------
__global__ __launch_bounds__(256) void k_gemm1(
    const unsigned short* __restrict__ xb, const unsigned short* __restrict__ WT,
    unsigned short* __restrict__ Q, unsigned short* __restrict__ K,
    unsigned short* __restrict__ V, unsigned short* __restrict__ G) {
  __shared__ short As[128 * 64];
  __shared__ short Bs[128 * 64];
  const int tid = threadIdx.x;
  const int w = tid >> 6, l = tid & 63;
  const int lr = l & 15, lg = l >> 4;
  const int wr = w >> 1, wc = w & 1;
  const int wg = xcd_swz(blockIdx.x, gridDim.x);
  const int m0 = (wg % (BT / 128)) * 128;
  const int n0 = (wg / (BT / 128)) * 128;

  f32x4 acc[4][4];
#pragma unroll
  for (int i = 0; i < 4; ++i)
#pragma unroll
    for (int j = 0; j < 4; ++j) acc[i][j] = (f32x4){0.f, 0.f, 0.f, 0.f};

  for (int k0 = 0; k0 < DM; k0 += 64) {
    stage_tile((const short*)xb + (size_t)m0 * DM, DM, k0, As, w, l);
    stage_tile((const short*)WT + (size_t)n0 * DM, DM, k0, Bs, w, l);
    __syncthreads();
#pragma unroll
    for (int ks = 0; ks < 2; ++ks) {
      bf16x8 af[4], bf[4];
#pragma unroll
      for (int mi = 0; mi < 4; ++mi)
        af[mi] = *(const bf16x8*)&As[(wr * 64 + mi * 16 + lr) * 64 + ks * 32 + lg * 8];
#pragma unroll
      for (int ni = 0; ni < 4; ++ni)
        bf[ni] = *(const bf16x8*)&Bs[(wc * 64 + ni * 16 + lr) * 64 + ks * 32 + lg * 8];
#pragma unroll
      for (int mi = 0; mi < 4; ++mi)
#pragma unroll
        for (int ni = 0; ni < 4; ++ni)
          acc[mi][ni] = __builtin_amdgcn_mfma_f32_16x16x32_bf16(
              af[mi], bf[ni], acc[mi][ni], 0, 0, 0);
    }
    __syncthreads();
  }

#pragma unroll
  for (int mi = 0; mi < 4; ++mi)
#pragma unroll
    for (int ni = 0; ni < 4; ++ni) {
      int col0 = n0 + wc * 64 + ni * 16;  // uniform across lanes, 16-aligned
#pragma unroll
      for (int r = 0; r < 4; ++r) {
        int row = m0 + wr * 64 + mi * 16 + lg * 4 + r;
        float v = acc[mi][ni][r];
        if (col0 < 512) {
          unsigned short* dst = (col0 < 256) ? Q : K;
          dst[(size_t)row * DIM + (col0 & 255) + lr] = f2bf(elu1(v));
        } else if (col0 < 768) {
          V[(size_t)row * DIM + (col0 & 255) + lr] = f2bf(v);
        } else {
          float g = 1.f / (1.f + expf(-v));
          G[(size_t)row * DM + (col0 - 768) + lr] = f2bf(g);
        }
      }
    }
}

// ---------------------------------------------------------------------------
// K2: per-chunk local sums (fp32 vector, bf16 inputs).
// ---------------------------------------------------------------------------
__global__ __launch_bounds__(256) void k_chunksum(
    const unsigned short* __restrict__ K, const unsigned short* __restrict__ V,
    float* __restrict__ Sc, float* __restrict__ zc) {
  __shared__ float Ks[CH][68];
  __shared__ float Vs[CH][68];
  const int c = blockIdx.x, h = blockIdx.y, b = blockIdx.z;
  const int tx = threadIdx.x, ty = threadIdx.y;
  const int tid = ty * 16 + tx;
  const int t0 = c * CH;
#pragma unroll
  for (int l = 0; l < 4; ++l) {
    int idx = tid + l * 256;
    int d4 = idx & 15, t = idx >> 4;
    size_t o = (size_t)(b * Tt + t0 + t) * DIM + h * Dd + d4 * 4;
    short4 k4 = *(const short4*)(K + o);
    short4 v4 = *(const short4*)(V + o);
    Ks[t][d4 * 4 + 0] = bf2f(k4.x); Ks[t][d4 * 4 + 1] = bf2f(k4.y);
    Ks[t][d4 * 4 + 2] = bf2f(k4.z); Ks[t][d4 * 4 + 3] = bf2f(k4.w);
    Vs[t][d4 * 4 + 0] = bf2f(v4.x); Vs[t][d4 * 4 + 1] = bf2f(v4.y);
    Vs[t][d4 * 4 + 2] = bf2f(v4.z); Vs[t][d4 * 4 + 3] = bf2f(v4.w);
  }
  __syncthreads();
  float acc[4][4] = {};
  for (int t = 0; t < CH; ++t) {
    float4 k4 = *(const float4*)&Ks[t][ty * 4];
    float4 v4 = *(const float4*)&Vs[t][tx * 4];
    float kv[4] = {k4.x, k4.y, k4.z, k4.w};
    float vv[4] = {v4.x, v4.y, v4.z, v4.w};
#pragma unroll
    for (int i = 0; i < 4; ++i)
#pragma unroll
      for (int j = 0; j < 4; ++j) acc[i][j] += kv[i] * vv[j];
  }
  const size_t base = ((size_t)(b * Hh + h) * NC + c) * (Dd * Dd);
#pragma unroll
  for (int i = 0; i < 4; ++i) {
    float4 s4 = make_float4(acc[i][0], acc[i][1], acc[i][2], acc[i][3]);
    *(float4*)&Sc[base + (size_t)(ty * 4 + i) * Dd + tx * 4] = s4;
  }
  if (tid < Dd) {
    float s = 0.f;
    for (int t = 0; t < CH; ++t) s += Ks[t][tid];
    zc[((size_t)(b * Hh + h) * NC + c) * Dd + tid] = s;
  }
}

// ---------------------------------------------------------------------------
// K3: exclusive prefix scan over chunks. grid (16 bh, 16 slices) x 256.
// ---------------------------------------------------------------------------
__global__ __launch_bounds__(256) void k_scan(float* __restrict__ Sc,
                                              float* __restrict__ zc) {
  const int bh = blockIdx.x;
  const int o = blockIdx.y * 256 + threadIdx.x;
  const size_t base = (size_t)bh * NC * (Dd * Dd) + o;
  float v[NC];
#pragma unroll
  for (int c = 0; c < NC; ++c) v[c] = Sc[base + (size_t)c * (Dd * Dd)];
  float run = 0.f;
#pragma unroll
  for (int c = 0; c < NC; ++c) {
    Sc[base + (size_t)c * (Dd * Dd)] = run;
    run += v[c];
  }
  if (blockIdx.y == 0 && threadIdx.x < Dd) {
    float rz = 0.f;
    for (int c = 0; c < NC; ++c) {
      size_t oz = ((size_t)bh * NC + c) * Dd + threadIdx.x;
      float cur = zc[oz];
      zc[oz] = rz;
      rz += cur;
    }
  }
}

// ---------------------------------------------------------------------------
// K4: per-chunk output (fp32 vector, bf16 in/out).
// ---------------------------------------------------------------------------
__global__ __launch_bounds__(256) void k_out(
    const unsigned short* __restrict__ Q, const unsigned short* __restrict__ K,
    const unsigned short* __restrict__ V, const float* __restrict__ Sc,
    const float* __restrict__ zc, unsigned short* __restrict__ O) {
  __shared__ float Qs[CH][68];
  __shared__ float KVs[CH * 68];
  __shared__ float As[CH][68];
  __shared__ float Ss[Dd][68];
  __shared__ float zs[Dd];
  __shared__ float dens[CH];
  const int c = blockIdx.x, h = blockIdx.y, b = blockIdx.z;
  const int tx = threadIdx.x, ty = threadIdx.y;
  const int tid = ty * 16 + tx;
  const int t0 = c * CH;

  // load Q [t][d]; K transposed [d][t] (pad 65)
#pragma unroll
  for (int l = 0; l < 4; ++l) {
    int idx = tid + l * 256;
    int d4 = idx & 15, t = idx >> 4;
    size_t o = (size_t)(b * Tt + t0 + t) * DIM + h * Dd + d4 * 4;
    short4 q4 = *(const short4*)(Q + o);
    short4 k4 = *(const short4*)(K + o);
    Qs[t][d4 * 4 + 0] = bf2f(q4.x); Qs[t][d4 * 4 + 1] = bf2f(q4.y);
    Qs[t][d4 * 4 + 2] = bf2f(q4.z); Qs[t][d4 * 4 + 3] = bf2f(q4.w);
    KVs[(d4 * 4 + 0) * 65 + t] = bf2f(k4.x);
    KVs[(d4 * 4 + 1) * 65 + t] = bf2f(k4.y);
    KVs[(d4 * 4 + 2) * 65 + t] = bf2f(k4.z);
    KVs[(d4 * 4 + 3) * 65 + t] = bf2f(k4.w);
  }
  __syncthreads();

  // A[i][j] = sum_d Q[i][d]*K[j][d], masked j<=i
  float acc[4][4] = {};
  for (int d0 = 0; d0 < Dd; d0 += 4) {
    float4 q4[4];
#pragma unroll
    for (int i = 0; i < 4; ++i) q4[i] = *(const float4*)&Qs[ty * 4 + i][d0];
#pragma unroll
    for (int dd = 0; dd < 4; ++dd) {
      int d = d0 + dd;
      float kv[4];
#pragma unroll
      for (int j = 0; j < 4; ++j) kv[j] = KVs[d * 65 + tx * 4 + j];
#pragma unroll
      for (int i = 0; i < 4; ++i) {
        float qv = ((const float*)&q4[i])[dd];
#pragma unroll
        for (int j = 0; j < 4; ++j) acc[i][j] += qv * kv[j];
      }
    }
  }
#pragma unroll
  for (int i = 0; i < 4; ++i)
#pragma unroll
    for (int j = 0; j < 4; ++j) {
      int ti = ty * 4 + i, sj = tx * 4 + j;
      As[ti][sj] = (sj <= ti) ? acc[i][j] : 0.f;
    }
  __syncthreads();

  // V into KVs row-major (pad 68); S_prev, z_prev
#pragma unroll
  for (int l = 0; l < 4; ++l) {
    int idx = tid + l * 256;
    int d4 = idx & 15, t = idx >> 4;
    size_t o = (size_t)(b * Tt + t0 + t) * DIM + h * Dd + d4 * 4;
    short4 v4 = *(const short4*)(V + o);
    KVs[t * 68 + d4 * 4 + 0] = bf2f(v4.x);
    KVs[t * 68 + d4 * 4 + 1] = bf2f(v4.y);
    KVs[t * 68 + d4 * 4 + 2] = bf2f(v4.z);
    KVs[t * 68 + d4 * 4 + 3] = bf2f(v4.w);
  }
  const size_t sbase = ((size_t)(b * Hh + h) * NC + c) * (Dd * Dd);
#pragma unroll
  for (int l = 0; l < 4; ++l) {
    int idx = tid + l * 256;
    int e4 = idx & 15, dd = idx >> 4;
    float4 s4 = *(const float4*)&Sc[sbase + (size_t)dd * Dd + e4 * 4];
    Ss[dd][e4 * 4 + 0] = s4.x; Ss[dd][e4 * 4 + 1] = s4.y;
    Ss[dd][e4 * 4 + 2] = s4.z; Ss[dd][e4 * 4 + 3] = s4.w;
  }
  if (tid < Dd) zs[tid] = zc[((size_t)(b * Hh + h) * NC + c) * Dd + tid];
  __syncthreads();

  if (tid < CH) {
    int i = tid;
    float rs = 0.f;
    for (int j = 0; j < CH; ++j) rs += As[i][j];
    float qz = 0.f;
    for (int d = 0; d < Dd; ++d) qz += Qs[i][d] * zs[d];
    dens[i] = fmaxf(rs + qz, 1e-6f);
  }
  float oacc[4][4] = {};
  for (int j = 0; j < CH; ++j) {
    float4 v4 = *(const float4*)&KVs[j * 68 + tx * 4];
    float vv[4] = {v4.x, v4.y, v4.z, v4.w};
    float av[4];
#pragma unroll
    for (int i = 0; i < 4; ++i) av[i] = As[ty * 4 + i][j];
#pragma unroll
    for (int i = 0; i < 4; ++i)
#pragma unroll
      for (int jj = 0; jj < 4; ++jj) oacc[i][jj] += av[i] * vv[jj];
  }
  for (int d = 0; d < Dd; ++d) {
    float4 s4 = *(const float4*)&Ss[d][tx * 4];
    float sv[4] = {s4.x, s4.y, s4.z, s4.w};
    float qv[4];
#pragma unroll
    for (int i = 0; i < 4; ++i) qv[i] = Qs[ty * 4 + i][d];
#pragma unroll
    for (int i = 0; i < 4; ++i)
#pragma unroll
      for (int jj = 0; jj < 4; ++jj) oacc[i][jj] += qv[i] * sv[jj];
  }
  __syncthreads();
#pragma unroll
  for (int i = 0; i < 4; ++i) {
    float inv = 1.f / dens[ty * 4 + i];
#pragma unroll
    for (int jj = 0; jj < 4; ++jj) {
      O[(size_t)(b * Tt + t0 + ty * 4 + i) * DIM + h * Dd + tx * 4 + jj] =
          f2bf(oacc[i][jj] * inv);
    }
  }
}

// ---------------------------------------------------------------------------
// GEMM2: out = (O @ Wo) * G.  M=8192, K=256, N=768.
// ---------------------------------------------------------------------------
__global__ __launch_bounds__(256) void k_gemm2(
    const unsigned short* __restrict__ Ob, const unsigned short* __restrict__ WoT,
    const unsigned short* __restrict__ G, float* __restrict__ out) {
  __shared__ short As[128 * 64];
  __shared__ short Bs[128 * 64];
  const int tid = threadIdx.x;
  const int w = tid >> 6, l = tid & 63;
  const int lr = l & 15, lg = l >> 4;
  const int wr = w >> 1, wc = w & 1;
  const int wg = xcd_swz(blockIdx.x, gridDim.x);
  const int m0 = (wg % (BT / 128)) * 128;
  const int n0 = (wg / (BT / 128)) * 128;

  f32x4 acc[4][4];
#pragma unroll
  for (int i = 0; i < 4; ++i)
#pragma unroll
    for (int j = 0; j < 4; ++j) acc[i][j] = (f32x4){0.f, 0.f, 0.f, 0.f};

  for (int k0 = 0; k0 < DIM; k0 += 64) {
    stage_tile((const short*)Ob + (size_t)m0 * DIM, DIM, k0, As, w, l);
    stage_tile((const short*)WoT + (size_t)n0 * DIM, DIM, k0, Bs, w, l);
    __syncthreads();
#pragma unroll
    for (int ks = 0; ks < 2; ++ks) {
      bf16x8 af[4], bf[4];
#pragma unroll
      for (int mi = 0; mi < 4; ++mi)
        af[mi] = *(const bf16x8*)&As[(wr * 64 + mi * 16 + lr) * 64 + ks * 32 + lg * 8];
#pragma unroll
      for (int ni = 0; ni < 4; ++ni)
        bf[ni] = *(const bf16x8*)&Bs[(wc * 64 + ni * 16 + lr) * 64 + ks * 32 + lg * 8];
#pragma unroll
      for (int mi = 0; mi < 4; ++mi)
#pragma unroll
        for (int ni = 0; ni < 4; ++ni)
          acc[mi][ni] = __builtin_amdgcn_mfma_f32_16x16x32_bf16(
              af[mi], bf[ni], acc[mi][ni], 0, 0, 0);
    }
    __syncthreads();
  }

#pragma unroll
  for (int mi = 0; mi < 4; ++mi)
#pragma unroll
    for (int ni = 0; ni < 4; ++ni) {
      int col = n0 + wc * 64 + ni * 16 + lr;
#pragma unroll
      for (int r = 0; r < 4; ++r) {
        int row = m0 + wr * 64 + mi * 16 + lg * 4 + r;
        float g = bf2f(G[(size_t)row * DM + col]);
        out[(size_t)row * DM + col] = acc[mi][ni][r] * g;
      }
    }
}

// ---------------------------------------------------------------------------
extern "C" void kernel_launch(void* const* d_in, const int* in_sizes, int n_in,
                              void* d_out, int out_size, void* d_ws,
                              size_t ws_size, hipStream_t stream) {
  const float* x  = (const float*)d_in[0];
  const float* Wq = (const float*)d_in[1];
  const float* Wk = (const float*)d_in[2];
  const float* Wv = (const float*)d_in[3];
  const float* Wo = (const float*)d_in[4];
  const float* Wg = (const float*)d_in[5];
  float* out = (float*)d_out;

  char* p = (char*)d_ws;
  size_t off = 0;
  auto alloc = [&](size_t bytes) {
    void* r = p + off;
    off = (off + bytes + 255) & ~(size_t)255;
    return r;
  };
  unsigned short* xb  = (unsigned short*)alloc((size_t)BT * DM * 2);
  unsigned short* WT  = (unsigned short*)alloc((size_t)NQKVG * DM * 2);
  unsigned short* WoT = (unsigned short*)alloc((size_t)DM * DIM * 2);
  unsigned short* Q   = (unsigned short*)alloc((size_t)BT * DIM * 2);
  unsigned short* Kf  = (unsigned short*)alloc((size_t)BT * DIM * 2);
  unsigned short* Vf  = (unsigned short*)alloc((size_t)BT * DIM * 2);
  unsigned short* G   = (unsigned short*)alloc((size_t)BT * DM * 2);
  unsigned short* Ob  = (unsigned short*)alloc((size_t)BT * DIM * 2);
  float* Sc = (float*)alloc((size_t)Bb * Hh * NC * Dd * Dd * 4);
  float* zc = (float*)alloc((size_t)Bb * Hh * NC * Dd * 4);

  // 1. input cast + all weight transposes (one launch each)
  k_cast<<<dim3((BT * DM / 8 + 255) / 256), dim3(256), 0, stream>>>(x, xb, BT * DM / 8);
  k_convAll<<<dim3(1344), dim3(32, 8), 0, stream>>>(Wq, Wk, Wv, Wg, Wo, WT, WoT);

  // 2. fused QKV + gate projection (MFMA), N=1536
  k_gemm1<<<dim3((BT / 128) * (NQKVG / 128)), dim3(256), 0, stream>>>(
      xb, WT, Q, Kf, Vf, G);

  // 3. chunked linear attention
  dim3 blk(16, 16);
  k_chunksum<<<dim3(NC, Hh, Bb), blk, 0, stream>>>(Kf, Vf, Sc, zc);
  k_scan<<<dim3(Bb * Hh, Dd * Dd / 256), dim3(256), 0, stream>>>(Sc, zc);
  k_out<<<dim3(NC, Hh, Bb), blk, 0, stream>>>(Q, Kf, Vf, Sc, zc, Ob);

  // 4. output GEMM * gate (MFMA)
  k_gemm2<<<dim3((BT / 128) * (DM / 128)), dim3(256), 0, stream>>>(Ob, WoT, G, out);
}

// Round 4
// 115.531 us; speedup vs baseline: 1.0302x; 1.0302x over previous
//
#include <hip/hip_runtime.h>
#include <math.h>

typedef __attribute__((ext_vector_type(8))) short bf16x8;
typedef __attribute__((ext_vector_type(4))) float f32x4;

namespace {
constexpr int Bb  = 4;
constexpr int Tt  = 2048;
constexpr int DM  = 768;
constexpr int Hh  = 4;
constexpr int Dd  = 64;
constexpr int DIM = 256;          // H*D
constexpr int BT  = Bb * Tt;      // 8192
constexpr int CH  = 64;           // chunk length
constexpr int NC  = Tt / CH;      // 32 chunks
constexpr int NQKVG = 1536;       // QKV (768) + gate (768) output cols
constexpr int MT  = BT / 128;     // 64 m-tiles
}

__device__ __forceinline__ float elu1(float x) { return x > 0.f ? x + 1.f : expf(x); }

// fp32 -> bf16, round-to-nearest-even
__device__ __forceinline__ unsigned short f2bf(float f) {
  unsigned int x = __float_as_uint(f);
  unsigned int r = (x + 0x7fffu + ((x >> 16) & 1u)) >> 16;
  return (unsigned short)r;
}
__device__ __forceinline__ float bf2f(unsigned short u) {
  return __uint_as_float((unsigned int)u << 16);
}

__device__ __forceinline__ void gload16(const void* g, void* l) {
  __builtin_amdgcn_global_load_lds(
      (const __attribute__((address_space(1))) void*)g,
      (__attribute__((address_space(3))) void*)l, 16, 0, 0);
}

// stage a 128x64 bf16 tile (row-major, ld elems per src row) into linear lds.
__device__ __forceinline__ void stage_tile(const short* __restrict__ gbase,
                                           size_t ld, int k0,
                                           short* lds, int w, int l) {
#pragma unroll
  for (int i = 0; i < 4; ++i) {
    int seg = w * 4 + i;
    int row = seg * 8 + (l >> 3);
    int kk  = (l & 7) * 8;
    gload16(gbase + (size_t)row * ld + k0 + kk, (char*)lds + seg * 1024);
  }
}

// L2-resident tiling: each XCD (bid&7, round-robin dispatch) owns 8
// contiguous m-tiles and iterates all n-tiles over them. Per-XCD working
// set = 8x196KB A-panel + B stream -> fits 4MB XCD L2.
__device__ __forceinline__ void xcd_tile(int bid, int nt_count, int& mt, int& nt) {
  int xcd = bid & 7;
  int idx = bid >> 3;
  mt = xcd * 8 + (idx & 7);
  nt = idx >> 3;
  (void)nt_count;
}

// ---------------------------------------------------------------------------
// cast fp32 -> bf16, 8 elements/thread
// ---------------------------------------------------------------------------
__global__ __launch_bounds__(256) void k_cast(const float* __restrict__ in,
                                              unsigned short* __restrict__ out,
                                              int n8) {
  int i = blockIdx.x * 256 + threadIdx.x;
  if (i >= n8) return;
  const float4* p = (const float4*)(in + (size_t)i * 8);
  float4 a = p[0], b = p[1];
  union { unsigned short u[8]; uint4 v; } r;
  r.u[0] = f2bf(a.x); r.u[1] = f2bf(a.y); r.u[2] = f2bf(a.z); r.u[3] = f2bf(a.w);
  r.u[4] = f2bf(b.x); r.u[5] = f2bf(b.y); r.u[6] = f2bf(b.z); r.u[7] = f2bf(b.w);
  *(uint4*)(out + (size_t)i * 8) = r.v;
}

// ---------------------------------------------------------------------------
// all weight transposes in ONE launch.
// WT rows: [0,256)=Wq^T [256,512)=Wk^T [512,768)=Wv^T [768,1536)=Wg^T, ld=768
// WoT: Wo^T [768][256], ld=256
// ---------------------------------------------------------------------------
__global__ __launch_bounds__(256) void k_convAll(
    const float* __restrict__ Wq, const float* __restrict__ Wk,
    const float* __restrict__ Wv, const float* __restrict__ Wg,
    const float* __restrict__ Wo, unsigned short* __restrict__ WT,
    unsigned short* __restrict__ WoT) {
  __shared__ float t[32][33];
  int idx = blockIdx.x;
  const float* src;
  unsigned short* out;
  int K, N, n_off, ldo;
  if (idx < 576) {               // Wq/Wk/Wv: [768][256], 192 tiles each
    int z = idx / 192;
    idx %= 192;
    src = (z == 0) ? Wq : (z == 1) ? Wk : Wv;
    out = WT; K = 768; N = 256; n_off = z * 256; ldo = 768;
  } else if (idx < 1152) {       // Wg: [768][768], 576 tiles
    idx -= 576;
    src = Wg; out = WT; K = 768; N = 768; n_off = 768; ldo = 768;
  } else {                       // Wo: [256][768], 192 tiles
    idx -= 1152;
    src = Wo; out = WoT; K = 256; N = 768; n_off = 0; ldo = 256;
  }
  int kt = idx % (K / 32), nt = idx / (K / 32);
  int k0 = kt * 32, n0 = nt * 32;
  const int tx = threadIdx.x, ty = threadIdx.y;
  for (int i = ty; i < 32; i += 8)
    t[i][tx] = src[(size_t)(k0 + i) * N + n0 + tx];
  __syncthreads();
  for (int i = ty; i < 32; i += 8)
    out[(size_t)(n_off + n0 + i) * ldo + k0 + tx] = f2bf(t[tx][i]);
}

// ---------------------------------------------------------------------------
// GEMM1: [QKVG] = x @ [Wq|Wk|Wv|Wg]^T.  M=8192, K=768, N=1536 (B^T input).
// 128x128 tile, 4 waves (2x2), 4x4 fragments of 16x16x32 per wave.
// Epilogue: cols<512 -> elu+1 -> Q/K bf16; <768 -> V bf16; else sigmoid -> G.
// ---------------------------------------------------------------------------
__global__ __launch_bounds__(256) void k_gemm1(
    const unsigned short* __restrict__ xb, const unsigned short* __restrict__ WT,
    unsigned short* __restrict__ Q, unsigned short* __restrict__ K,
    unsigned short* __restrict__ V, unsigned short* __restrict__ G) {
  __shared__ short As[128 * 64];
  __shared__ short Bs[128 * 64];
  const int tid = threadIdx.x;
  const int w = tid >> 6, l = tid & 63;
  const int lr = l & 15, lg = l >> 4;
  const int wr = w >> 1, wc = w & 1;
  int mt, nt;
  xcd_tile(blockIdx.x, NQKVG / 128, mt, nt);
  const int m0 = mt * 128, n0 = nt * 128;

  f32x4 acc[4][4];
#pragma unroll
  for (int i = 0; i < 4; ++i)
#pragma unroll
    for (int j = 0; j < 4; ++j) acc[i][j] = (f32x4){0.f, 0.f, 0.f, 0.f};

  for (int k0 = 0; k0 < DM; k0 += 64) {
    stage_tile((const short*)xb + (size_t)m0 * DM, DM, k0, As, w, l);
    stage_tile((const short*)WT + (size_t)n0 * DM, DM, k0, Bs, w, l);
    __syncthreads();
#pragma unroll
    for (int ks = 0; ks < 2; ++ks) {
      bf16x8 af[4], bf[4];
#pragma unroll
      for (int mi = 0; mi < 4; ++mi)
        af[mi] = *(const bf16x8*)&As[(wr * 64 + mi * 16 + lr) * 64 + ks * 32 + lg * 8];
#pragma unroll
      for (int ni = 0; ni < 4; ++ni)
        bf[ni] = *(const bf16x8*)&Bs[(wc * 64 + ni * 16 + lr) * 64 + ks * 32 + lg * 8];
#pragma unroll
      for (int mi = 0; mi < 4; ++mi)
#pragma unroll
        for (int ni = 0; ni < 4; ++ni)
          acc[mi][ni] = __builtin_amdgcn_mfma_f32_16x16x32_bf16(
              af[mi], bf[ni], acc[mi][ni], 0, 0, 0);
    }
    __syncthreads();
  }

#pragma unroll
  for (int mi = 0; mi < 4; ++mi)
#pragma unroll
    for (int ni = 0; ni < 4; ++ni) {
      int col0 = n0 + wc * 64 + ni * 16;  // uniform across lanes, 16-aligned
#pragma unroll
      for (int r = 0; r < 4; ++r) {
        int row = m0 + wr * 64 + mi * 16 + lg * 4 + r;
        float v = acc[mi][ni][r];
        if (col0 < 512) {
          unsigned short* dst = (col0 < 256) ? Q : K;
          dst[(size_t)row * DIM + (col0 & 255) + lr] = f2bf(elu1(v));
        } else if (col0 < 768) {
          V[(size_t)row * DIM + (col0 & 255) + lr] = f2bf(v);
        } else {
          float g = 1.f / (1.f + expf(-v));
          G[(size_t)row * DM + (col0 - 768) + lr] = f2bf(g);
        }
      }
    }
}

// ---------------------------------------------------------------------------
// K2: per-chunk local sums (fp32 vector, bf16 inputs).
// ---------------------------------------------------------------------------
__global__ __launch_bounds__(256) void k_chunksum(
    const unsigned short* __restrict__ K, const unsigned short* __restrict__ V,
    float* __restrict__ Sc, float* __restrict__ zc) {
  __shared__ float Ks[CH][68];
  __shared__ float Vs[CH][68];
  const int c = blockIdx.x, h = blockIdx.y, b = blockIdx.z;
  const int tx = threadIdx.x, ty = threadIdx.y;
  const int tid = ty * 16 + tx;
  const int t0 = c * CH;
#pragma unroll
  for (int l = 0; l < 4; ++l) {
    int idx = tid + l * 256;
    int d4 = idx & 15, t = idx >> 4;
    size_t o = (size_t)(b * Tt + t0 + t) * DIM + h * Dd + d4 * 4;
    short4 k4 = *(const short4*)(K + o);
    short4 v4 = *(const short4*)(V + o);
    Ks[t][d4 * 4 + 0] = bf2f(k4.x); Ks[t][d4 * 4 + 1] = bf2f(k4.y);
    Ks[t][d4 * 4 + 2] = bf2f(k4.z); Ks[t][d4 * 4 + 3] = bf2f(k4.w);
    Vs[t][d4 * 4 + 0] = bf2f(v4.x); Vs[t][d4 * 4 + 1] = bf2f(v4.y);
    Vs[t][d4 * 4 + 2] = bf2f(v4.z); Vs[t][d4 * 4 + 3] = bf2f(v4.w);
  }
  __syncthreads();
  float acc[4][4] = {};
  for (int t = 0; t < CH; ++t) {
    float4 k4 = *(const float4*)&Ks[t][ty * 4];
    float4 v4 = *(const float4*)&Vs[t][tx * 4];
    float kv[4] = {k4.x, k4.y, k4.z, k4.w};
    float vv[4] = {v4.x, v4.y, v4.z, v4.w};
#pragma unroll
    for (int i = 0; i < 4; ++i)
#pragma unroll
      for (int j = 0; j < 4; ++j) acc[i][j] += kv[i] * vv[j];
  }
  const size_t base = ((size_t)(b * Hh + h) * NC + c) * (Dd * Dd);
#pragma unroll
  for (int i = 0; i < 4; ++i) {
    float4 s4 = make_float4(acc[i][0], acc[i][1], acc[i][2], acc[i][3]);
    *(float4*)&Sc[base + (size_t)(ty * 4 + i) * Dd + tx * 4] = s4;
  }
  if (tid < Dd) {
    float s = 0.f;
    for (int t = 0; t < CH; ++t) s += Ks[t][tid];
    zc[((size_t)(b * Hh + h) * NC + c) * Dd + tid] = s;
  }
}

// ---------------------------------------------------------------------------
// K3: exclusive prefix scan over chunks. grid (16 bh, 16 slices) x 256.
// ---------------------------------------------------------------------------
__global__ __launch_bounds__(256) void k_scan(float* __restrict__ Sc,
                                              float* __restrict__ zc) {
  const int bh = blockIdx.x;
  const int o = blockIdx.y * 256 + threadIdx.x;
  const size_t base = (size_t)bh * NC * (Dd * Dd) + o;
  float v[NC];
#pragma unroll
  for (int c = 0; c < NC; ++c) v[c] = Sc[base + (size_t)c * (Dd * Dd)];
  float run = 0.f;
#pragma unroll
  for (int c = 0; c < NC; ++c) {
    Sc[base + (size_t)c * (Dd * Dd)] = run;
    run += v[c];
  }
  if (blockIdx.y == 0 && threadIdx.x < Dd) {
    float rz = 0.f;
    for (int c = 0; c < NC; ++c) {
      size_t oz = ((size_t)bh * NC + c) * Dd + threadIdx.x;
      float cur = zc[oz];
      zc[oz] = rz;
      rz += cur;
    }
  }
}

// ---------------------------------------------------------------------------
// K4: per-chunk output (fp32 vector, bf16 in/out).
// ---------------------------------------------------------------------------
__global__ __launch_bounds__(256) void k_out(
    const unsigned short* __restrict__ Q, const unsigned short* __restrict__ K,
    const unsigned short* __restrict__ V, const float* __restrict__ Sc,
    const float* __restrict__ zc, unsigned short* __restrict__ O) {
  __shared__ float Qs[CH][68];
  __shared__ float KVs[CH * 68];
  __shared__ float As[CH][68];
  __shared__ float Ss[Dd][68];
  __shared__ float zs[Dd];
  __shared__ float dens[CH];
  const int c = blockIdx.x, h = blockIdx.y, b = blockIdx.z;
  const int tx = threadIdx.x, ty = threadIdx.y;
  const int tid = ty * 16 + tx;
  const int t0 = c * CH;

  // load Q [t][d]; K transposed [d][t] (pad 65)
#pragma unroll
  for (int l = 0; l < 4; ++l) {
    int idx = tid + l * 256;
    int d4 = idx & 15, t = idx >> 4;
    size_t o = (size_t)(b * Tt + t0 + t) * DIM + h * Dd + d4 * 4;
    short4 q4 = *(const short4*)(Q + o);
    short4 k4 = *(const short4*)(K + o);
    Qs[t][d4 * 4 + 0] = bf2f(q4.x); Qs[t][d4 * 4 + 1] = bf2f(q4.y);
    Qs[t][d4 * 4 + 2] = bf2f(q4.z); Qs[t][d4 * 4 + 3] = bf2f(q4.w);
    KVs[(d4 * 4 + 0) * 65 + t] = bf2f(k4.x);
    KVs[(d4 * 4 + 1) * 65 + t] = bf2f(k4.y);
    KVs[(d4 * 4 + 2) * 65 + t] = bf2f(k4.z);
    KVs[(d4 * 4 + 3) * 65 + t] = bf2f(k4.w);
  }
  __syncthreads();

  // A[i][j] = sum_d Q[i][d]*K[j][d], masked j<=i
  float acc[4][4] = {};
  for (int d0 = 0; d0 < Dd; d0 += 4) {
    float4 q4[4];
#pragma unroll
    for (int i = 0; i < 4; ++i) q4[i] = *(const float4*)&Qs[ty * 4 + i][d0];
#pragma unroll
    for (int dd = 0; dd < 4; ++dd) {
      int d = d0 + dd;
      float kv[4];
#pragma unroll
      for (int j = 0; j < 4; ++j) kv[j] = KVs[d * 65 + tx * 4 + j];
#pragma unroll
      for (int i = 0; i < 4; ++i) {
        float qv = ((const float*)&q4[i])[dd];
#pragma unroll
        for (int j = 0; j < 4; ++j) acc[i][j] += qv * kv[j];
      }
    }
  }
#pragma unroll
  for (int i = 0; i < 4; ++i)
#pragma unroll
    for (int j = 0; j < 4; ++j) {
      int ti = ty * 4 + i, sj = tx * 4 + j;
      As[ti][sj] = (sj <= ti) ? acc[i][j] : 0.f;
    }
  __syncthreads();

  // V into KVs row-major (pad 68); S_prev, z_prev
#pragma unroll
  for (int l = 0; l < 4; ++l) {
    int idx = tid + l * 256;
    int d4 = idx & 15, t = idx >> 4;
    size_t o = (size_t)(b * Tt + t0 + t) * DIM + h * Dd + d4 * 4;
    short4 v4 = *(const short4*)(V + o);
    KVs[t * 68 + d4 * 4 + 0] = bf2f(v4.x);
    KVs[t * 68 + d4 * 4 + 1] = bf2f(v4.y);
    KVs[t * 68 + d4 * 4 + 2] = bf2f(v4.z);
    KVs[t * 68 + d4 * 4 + 3] = bf2f(v4.w);
  }
  const size_t sbase = ((size_t)(b * Hh + h) * NC + c) * (Dd * Dd);
#pragma unroll
  for (int l = 0; l < 4; ++l) {
    int idx = tid + l * 256;
    int e4 = idx & 15, dd = idx >> 4;
    float4 s4 = *(const float4*)&Sc[sbase + (size_t)dd * Dd + e4 * 4];
    Ss[dd][e4 * 4 + 0] = s4.x; Ss[dd][e4 * 4 + 1] = s4.y;
    Ss[dd][e4 * 4 + 2] = s4.z; Ss[dd][e4 * 4 + 3] = s4.w;
  }
  if (tid < Dd) zs[tid] = zc[((size_t)(b * Hh + h) * NC + c) * Dd + tid];
  __syncthreads();

  if (tid < CH) {
    int i = tid;
    float rs = 0.f;
    for (int j = 0; j < CH; ++j) rs += As[i][j];
    float qz = 0.f;
    for (int d = 0; d < Dd; ++d) qz += Qs[i][d] * zs[d];
    dens[i] = fmaxf(rs + qz, 1e-6f);
  }
  float oacc[4][4] = {};
  for (int j = 0; j < CH; ++j) {
    float4 v4 = *(const float4*)&KVs[j * 68 + tx * 4];
    float vv[4] = {v4.x, v4.y, v4.z, v4.w};
    float av[4];
#pragma unroll
    for (int i = 0; i < 4; ++i) av[i] = As[ty * 4 + i][j];
#pragma unroll
    for (int i = 0; i < 4; ++i)
#pragma unroll
      for (int jj = 0; jj < 4; ++jj) oacc[i][jj] += av[i] * vv[jj];
  }
  for (int d = 0; d < Dd; ++d) {
    float4 s4 = *(const float4*)&Ss[d][tx * 4];
    float sv[4] = {s4.x, s4.y, s4.z, s4.w};
    float qv[4];
#pragma unroll
    for (int i = 0; i < 4; ++i) qv[i] = Qs[ty * 4 + i][d];
#pragma unroll
    for (int i = 0; i < 4; ++i)
#pragma unroll
      for (int jj = 0; jj < 4; ++jj) oacc[i][jj] += qv[i] * sv[jj];
  }
  __syncthreads();
#pragma unroll
  for (int i = 0; i < 4; ++i) {
    float inv = 1.f / dens[ty * 4 + i];
#pragma unroll
    for (int jj = 0; jj < 4; ++jj) {
      O[(size_t)(b * Tt + t0 + ty * 4 + i) * DIM + h * Dd + tx * 4 + jj] =
          f2bf(oacc[i][jj] * inv);
    }
  }
}

// ---------------------------------------------------------------------------
// GEMM2: out = (O @ Wo) * G.  M=8192, K=256, N=768.
// ---------------------------------------------------------------------------
__global__ __launch_bounds__(256) void k_gemm2(
    const unsigned short* __restrict__ Ob, const unsigned short* __restrict__ WoT,
    const unsigned short* __restrict__ G, float* __restrict__ out) {
  __shared__ short As[128 * 64];
  __shared__ short Bs[128 * 64];
  const int tid = threadIdx.x;
  const int w = tid >> 6, l = tid & 63;
  const int lr = l & 15, lg = l >> 4;
  const int wr = w >> 1, wc = w & 1;
  int mt, nt;
  xcd_tile(blockIdx.x, DM / 128, mt, nt);
  const int m0 = mt * 128, n0 = nt * 128;

  f32x4 acc[4][4];
#pragma unroll
  for (int i = 0; i < 4; ++i)
#pragma unroll
    for (int j = 0; j < 4; ++j) acc[i][j] = (f32x4){0.f, 0.f, 0.f, 0.f};

  for (int k0 = 0; k0 < DIM; k0 += 64) {
    stage_tile((const short*)Ob + (size_t)m0 * DIM, DIM, k0, As, w, l);
    stage_tile((const short*)WoT + (size_t)n0 * DIM, DIM, k0, Bs, w, l);
    __syncthreads();
#pragma unroll
    for (int ks = 0; ks < 2; ++ks) {
      bf16x8 af[4], bf[4];
#pragma unroll
      for (int mi = 0; mi < 4; ++mi)
        af[mi] = *(const bf16x8*)&As[(wr * 64 + mi * 16 + lr) * 64 + ks * 32 + lg * 8];
#pragma unroll
      for (int ni = 0; ni < 4; ++ni)
        bf[ni] = *(const bf16x8*)&Bs[(wc * 64 + ni * 16 + lr) * 64 + ks * 32 + lg * 8];
#pragma unroll
      for (int mi = 0; mi < 4; ++mi)
#pragma unroll
        for (int ni = 0; ni < 4; ++ni)
          acc[mi][ni] = __builtin_amdgcn_mfma_f32_16x16x32_bf16(
              af[mi], bf[ni], acc[mi][ni], 0, 0, 0);
    }
    __syncthreads();
  }

#pragma unroll
  for (int mi = 0; mi < 4; ++mi)
#pragma unroll
    for (int ni = 0; ni < 4; ++ni) {
      int col = n0 + wc * 64 + ni * 16 + lr;
#pragma unroll
      for (int r = 0; r < 4; ++r) {
        int row = m0 + wr * 64 + mi * 16 + lg * 4 + r;
        float g = bf2f(G[(size_t)row * DM + col]);
        out[(size_t)row * DM + col] = acc[mi][ni][r] * g;
      }
    }
}

// ---------------------------------------------------------------------------
extern "C" void kernel_launch(void* const* d_in, const int* in_sizes, int n_in,
                              void* d_out, int out_size, void* d_ws,
                              size_t ws_size, hipStream_t stream) {
  const float* x  = (const float*)d_in[0];
  const float* Wq = (const float*)d_in[1];
  const float* Wk = (const float*)d_in[2];
  const float* Wv = (const float*)d_in[3];
  const float* Wo = (const float*)d_in[4];
  const float* Wg = (const float*)d_in[5];
  float* out = (float*)d_out;

  char* p = (char*)d_ws;
  size_t off = 0;
  auto alloc = [&](size_t bytes) {
    void* r = p + off;
    off = (off + bytes + 255) & ~(size_t)255;
    return r;
  };
  unsigned short* xb  = (unsigned short*)alloc((size_t)BT * DM * 2);
  unsigned short* WT  = (unsigned short*)alloc((size_t)NQKVG * DM * 2);
  unsigned short* WoT = (unsigned short*)alloc((size_t)DM * DIM * 2);
  unsigned short* Q   = (unsigned short*)alloc((size_t)BT * DIM * 2);
  unsigned short* Kf  = (unsigned short*)alloc((size_t)BT * DIM * 2);
  unsigned short* Vf  = (unsigned short*)alloc((size_t)BT * DIM * 2);
  unsigned short* G   = (unsigned short*)alloc((size_t)BT * DM * 2);
  unsigned short* Ob  = (unsigned short*)alloc((size_t)BT * DIM * 2);
  float* Sc = (float*)alloc((size_t)Bb * Hh * NC * Dd * Dd * 4);
  float* zc = (float*)alloc((size_t)Bb * Hh * NC * Dd * 4);

  // 1. input cast + all weight transposes (one launch each)
  k_cast<<<dim3((BT * DM / 8 + 255) / 256), dim3(256), 0, stream>>>(x, xb, BT * DM / 8);
  k_convAll<<<dim3(1344), dim3(32, 8), 0, stream>>>(Wq, Wk, Wv, Wg, Wo, WT, WoT);

  // 2. fused QKV + gate projection (MFMA), N=1536
  k_gemm1<<<dim3(MT * (NQKVG / 128)), dim3(256), 0, stream>>>(
      xb, WT, Q, Kf, Vf, G);

  // 3. chunked linear attention
  dim3 blk(16, 16);
  k_chunksum<<<dim3(NC, Hh, Bb), blk, 0, stream>>>(Kf, Vf, Sc, zc);
  k_scan<<<dim3(Bb * Hh, Dd * Dd / 256), dim3(256), 0, stream>>>(Sc, zc);
  k_out<<<dim3(NC, Hh, Bb), blk, 0, stream>>>(Q, Kf, Vf, Sc, zc, Ob);

  // 4. output GEMM * gate (MFMA)
  k_gemm2<<<dim3(MT * (DM / 128)), dim3(256), 0, stream>>>(Ob, WoT, G, out);
}

// Round 5
// 108.593 us; speedup vs baseline: 1.0960x; 1.0639x over previous
//
#include <hip/hip_runtime.h>
#include <math.h>

typedef __attribute__((ext_vector_type(8))) short bf16x8;
typedef __attribute__((ext_vector_type(4))) float f32x4;

namespace {
constexpr int Bb  = 4;
constexpr int Tt  = 2048;
constexpr int DM  = 768;
constexpr int Hh  = 4;
constexpr int Dd  = 64;
constexpr int DIM = 256;          // H*D
constexpr int BT  = Bb * Tt;      // 8192
constexpr int CH  = 64;           // chunk length
constexpr int NC  = Tt / CH;      // 32 chunks
constexpr int NQKVG = 1536;       // QKV (768) + gate (768) output cols
constexpr int MT  = BT / 128;     // 64 m-tiles
}

__device__ __forceinline__ float elu1(float x) { return x > 0.f ? x + 1.f : expf(x); }

// fp32 -> bf16, round-to-nearest-even
__device__ __forceinline__ unsigned short f2bf(float f) {
  unsigned int x = __float_as_uint(f);
  unsigned int r = (x + 0x7fffu + ((x >> 16) & 1u)) >> 16;
  return (unsigned short)r;
}
__device__ __forceinline__ float bf2f(unsigned short u) {
  return __uint_as_float((unsigned int)u << 16);
}

__device__ __forceinline__ void gload16(const void* g, void* l) {
  __builtin_amdgcn_global_load_lds(
      (const __attribute__((address_space(1))) void*)g,
      (__attribute__((address_space(3))) void*)l, 16, 0, 0);
}

// Stage a 128x64 bf16 tile into LDS with XOR-swizzle (T2, rule #21):
// LDS dest stays linear (gload_lds writes base+lane*16); the 16B-column each
// lane FETCHES is permuted c16' = (l&7) ^ (l>>3)  (row&7 == l>>3).
// Readers must XOR their 16B-slot index with (row&7).
__device__ __forceinline__ void stage_tile(const short* __restrict__ gbase,
                                           size_t ld, int k0,
                                           short* lds, int w, int l) {
  const int c16 = (l & 7) ^ (l >> 3);
#pragma unroll
  for (int i = 0; i < 4; ++i) {
    int seg = w * 4 + i;
    int row = seg * 8 + (l >> 3);
    gload16(gbase + (size_t)row * ld + k0 + c16 * 8, (char*)lds + seg * 1024);
  }
}

// L2-resident tiling: each XCD (bid&7, round-robin dispatch) owns 8
// contiguous m-tiles and iterates all n-tiles over them. Per-XCD working
// set = 8x196KB A-panel + B stream -> fits 4MB XCD L2.
__device__ __forceinline__ void xcd_tile(int bid, int nt_count, int& mt, int& nt) {
  int xcd = bid & 7;
  int idx = bid >> 3;
  mt = xcd * 8 + (idx & 7);
  nt = idx >> 3;
  (void)nt_count;
}

// ---------------------------------------------------------------------------
// cast fp32 -> bf16, 8 elements/thread
// ---------------------------------------------------------------------------
__global__ __launch_bounds__(256) void k_cast(const float* __restrict__ in,
                                              unsigned short* __restrict__ out,
                                              int n8) {
  int i = blockIdx.x * 256 + threadIdx.x;
  if (i >= n8) return;
  const float4* p = (const float4*)(in + (size_t)i * 8);
  float4 a = p[0], b = p[1];
  union { unsigned short u[8]; uint4 v; } r;
  r.u[0] = f2bf(a.x); r.u[1] = f2bf(a.y); r.u[2] = f2bf(a.z); r.u[3] = f2bf(a.w);
  r.u[4] = f2bf(b.x); r.u[5] = f2bf(b.y); r.u[6] = f2bf(b.z); r.u[7] = f2bf(b.w);
  *(uint4*)(out + (size_t)i * 8) = r.v;
}

// ---------------------------------------------------------------------------
// all weight transposes in ONE launch.
// WT rows: [0,256)=Wq^T [256,512)=Wk^T [512,768)=Wv^T [768,1536)=Wg^T, ld=768
// WoT: Wo^T [768][256], ld=256
// ---------------------------------------------------------------------------
__global__ __launch_bounds__(256) void k_convAll(
    const float* __restrict__ Wq, const float* __restrict__ Wk,
    const float* __restrict__ Wv, const float* __restrict__ Wg,
    const float* __restrict__ Wo, unsigned short* __restrict__ WT,
    unsigned short* __restrict__ WoT) {
  __shared__ float t[32][33];
  int idx = blockIdx.x;
  const float* src;
  unsigned short* out;
  int K, N, n_off, ldo;
  if (idx < 576) {               // Wq/Wk/Wv: [768][256], 192 tiles each
    int z = idx / 192;
    idx %= 192;
    src = (z == 0) ? Wq : (z == 1) ? Wk : Wv;
    out = WT; K = 768; N = 256; n_off = z * 256; ldo = 768;
  } else if (idx < 1152) {       // Wg: [768][768], 576 tiles
    idx -= 576;
    src = Wg; out = WT; K = 768; N = 768; n_off = 768; ldo = 768;
  } else {                       // Wo: [256][768], 192 tiles
    idx -= 1152;
    src = Wo; out = WoT; K = 256; N = 768; n_off = 0; ldo = 256;
  }
  int kt = idx % (K / 32), nt = idx / (K / 32);
  int k0 = kt * 32, n0 = nt * 32;
  const int tx = threadIdx.x, ty = threadIdx.y;
  for (int i = ty; i < 32; i += 8)
    t[i][tx] = src[(size_t)(k0 + i) * N + n0 + tx];
  __syncthreads();
  for (int i = ty; i < 32; i += 8)
    out[(size_t)(n_off + n0 + i) * ldo + k0 + tx] = f2bf(t[tx][i]);
}

// ---------------------------------------------------------------------------
// GEMM1: [QKVG] = x @ [Wq|Wk|Wv|Wg]^T.  M=8192, K=768, N=1536 (B^T input).
// 128x128 tile, 4 waves (2x2), 4x4 fragments of 16x16x32 per wave.
// LDS tiles XOR-swizzled (see stage_tile).
// Epilogue: cols<512 -> elu+1 -> Q/K bf16; <768 -> V bf16; else sigmoid -> G.
// ---------------------------------------------------------------------------
__global__ __launch_bounds__(256) void k_gemm1(
    const unsigned short* __restrict__ xb, const unsigned short* __restrict__ WT,
    unsigned short* __restrict__ Q, unsigned short* __restrict__ K,
    unsigned short* __restrict__ V, unsigned short* __restrict__ G) {
  __shared__ short As[128 * 64];
  __shared__ short Bs[128 * 64];
  const int tid = threadIdx.x;
  const int w = tid >> 6, l = tid & 63;
  const int lr = l & 15, lg = l >> 4;
  const int wr = w >> 1, wc = w & 1;
  const int sa = lr & 7;               // row&7 for this lane's fragment rows
  int mt, nt;
  xcd_tile(blockIdx.x, NQKVG / 128, mt, nt);
  const int m0 = mt * 128, n0 = nt * 128;

  f32x4 acc[4][4];
#pragma unroll
  for (int i = 0; i < 4; ++i)
#pragma unroll
    for (int j = 0; j < 4; ++j) acc[i][j] = (f32x4){0.f, 0.f, 0.f, 0.f};

  for (int k0 = 0; k0 < DM; k0 += 64) {
    stage_tile((const short*)xb + (size_t)m0 * DM, DM, k0, As, w, l);
    stage_tile((const short*)WT + (size_t)n0 * DM, DM, k0, Bs, w, l);
    __syncthreads();
#pragma unroll
    for (int ks = 0; ks < 2; ++ks) {
      bf16x8 af[4], bf[4];
#pragma unroll
      for (int mi = 0; mi < 4; ++mi)
        af[mi] = *(const bf16x8*)&As[(wr * 64 + mi * 16 + lr) * 64 +
                                     ((ks * 4 + lg) ^ sa) * 8];
#pragma unroll
      for (int ni = 0; ni < 4; ++ni)
        bf[ni] = *(const bf16x8*)&Bs[(wc * 64 + ni * 16 + lr) * 64 +
                                     ((ks * 4 + lg) ^ sa) * 8];
#pragma unroll
      for (int mi = 0; mi < 4; ++mi)
#pragma unroll
        for (int ni = 0; ni < 4; ++ni)
          acc[mi][ni] = __builtin_amdgcn_mfma_f32_16x16x32_bf16(
              af[mi], bf[ni], acc[mi][ni], 0, 0, 0);
    }
    __syncthreads();
  }

#pragma unroll
  for (int mi = 0; mi < 4; ++mi)
#pragma unroll
    for (int ni = 0; ni < 4; ++ni) {
      int col0 = n0 + wc * 64 + ni * 16;  // uniform across lanes, 16-aligned
#pragma unroll
      for (int r = 0; r < 4; ++r) {
        int row = m0 + wr * 64 + mi * 16 + lg * 4 + r;
        float v = acc[mi][ni][r];
        if (col0 < 512) {
          unsigned short* dst = (col0 < 256) ? Q : K;
          dst[(size_t)row * DIM + (col0 & 255) + lr] = f2bf(elu1(v));
        } else if (col0 < 768) {
          V[(size_t)row * DIM + (col0 & 255) + lr] = f2bf(v);
        } else {
          float g = 1.f / (1.f + expf(-v));
          G[(size_t)row * DM + (col0 - 768) + lr] = f2bf(g);
        }
      }
    }
}

// ---------------------------------------------------------------------------
// K2: per-chunk local sums (fp32 vector, bf16 inputs).
// ---------------------------------------------------------------------------
__global__ __launch_bounds__(256) void k_chunksum(
    const unsigned short* __restrict__ K, const unsigned short* __restrict__ V,
    float* __restrict__ Sc, float* __restrict__ zc) {
  __shared__ float Ks[CH][68];
  __shared__ float Vs[CH][68];
  const int c = blockIdx.x, h = blockIdx.y, b = blockIdx.z;
  const int tx = threadIdx.x, ty = threadIdx.y;
  const int tid = ty * 16 + tx;
  const int t0 = c * CH;
#pragma unroll
  for (int l = 0; l < 4; ++l) {
    int idx = tid + l * 256;
    int d4 = idx & 15, t = idx >> 4;
    size_t o = (size_t)(b * Tt + t0 + t) * DIM + h * Dd + d4 * 4;
    short4 k4 = *(const short4*)(K + o);
    short4 v4 = *(const short4*)(V + o);
    Ks[t][d4 * 4 + 0] = bf2f(k4.x); Ks[t][d4 * 4 + 1] = bf2f(k4.y);
    Ks[t][d4 * 4 + 2] = bf2f(k4.z); Ks[t][d4 * 4 + 3] = bf2f(k4.w);
    Vs[t][d4 * 4 + 0] = bf2f(v4.x); Vs[t][d4 * 4 + 1] = bf2f(v4.y);
    Vs[t][d4 * 4 + 2] = bf2f(v4.z); Vs[t][d4 * 4 + 3] = bf2f(v4.w);
  }
  __syncthreads();
  float acc[4][4] = {};
  for (int t = 0; t < CH; ++t) {
    float4 k4 = *(const float4*)&Ks[t][ty * 4];
    float4 v4 = *(const float4*)&Vs[t][tx * 4];
    float kv[4] = {k4.x, k4.y, k4.z, k4.w};
    float vv[4] = {v4.x, v4.y, v4.z, v4.w};
#pragma unroll
    for (int i = 0; i < 4; ++i)
#pragma unroll
      for (int j = 0; j < 4; ++j) acc[i][j] += kv[i] * vv[j];
  }
  const size_t base = ((size_t)(b * Hh + h) * NC + c) * (Dd * Dd);
#pragma unroll
  for (int i = 0; i < 4; ++i) {
    float4 s4 = make_float4(acc[i][0], acc[i][1], acc[i][2], acc[i][3]);
    *(float4*)&Sc[base + (size_t)(ty * 4 + i) * Dd + tx * 4] = s4;
  }
  if (tid < Dd) {
    float s = 0.f;
    for (int t = 0; t < CH; ++t) s += Ks[t][tid];
    zc[((size_t)(b * Hh + h) * NC + c) * Dd + tid] = s;
  }
}

// ---------------------------------------------------------------------------
// K3: exclusive prefix scan over chunks. grid (16 bh, 16 slices) x 256.
// ---------------------------------------------------------------------------
__global__ __launch_bounds__(256) void k_scan(float* __restrict__ Sc,
                                              float* __restrict__ zc) {
  const int bh = blockIdx.x;
  const int o = blockIdx.y * 256 + threadIdx.x;
  const size_t base = (size_t)bh * NC * (Dd * Dd) + o;
  float v[NC];
#pragma unroll
  for (int c = 0; c < NC; ++c) v[c] = Sc[base + (size_t)c * (Dd * Dd)];
  float run = 0.f;
#pragma unroll
  for (int c = 0; c < NC; ++c) {
    Sc[base + (size_t)c * (Dd * Dd)] = run;
    run += v[c];
  }
  if (blockIdx.y == 0 && threadIdx.x < Dd) {
    float rz = 0.f;
    for (int c = 0; c < NC; ++c) {
      size_t oz = ((size_t)bh * NC + c) * Dd + threadIdx.x;
      float cur = zc[oz];
      zc[oz] = rz;
      rz += cur;
    }
  }
}

// ---------------------------------------------------------------------------
// K4: per-chunk output (fp32 vector, bf16 in/out).
// ---------------------------------------------------------------------------
__global__ __launch_bounds__(256) void k_out(
    const unsigned short* __restrict__ Q, const unsigned short* __restrict__ K,
    const unsigned short* __restrict__ V, const float* __restrict__ Sc,
    const float* __restrict__ zc, unsigned short* __restrict__ O) {
  __shared__ float Qs[CH][68];
  __shared__ float KVs[CH * 68];
  __shared__ float As[CH][68];
  __shared__ float Ss[Dd][68];
  __shared__ float zs[Dd];
  __shared__ float dens[CH];
  const int c = blockIdx.x, h = blockIdx.y, b = blockIdx.z;
  const int tx = threadIdx.x, ty = threadIdx.y;
  const int tid = ty * 16 + tx;
  const int t0 = c * CH;

  // load Q [t][d]; K transposed [d][t] (pad 65)
#pragma unroll
  for (int l = 0; l < 4; ++l) {
    int idx = tid + l * 256;
    int d4 = idx & 15, t = idx >> 4;
    size_t o = (size_t)(b * Tt + t0 + t) * DIM + h * Dd + d4 * 4;
    short4 q4 = *(const short4*)(Q + o);
    short4 k4 = *(const short4*)(K + o);
    Qs[t][d4 * 4 + 0] = bf2f(q4.x); Qs[t][d4 * 4 + 1] = bf2f(q4.y);
    Qs[t][d4 * 4 + 2] = bf2f(q4.z); Qs[t][d4 * 4 + 3] = bf2f(q4.w);
    KVs[(d4 * 4 + 0) * 65 + t] = bf2f(k4.x);
    KVs[(d4 * 4 + 1) * 65 + t] = bf2f(k4.y);
    KVs[(d4 * 4 + 2) * 65 + t] = bf2f(k4.z);
    KVs[(d4 * 4 + 3) * 65 + t] = bf2f(k4.w);
  }
  __syncthreads();

  // A[i][j] = sum_d Q[i][d]*K[j][d], masked j<=i
  float acc[4][4] = {};
  for (int d0 = 0; d0 < Dd; d0 += 4) {
    float4 q4[4];
#pragma unroll
    for (int i = 0; i < 4; ++i) q4[i] = *(const float4*)&Qs[ty * 4 + i][d0];
#pragma unroll
    for (int dd = 0; dd < 4; ++dd) {
      int d = d0 + dd;
      float kv[4];
#pragma unroll
      for (int j = 0; j < 4; ++j) kv[j] = KVs[d * 65 + tx * 4 + j];
#pragma unroll
      for (int i = 0; i < 4; ++i) {
        float qv = ((const float*)&q4[i])[dd];
#pragma unroll
        for (int j = 0; j < 4; ++j) acc[i][j] += qv * kv[j];
      }
    }
  }
#pragma unroll
  for (int i = 0; i < 4; ++i)
#pragma unroll
    for (int j = 0; j < 4; ++j) {
      int ti = ty * 4 + i, sj = tx * 4 + j;
      As[ti][sj] = (sj <= ti) ? acc[i][j] : 0.f;
    }
  __syncthreads();

  // V into KVs row-major (pad 68); S_prev, z_prev
#pragma unroll
  for (int l = 0; l < 4; ++l) {
    int idx = tid + l * 256;
    int d4 = idx & 15, t = idx >> 4;
    size_t o = (size_t)(b * Tt + t0 + t) * DIM + h * Dd + d4 * 4;
    short4 v4 = *(const short4*)(V + o);
    KVs[t * 68 + d4 * 4 + 0] = bf2f(v4.x);
    KVs[t * 68 + d4 * 4 + 1] = bf2f(v4.y);
    KVs[t * 68 + d4 * 4 + 2] = bf2f(v4.z);
    KVs[t * 68 + d4 * 4 + 3] = bf2f(v4.w);
  }
  const size_t sbase = ((size_t)(b * Hh + h) * NC + c) * (Dd * Dd);
#pragma unroll
  for (int l = 0; l < 4; ++l) {
    int idx = tid + l * 256;
    int e4 = idx & 15, dd = idx >> 4;
    float4 s4 = *(const float4*)&Sc[sbase + (size_t)dd * Dd + e4 * 4];
    Ss[dd][e4 * 4 + 0] = s4.x; Ss[dd][e4 * 4 + 1] = s4.y;
    Ss[dd][e4 * 4 + 2] = s4.z; Ss[dd][e4 * 4 + 3] = s4.w;
  }
  if (tid < Dd) zs[tid] = zc[((size_t)(b * Hh + h) * NC + c) * Dd + tid];
  __syncthreads();

  if (tid < CH) {
    int i = tid;
    float rs = 0.f;
    for (int j = 0; j < CH; ++j) rs += As[i][j];
    float qz = 0.f;
    for (int d = 0; d < Dd; ++d) qz += Qs[i][d] * zs[d];
    dens[i] = fmaxf(rs + qz, 1e-6f);
  }
  float oacc[4][4] = {};
  for (int j = 0; j < CH; ++j) {
    float4 v4 = *(const float4*)&KVs[j * 68 + tx * 4];
    float vv[4] = {v4.x, v4.y, v4.z, v4.w};
    float av[4];
#pragma unroll
    for (int i = 0; i < 4; ++i) av[i] = As[ty * 4 + i][j];
#pragma unroll
    for (int i = 0; i < 4; ++i)
#pragma unroll
      for (int jj = 0; jj < 4; ++jj) oacc[i][jj] += av[i] * vv[jj];
  }
  for (int d = 0; d < Dd; ++d) {
    float4 s4 = *(const float4*)&Ss[d][tx * 4];
    float sv[4] = {s4.x, s4.y, s4.z, s4.w};
    float qv[4];
#pragma unroll
    for (int i = 0; i < 4; ++i) qv[i] = Qs[ty * 4 + i][d];
#pragma unroll
    for (int i = 0; i < 4; ++i)
#pragma unroll
      for (int jj = 0; jj < 4; ++jj) oacc[i][jj] += qv[i] * sv[jj];
  }
  __syncthreads();
#pragma unroll
  for (int i = 0; i < 4; ++i) {
    float inv = 1.f / dens[ty * 4 + i];
#pragma unroll
    for (int jj = 0; jj < 4; ++jj) {
      O[(size_t)(b * Tt + t0 + ty * 4 + i) * DIM + h * Dd + tx * 4 + jj] =
          f2bf(oacc[i][jj] * inv);
    }
  }
}

// ---------------------------------------------------------------------------
// GEMM2: out = (O @ Wo) * G.  M=8192, K=256, N=768.  Swizzled LDS.
// ---------------------------------------------------------------------------
__global__ __launch_bounds__(256) void k_gemm2(
    const unsigned short* __restrict__ Ob, const unsigned short* __restrict__ WoT,
    const unsigned short* __restrict__ G, float* __restrict__ out) {
  __shared__ short As[128 * 64];
  __shared__ short Bs[128 * 64];
  const int tid = threadIdx.x;
  const int w = tid >> 6, l = tid & 63;
  const int lr = l & 15, lg = l >> 4;
  const int wr = w >> 1, wc = w & 1;
  const int sa = lr & 7;
  int mt, nt;
  xcd_tile(blockIdx.x, DM / 128, mt, nt);
  const int m0 = mt * 128, n0 = nt * 128;

  f32x4 acc[4][4];
#pragma unroll
  for (int i = 0; i < 4; ++i)
#pragma unroll
    for (int j = 0; j < 4; ++j) acc[i][j] = (f32x4){0.f, 0.f, 0.f, 0.f};

  for (int k0 = 0; k0 < DIM; k0 += 64) {
    stage_tile((const short*)Ob + (size_t)m0 * DIM, DIM, k0, As, w, l);
    stage_tile((const short*)WoT + (size_t)n0 * DIM, DIM, k0, Bs, w, l);
    __syncthreads();
#pragma unroll
    for (int ks = 0; ks < 2; ++ks) {
      bf16x8 af[4], bf[4];
#pragma unroll
      for (int mi = 0; mi < 4; ++mi)
        af[mi] = *(const bf16x8*)&As[(wr * 64 + mi * 16 + lr) * 64 +
                                     ((ks * 4 + lg) ^ sa) * 8];
#pragma unroll
      for (int ni = 0; ni < 4; ++ni)
        bf[ni] = *(const bf16x8*)&Bs[(wc * 64 + ni * 16 + lr) * 64 +
                                     ((ks * 4 + lg) ^ sa) * 8];
#pragma unroll
      for (int mi = 0; mi < 4; ++mi)
#pragma unroll
        for (int ni = 0; ni < 4; ++ni)
          acc[mi][ni] = __builtin_amdgcn_mfma_f32_16x16x32_bf16(
              af[mi], bf[ni], acc[mi][ni], 0, 0, 0);
    }
    __syncthreads();
  }

#pragma unroll
  for (int mi = 0; mi < 4; ++mi)
#pragma unroll
    for (int ni = 0; ni < 4; ++ni) {
      int col = n0 + wc * 64 + ni * 16 + lr;
#pragma unroll
      for (int r = 0; r < 4; ++r) {
        int row = m0 + wr * 64 + mi * 16 + lg * 4 + r;
        float g = bf2f(G[(size_t)row * DM + col]);
        out[(size_t)row * DM + col] = acc[mi][ni][r] * g;
      }
    }
}

// ---------------------------------------------------------------------------
extern "C" void kernel_launch(void* const* d_in, const int* in_sizes, int n_in,
                              void* d_out, int out_size, void* d_ws,
                              size_t ws_size, hipStream_t stream) {
  const float* x  = (const float*)d_in[0];
  const float* Wq = (const float*)d_in[1];
  const float* Wk = (const float*)d_in[2];
  const float* Wv = (const float*)d_in[3];
  const float* Wo = (const float*)d_in[4];
  const float* Wg = (const float*)d_in[5];
  float* out = (float*)d_out;

  char* p = (char*)d_ws;
  size_t off = 0;
  auto alloc = [&](size_t bytes) {
    void* r = p + off;
    off = (off + bytes + 255) & ~(size_t)255;
    return r;
  };
  unsigned short* xb  = (unsigned short*)alloc((size_t)BT * DM * 2);
  unsigned short* WT  = (unsigned short*)alloc((size_t)NQKVG * DM * 2);
  unsigned short* WoT = (unsigned short*)alloc((size_t)DM * DIM * 2);
  unsigned short* Q   = (unsigned short*)alloc((size_t)BT * DIM * 2);
  unsigned short* Kf  = (unsigned short*)alloc((size_t)BT * DIM * 2);
  unsigned short* Vf  = (unsigned short*)alloc((size_t)BT * DIM * 2);
  unsigned short* G   = (unsigned short*)alloc((size_t)BT * DM * 2);
  unsigned short* Ob  = (unsigned short*)alloc((size_t)BT * DIM * 2);
  float* Sc = (float*)alloc((size_t)Bb * Hh * NC * Dd * Dd * 4);
  float* zc = (float*)alloc((size_t)Bb * Hh * NC * Dd * 4);

  // 1. input cast + all weight transposes (one launch each)
  k_cast<<<dim3((BT * DM / 8 + 255) / 256), dim3(256), 0, stream>>>(x, xb, BT * DM / 8);
  k_convAll<<<dim3(1344), dim3(32, 8), 0, stream>>>(Wq, Wk, Wv, Wg, Wo, WT, WoT);

  // 2. fused QKV + gate projection (MFMA), N=1536
  k_gemm1<<<dim3(MT * (NQKVG / 128)), dim3(256), 0, stream>>>(
      xb, WT, Q, Kf, Vf, G);

  // 3. chunked linear attention
  dim3 blk(16, 16);
  k_chunksum<<<dim3(NC, Hh, Bb), blk, 0, stream>>>(Kf, Vf, Sc, zc);
  k_scan<<<dim3(Bb * Hh, Dd * Dd / 256), dim3(256), 0, stream>>>(Sc, zc);
  k_out<<<dim3(NC, Hh, Bb), blk, 0, stream>>>(Q, Kf, Vf, Sc, zc, Ob);

  // 4. output GEMM * gate (MFMA)
  k_gemm2<<<dim3(MT * (DM / 128)), dim3(256), 0, stream>>>(Ob, WoT, G, out);
}

// Round 6
// 93.295 us; speedup vs baseline: 1.2757x; 1.1640x over previous
//
#include <hip/hip_runtime.h>
#include <math.h>

typedef __attribute__((ext_vector_type(8))) short bf16x8;
typedef __attribute__((ext_vector_type(4))) float f32x4;

namespace {
constexpr int Bb  = 4;
constexpr int Tt  = 2048;
constexpr int DM  = 768;
constexpr int Hh  = 4;
constexpr int Dd  = 64;
constexpr int DIM = 256;          // H*D
constexpr int BT  = Bb * Tt;      // 8192
constexpr int CH  = 64;           // chunk length
constexpr int NC  = Tt / CH;      // 32 chunks
constexpr int NQKVG = 1536;       // QKV (768) + gate (768) output cols
constexpr int MT  = BT / 128;     // 64 m-tiles
}

__device__ __forceinline__ float elu1(float x) { return x > 0.f ? x + 1.f : expf(x); }

// fp32 -> bf16, round-to-nearest-even
__device__ __forceinline__ unsigned short f2bf(float f) {
  unsigned int x = __float_as_uint(f);
  unsigned int r = (x + 0x7fffu + ((x >> 16) & 1u)) >> 16;
  return (unsigned short)r;
}
__device__ __forceinline__ float bf2f(unsigned short u) {
  return __uint_as_float((unsigned int)u << 16);
}

__device__ __forceinline__ void gload16(const void* g, void* l) {
  __builtin_amdgcn_global_load_lds(
      (const __attribute__((address_space(1))) void*)g,
      (__attribute__((address_space(3))) void*)l, 16, 0, 0);
}

// Stage a 128x64 A-tile and B-tile (bf16 row-major) into LDS buffers with the
// XOR source-swizzle (T2, rule #21): LDS dest linear, fetched 16B-column
// permuted c16' = (l&7)^(l>>3); readers XOR their 16B slot with (row&7).
__device__ __forceinline__ void stage2(const short* __restrict__ Ag, size_t lda,
                                       const short* __restrict__ Bg, size_t ldb,
                                       int k0, short* as, short* bs, int w, int l) {
  const int c16 = (l & 7) ^ (l >> 3);
#pragma unroll
  for (int i = 0; i < 4; ++i) {
    int seg = w * 4 + i;
    int row = seg * 8 + (l >> 3);
    gload16(Ag + (size_t)row * lda + k0 + c16 * 8, (char*)as + seg * 1024);
    gload16(Bg + (size_t)row * ldb + k0 + c16 * 8, (char*)bs + seg * 1024);
  }
}

// one 128x128x64 MFMA step from swizzled LDS tiles
__device__ __forceinline__ void mma64(const short* as, const short* bs,
                                      f32x4 (&acc)[4][4],
                                      int wr, int wc, int lr, int lg) {
  const int sa = lr & 7;
#pragma unroll
  for (int ks = 0; ks < 2; ++ks) {
    bf16x8 af[4], bf[4];
#pragma unroll
    for (int mi = 0; mi < 4; ++mi)
      af[mi] = *(const bf16x8*)&as[(wr * 64 + mi * 16 + lr) * 64 +
                                   ((ks * 4 + lg) ^ sa) * 8];
#pragma unroll
    for (int ni = 0; ni < 4; ++ni)
      bf[ni] = *(const bf16x8*)&bs[(wc * 64 + ni * 16 + lr) * 64 +
                                   ((ks * 4 + lg) ^ sa) * 8];
#pragma unroll
    for (int mi = 0; mi < 4; ++mi)
#pragma unroll
      for (int ni = 0; ni < 4; ++ni)
        acc[mi][ni] = __builtin_amdgcn_mfma_f32_16x16x32_bf16(
            af[mi], bf[ni], acc[mi][ni], 0, 0, 0);
  }
}

// L2-resident tiling: each XCD (bid&7) owns 8 contiguous m-tiles.
__device__ __forceinline__ void xcd_tile(int bid, int& mt, int& nt) {
  int xcd = bid & 7;
  int idx = bid >> 3;
  mt = xcd * 8 + (idx & 7);
  nt = idx >> 3;
}

// ---------------------------------------------------------------------------
// cast fp32 -> bf16, 8 elements/thread
// ---------------------------------------------------------------------------
__global__ __launch_bounds__(256) void k_cast(const float* __restrict__ in,
                                              unsigned short* __restrict__ out,
                                              int n8) {
  int i = blockIdx.x * 256 + threadIdx.x;
  if (i >= n8) return;
  const float4* p = (const float4*)(in + (size_t)i * 8);
  float4 a = p[0], b = p[1];
  union { unsigned short u[8]; uint4 v; } r;
  r.u[0] = f2bf(a.x); r.u[1] = f2bf(a.y); r.u[2] = f2bf(a.z); r.u[3] = f2bf(a.w);
  r.u[4] = f2bf(b.x); r.u[5] = f2bf(b.y); r.u[6] = f2bf(b.z); r.u[7] = f2bf(b.w);
  *(uint4*)(out + (size_t)i * 8) = r.v;
}

// ---------------------------------------------------------------------------
// all weight transposes in ONE launch.
// WT rows: [0,256)=Wq^T [256,512)=Wk^T [512,768)=Wv^T [768,1536)=Wg^T, ld=768
// WoT: Wo^T [768][256], ld=256
// ---------------------------------------------------------------------------
__global__ __launch_bounds__(256) void k_convAll(
    const float* __restrict__ Wq, const float* __restrict__ Wk,
    const float* __restrict__ Wv, const float* __restrict__ Wg,
    const float* __restrict__ Wo, unsigned short* __restrict__ WT,
    unsigned short* __restrict__ WoT) {
  __shared__ float t[32][33];
  int idx = blockIdx.x;
  const float* src;
  unsigned short* out;
  int K, N, n_off, ldo;
  if (idx < 576) {               // Wq/Wk/Wv: [768][256], 192 tiles each
    int z = idx / 192;
    idx %= 192;
    src = (z == 0) ? Wq : (z == 1) ? Wk : Wv;
    out = WT; K = 768; N = 256; n_off = z * 256; ldo = 768;
  } else if (idx < 1152) {       // Wg: [768][768], 576 tiles
    idx -= 576;
    src = Wg; out = WT; K = 768; N = 768; n_off = 768; ldo = 768;
  } else {                       // Wo: [256][768], 192 tiles
    idx -= 1152;
    src = Wo; out = WoT; K = 256; N = 768; n_off = 0; ldo = 256;
  }
  int kt = idx % (K / 32), nt = idx / (K / 32);
  int k0 = kt * 32, n0 = nt * 32;
  const int tx = threadIdx.x, ty = threadIdx.y;
  for (int i = ty; i < 32; i += 8)
    t[i][tx] = src[(size_t)(k0 + i) * N + n0 + tx];
  __syncthreads();
  for (int i = ty; i < 32; i += 8)
    out[(size_t)(n_off + n0 + i) * ldo + k0 + tx] = f2bf(t[tx][i]);
}

// ---------------------------------------------------------------------------
// GEMM1: [QKVG] = x @ [Wq|Wk|Wv|Wg]^T.  M=8192, K=768, N=1536 (B^T input).
// Double-buffered LDS, prefetch-issue-first (T3 min-2ph), swizzled tiles,
// LDS-repack coalesced epilogue with fused activations.
// ---------------------------------------------------------------------------
__global__ __launch_bounds__(256) void k_gemm1(
    const unsigned short* __restrict__ xb, const unsigned short* __restrict__ WT,
    unsigned short* __restrict__ Q, unsigned short* __restrict__ K,
    unsigned short* __restrict__ V, unsigned short* __restrict__ G) {
  __shared__ __align__(16) char smem[65536];
  short* As0 = (short*)smem;
  short* As1 = (short*)(smem + 16384);
  short* Bs0 = (short*)(smem + 32768);
  short* Bs1 = (short*)(smem + 49152);
  const int tid = threadIdx.x;
  const int w = tid >> 6, l = tid & 63;
  const int lr = l & 15, lg = l >> 4;
  const int wr = w >> 1, wc = w & 1;
  int mt, nt;
  xcd_tile(blockIdx.x, mt, nt);
  const int m0 = mt * 128, n0 = nt * 128;
  const short* Ag = (const short*)xb + (size_t)m0 * DM;
  const short* Bg = (const short*)WT + (size_t)n0 * DM;

  f32x4 acc[4][4];
#pragma unroll
  for (int i = 0; i < 4; ++i)
#pragma unroll
    for (int j = 0; j < 4; ++j) acc[i][j] = (f32x4){0.f, 0.f, 0.f, 0.f};

  constexpr int NT = DM / 64;  // 12
  short *curA = As0, *curB = Bs0, *nxtA = As1, *nxtB = Bs1;
  stage2(Ag, DM, Bg, DM, 0, curA, curB, w, l);
  __syncthreads();
  for (int t = 0; t < NT; ++t) {
    if (t + 1 < NT) stage2(Ag, DM, Bg, DM, (t + 1) * 64, nxtA, nxtB, w, l);
    mma64(curA, curB, acc, wr, wc, lr, lg);
    __syncthreads();
    short* ta = curA; curA = nxtA; nxtA = ta;
    short* tb = curB; curB = nxtB; nxtB = tb;
  }

  // ---- epilogue: activation + repack through LDS, coalesced 16B stores ----
  const int ttype = (n0 < 512) ? 0 : (n0 < 768) ? 1 : 2;  // eluQK / V / G
  unsigned short* Cs = (unsigned short*)smem;              // 128x128 bf16
#pragma unroll
  for (int mi = 0; mi < 4; ++mi)
#pragma unroll
    for (int ni = 0; ni < 4; ++ni)
#pragma unroll
      for (int r = 0; r < 4; ++r) {
        float v = acc[mi][ni][r];
        if (ttype == 0) v = elu1(v);
        else if (ttype == 2) v = 1.f / (1.f + expf(-v));
        Cs[(wr * 64 + mi * 16 + lg * 4 + r) * 128 + wc * 64 + ni * 16 + lr] =
            f2bf(v);
      }
  __syncthreads();
  unsigned short* dst;
  int ldd, cb;
  if (n0 < 256)      { dst = Q; ldd = DIM; cb = n0; }
  else if (n0 < 512) { dst = K; ldd = DIM; cb = n0 - 256; }
  else if (n0 < 768) { dst = V; ldd = DIM; cb = n0 - 512; }
  else               { dst = G; ldd = DM;  cb = n0 - 768; }
  const uint4* Cv = (const uint4*)Cs;
#pragma unroll
  for (int i = 0; i < 8; ++i) {
    int idx = tid + i * 256;            // 2048 uint4 = 128x128 bf16
    int urow = idx >> 4, uc = idx & 15;
    *(uint4*)(dst + (size_t)(m0 + urow) * ldd + cb + uc * 8) = Cv[idx];
  }
}

// ---------------------------------------------------------------------------
// K2: per-chunk local sums (fp32 vector, bf16 inputs).
// ---------------------------------------------------------------------------
__global__ __launch_bounds__(256) void k_chunksum(
    const unsigned short* __restrict__ K, const unsigned short* __restrict__ V,
    float* __restrict__ Sc, float* __restrict__ zc) {
  __shared__ float Ks[CH][68];
  __shared__ float Vs[CH][68];
  const int c = blockIdx.x, h = blockIdx.y, b = blockIdx.z;
  const int tx = threadIdx.x, ty = threadIdx.y;
  const int tid = ty * 16 + tx;
  const int t0 = c * CH;
#pragma unroll
  for (int l = 0; l < 4; ++l) {
    int idx = tid + l * 256;
    int d4 = idx & 15, t = idx >> 4;
    size_t o = (size_t)(b * Tt + t0 + t) * DIM + h * Dd + d4 * 4;
    short4 k4 = *(const short4*)(K + o);
    short4 v4 = *(const short4*)(V + o);
    Ks[t][d4 * 4 + 0] = bf2f(k4.x); Ks[t][d4 * 4 + 1] = bf2f(k4.y);
    Ks[t][d4 * 4 + 2] = bf2f(k4.z); Ks[t][d4 * 4 + 3] = bf2f(k4.w);
    Vs[t][d4 * 4 + 0] = bf2f(v4.x); Vs[t][d4 * 4 + 1] = bf2f(v4.y);
    Vs[t][d4 * 4 + 2] = bf2f(v4.z); Vs[t][d4 * 4 + 3] = bf2f(v4.w);
  }
  __syncthreads();
  float acc[4][4] = {};
  for (int t = 0; t < CH; ++t) {
    float4 k4 = *(const float4*)&Ks[t][ty * 4];
    float4 v4 = *(const float4*)&Vs[t][tx * 4];
    float kv[4] = {k4.x, k4.y, k4.z, k4.w};
    float vv[4] = {v4.x, v4.y, v4.z, v4.w};
#pragma unroll
    for (int i = 0; i < 4; ++i)
#pragma unroll
      for (int j = 0; j < 4; ++j) acc[i][j] += kv[i] * vv[j];
  }
  const size_t base = ((size_t)(b * Hh + h) * NC + c) * (Dd * Dd);
#pragma unroll
  for (int i = 0; i < 4; ++i) {
    float4 s4 = make_float4(acc[i][0], acc[i][1], acc[i][2], acc[i][3]);
    *(float4*)&Sc[base + (size_t)(ty * 4 + i) * Dd + tx * 4] = s4;
  }
  if (tid < Dd) {
    float s = 0.f;
    for (int t = 0; t < CH; ++t) s += Ks[t][tid];
    zc[((size_t)(b * Hh + h) * NC + c) * Dd + tid] = s;
  }
}

// ---------------------------------------------------------------------------
// K3: exclusive prefix scan over chunks. grid (16 bh, 16 slices) x 256.
// ---------------------------------------------------------------------------
__global__ __launch_bounds__(256) void k_scan(float* __restrict__ Sc,
                                              float* __restrict__ zc) {
  const int bh = blockIdx.x;
  const int o = blockIdx.y * 256 + threadIdx.x;
  const size_t base = (size_t)bh * NC * (Dd * Dd) + o;
  float v[NC];
#pragma unroll
  for (int c = 0; c < NC; ++c) v[c] = Sc[base + (size_t)c * (Dd * Dd)];
  float run = 0.f;
#pragma unroll
  for (int c = 0; c < NC; ++c) {
    Sc[base + (size_t)c * (Dd * Dd)] = run;
    run += v[c];
  }
  if (blockIdx.y == 0 && threadIdx.x < Dd) {
    float rz = 0.f;
    for (int c = 0; c < NC; ++c) {
      size_t oz = ((size_t)bh * NC + c) * Dd + threadIdx.x;
      float cur = zc[oz];
      zc[oz] = rz;
      rz += cur;
    }
  }
}

// ---------------------------------------------------------------------------
// K4: per-chunk output (fp32 vector, bf16 in/out).
// ---------------------------------------------------------------------------
__global__ __launch_bounds__(256) void k_out(
    const unsigned short* __restrict__ Q, const unsigned short* __restrict__ K,
    const unsigned short* __restrict__ V, const float* __restrict__ Sc,
    const float* __restrict__ zc, unsigned short* __restrict__ O) {
  __shared__ float Qs[CH][68];
  __shared__ float KVs[CH * 68];
  __shared__ float As[CH][68];
  __shared__ float Ss[Dd][68];
  __shared__ float zs[Dd];
  __shared__ float dens[CH];
  const int c = blockIdx.x, h = blockIdx.y, b = blockIdx.z;
  const int tx = threadIdx.x, ty = threadIdx.y;
  const int tid = ty * 16 + tx;
  const int t0 = c * CH;

  // load Q [t][d]; K transposed [d][t] (pad 65)
#pragma unroll
  for (int l = 0; l < 4; ++l) {
    int idx = tid + l * 256;
    int d4 = idx & 15, t = idx >> 4;
    size_t o = (size_t)(b * Tt + t0 + t) * DIM + h * Dd + d4 * 4;
    short4 q4 = *(const short4*)(Q + o);
    short4 k4 = *(const short4*)(K + o);
    Qs[t][d4 * 4 + 0] = bf2f(q4.x); Qs[t][d4 * 4 + 1] = bf2f(q4.y);
    Qs[t][d4 * 4 + 2] = bf2f(q4.z); Qs[t][d4 * 4 + 3] = bf2f(q4.w);
    KVs[(d4 * 4 + 0) * 65 + t] = bf2f(k4.x);
    KVs[(d4 * 4 + 1) * 65 + t] = bf2f(k4.y);
    KVs[(d4 * 4 + 2) * 65 + t] = bf2f(k4.z);
    KVs[(d4 * 4 + 3) * 65 + t] = bf2f(k4.w);
  }
  __syncthreads();

  // A[i][j] = sum_d Q[i][d]*K[j][d], masked j<=i
  float acc[4][4] = {};
  for (int d0 = 0; d0 < Dd; d0 += 4) {
    float4 q4[4];
#pragma unroll
    for (int i = 0; i < 4; ++i) q4[i] = *(const float4*)&Qs[ty * 4 + i][d0];
#pragma unroll
    for (int dd = 0; dd < 4; ++dd) {
      int d = d0 + dd;
      float kv[4];
#pragma unroll
      for (int j = 0; j < 4; ++j) kv[j] = KVs[d * 65 + tx * 4 + j];
#pragma unroll
      for (int i = 0; i < 4; ++i) {
        float qv = ((const float*)&q4[i])[dd];
#pragma unroll
        for (int j = 0; j < 4; ++j) acc[i][j] += qv * kv[j];
      }
    }
  }
#pragma unroll
  for (int i = 0; i < 4; ++i)
#pragma unroll
    for (int j = 0; j < 4; ++j) {
      int ti = ty * 4 + i, sj = tx * 4 + j;
      As[ti][sj] = (sj <= ti) ? acc[i][j] : 0.f;
    }
  __syncthreads();

  // V into KVs row-major (pad 68); S_prev, z_prev
#pragma unroll
  for (int l = 0; l < 4; ++l) {
    int idx = tid + l * 256;
    int d4 = idx & 15, t = idx >> 4;
    size_t o = (size_t)(b * Tt + t0 + t) * DIM + h * Dd + d4 * 4;
    short4 v4 = *(const short4*)(V + o);
    KVs[t * 68 + d4 * 4 + 0] = bf2f(v4.x);
    KVs[t * 68 + d4 * 4 + 1] = bf2f(v4.y);
    KVs[t * 68 + d4 * 4 + 2] = bf2f(v4.z);
    KVs[t * 68 + d4 * 4 + 3] = bf2f(v4.w);
  }
  const size_t sbase = ((size_t)(b * Hh + h) * NC + c) * (Dd * Dd);
#pragma unroll
  for (int l = 0; l < 4; ++l) {
    int idx = tid + l * 256;
    int e4 = idx & 15, dd = idx >> 4;
    float4 s4 = *(const float4*)&Sc[sbase + (size_t)dd * Dd + e4 * 4];
    Ss[dd][e4 * 4 + 0] = s4.x; Ss[dd][e4 * 4 + 1] = s4.y;
    Ss[dd][e4 * 4 + 2] = s4.z; Ss[dd][e4 * 4 + 3] = s4.w;
  }
  if (tid < Dd) zs[tid] = zc[((size_t)(b * Hh + h) * NC + c) * Dd + tid];
  __syncthreads();

  if (tid < CH) {
    int i = tid;
    float rs = 0.f;
    for (int j = 0; j < CH; ++j) rs += As[i][j];
    float qz = 0.f;
    for (int d = 0; d < Dd; ++d) qz += Qs[i][d] * zs[d];
    dens[i] = fmaxf(rs + qz, 1e-6f);
  }
  float oacc[4][4] = {};
  for (int j = 0; j < CH; ++j) {
    float4 v4 = *(const float4*)&KVs[j * 68 + tx * 4];
    float vv[4] = {v4.x, v4.y, v4.z, v4.w};
    float av[4];
#pragma unroll
    for (int i = 0; i < 4; ++i) av[i] = As[ty * 4 + i][j];
#pragma unroll
    for (int i = 0; i < 4; ++i)
#pragma unroll
      for (int jj = 0; jj < 4; ++jj) oacc[i][jj] += av[i] * vv[jj];
  }
  for (int d = 0; d < Dd; ++d) {
    float4 s4 = *(const float4*)&Ss[d][tx * 4];
    float sv[4] = {s4.x, s4.y, s4.z, s4.w};
    float qv[4];
#pragma unroll
    for (int i = 0; i < 4; ++i) qv[i] = Qs[ty * 4 + i][d];
#pragma unroll
    for (int i = 0; i < 4; ++i)
#pragma unroll
      for (int jj = 0; jj < 4; ++jj) oacc[i][jj] += qv[i] * sv[jj];
  }
  __syncthreads();
#pragma unroll
  for (int i = 0; i < 4; ++i) {
    float inv = 1.f / dens[ty * 4 + i];
#pragma unroll
    for (int jj = 0; jj < 4; ++jj) {
      O[(size_t)(b * Tt + t0 + ty * 4 + i) * DIM + h * Dd + tx * 4 + jj] =
          f2bf(oacc[i][jj] * inv);
    }
  }
}

// ---------------------------------------------------------------------------
// GEMM2: out = (O @ Wo) * G.  M=8192, K=256, N=768.
// Double-buffered, swizzled; fp32 LDS-repack epilogue with gate multiply.
// ---------------------------------------------------------------------------
__global__ __launch_bounds__(256) void k_gemm2(
    const unsigned short* __restrict__ Ob, const unsigned short* __restrict__ WoT,
    const unsigned short* __restrict__ G, float* __restrict__ out) {
  __shared__ __align__(16) char smem[65536];
  short* As0 = (short*)smem;
  short* As1 = (short*)(smem + 16384);
  short* Bs0 = (short*)(smem + 32768);
  short* Bs1 = (short*)(smem + 49152);
  const int tid = threadIdx.x;
  const int w = tid >> 6, l = tid & 63;
  const int lr = l & 15, lg = l >> 4;
  const int wr = w >> 1, wc = w & 1;
  int mt, nt;
  xcd_tile(blockIdx.x, mt, nt);
  const int m0 = mt * 128, n0 = nt * 128;
  const short* Ag = (const short*)Ob + (size_t)m0 * DIM;
  const short* Bg = (const short*)WoT + (size_t)n0 * DIM;

  f32x4 acc[4][4];
#pragma unroll
  for (int i = 0; i < 4; ++i)
#pragma unroll
    for (int j = 0; j < 4; ++j) acc[i][j] = (f32x4){0.f, 0.f, 0.f, 0.f};

  constexpr int NT = DIM / 64;  // 4
  short *curA = As0, *curB = Bs0, *nxtA = As1, *nxtB = Bs1;
  stage2(Ag, DIM, Bg, DIM, 0, curA, curB, w, l);
  __syncthreads();
  for (int t = 0; t < NT; ++t) {
    if (t + 1 < NT) stage2(Ag, DIM, Bg, DIM, (t + 1) * 64, nxtA, nxtB, w, l);
    mma64(curA, curB, acc, wr, wc, lr, lg);
    __syncthreads();
    short* ta = curA; curA = nxtA; nxtA = ta;
    short* tb = curB; curB = nxtB; nxtB = tb;
  }

  // ---- epilogue: fp32 repack through LDS, gate multiply, 16B stores ----
  float* Cf = (float*)smem;  // 128x128 fp32 = 64KB
#pragma unroll
  for (int mi = 0; mi < 4; ++mi)
#pragma unroll
    for (int ni = 0; ni < 4; ++ni)
#pragma unroll
      for (int r = 0; r < 4; ++r)
        Cf[(wr * 64 + mi * 16 + lg * 4 + r) * 128 + wc * 64 + ni * 16 + lr] =
            acc[mi][ni][r];
  __syncthreads();
  const float4* Cv = (const float4*)Cf;
#pragma unroll
  for (int i = 0; i < 16; ++i) {
    int idx = tid + i * 256;            // 4096 float4 = 128x128 fp32
    int urow = idx >> 5, uc = idx & 31;
    float4 cv = Cv[idx];
    size_t go = (size_t)(m0 + urow) * DM + n0 + uc * 4;
    short4 g4 = *(const short4*)(G + go);
    float4 ov;
    ov.x = cv.x * bf2f(g4.x);
    ov.y = cv.y * bf2f(g4.y);
    ov.z = cv.z * bf2f(g4.z);
    ov.w = cv.w * bf2f(g4.w);
    *(float4*)(out + go) = ov;
  }
}

// ---------------------------------------------------------------------------
extern "C" void kernel_launch(void* const* d_in, const int* in_sizes, int n_in,
                              void* d_out, int out_size, void* d_ws,
                              size_t ws_size, hipStream_t stream) {
  const float* x  = (const float*)d_in[0];
  const float* Wq = (const float*)d_in[1];
  const float* Wk = (const float*)d_in[2];
  const float* Wv = (const float*)d_in[3];
  const float* Wo = (const float*)d_in[4];
  const float* Wg = (const float*)d_in[5];
  float* out = (float*)d_out;

  char* p = (char*)d_ws;
  size_t off = 0;
  auto alloc = [&](size_t bytes) {
    void* r = p + off;
    off = (off + bytes + 255) & ~(size_t)255;
    return r;
  };
  unsigned short* xb  = (unsigned short*)alloc((size_t)BT * DM * 2);
  unsigned short* WT  = (unsigned short*)alloc((size_t)NQKVG * DM * 2);
  unsigned short* WoT = (unsigned short*)alloc((size_t)DM * DIM * 2);
  unsigned short* Q   = (unsigned short*)alloc((size_t)BT * DIM * 2);
  unsigned short* Kf  = (unsigned short*)alloc((size_t)BT * DIM * 2);
  unsigned short* Vf  = (unsigned short*)alloc((size_t)BT * DIM * 2);
  unsigned short* G   = (unsigned short*)alloc((size_t)BT * DM * 2);
  unsigned short* Ob  = (unsigned short*)alloc((size_t)BT * DIM * 2);
  float* Sc = (float*)alloc((size_t)Bb * Hh * NC * Dd * Dd * 4);
  float* zc = (float*)alloc((size_t)Bb * Hh * NC * Dd * 4);

  // 1. input cast + all weight transposes (one launch each)
  k_cast<<<dim3((BT * DM / 8 + 255) / 256), dim3(256), 0, stream>>>(x, xb, BT * DM / 8);
  k_convAll<<<dim3(1344), dim3(32, 8), 0, stream>>>(Wq, Wk, Wv, Wg, Wo, WT, WoT);

  // 2. fused QKV + gate projection (MFMA), N=1536
  k_gemm1<<<dim3(MT * (NQKVG / 128)), dim3(256), 0, stream>>>(
      xb, WT, Q, Kf, Vf, G);

  // 3. chunked linear attention
  dim3 blk(16, 16);
  k_chunksum<<<dim3(NC, Hh, Bb), blk, 0, stream>>>(Kf, Vf, Sc, zc);
  k_scan<<<dim3(Bb * Hh, Dd * Dd / 256), dim3(256), 0, stream>>>(Sc, zc);
  k_out<<<dim3(NC, Hh, Bb), blk, 0, stream>>>(Q, Kf, Vf, Sc, zc, Ob);

  // 4. output GEMM * gate (MFMA)
  k_gemm2<<<dim3(MT * (DM / 128)), dim3(256), 0, stream>>>(Ob, WoT, G, out);
}

// Round 7
// 90.364 us; speedup vs baseline: 1.3171x; 1.0324x over previous
//
#include <hip/hip_runtime.h>
#include <math.h>

typedef __attribute__((ext_vector_type(8))) short bf16x8;
typedef __attribute__((ext_vector_type(4))) float f32x4;

namespace {
constexpr int Bb  = 4;
constexpr int Tt  = 2048;
constexpr int DM  = 768;
constexpr int Hh  = 4;
constexpr int Dd  = 64;
constexpr int DIM = 256;          // H*D
constexpr int BT  = Bb * Tt;      // 8192
constexpr int CH  = 64;           // chunk length
constexpr int NC  = Tt / CH;      // 32 chunks
constexpr int NQKVG = 1536;       // QKV (768) + gate (768) output cols
constexpr int MT  = BT / 128;     // 64 m-tiles
}

__device__ __forceinline__ float elu1(float x) { return x > 0.f ? x + 1.f : expf(x); }

// fp32 -> bf16, round-to-nearest-even
__device__ __forceinline__ unsigned short f2bf(float f) {
  unsigned int x = __float_as_uint(f);
  unsigned int r = (x + 0x7fffu + ((x >> 16) & 1u)) >> 16;
  return (unsigned short)r;
}
__device__ __forceinline__ float bf2f(unsigned short u) {
  return __uint_as_float((unsigned int)u << 16);
}

__device__ __forceinline__ void gload16(const void* g, void* l) {
  __builtin_amdgcn_global_load_lds(
      (const __attribute__((address_space(1))) void*)g,
      (__attribute__((address_space(3))) void*)l, 16, 0, 0);
}

// Stage a 128x64 A-tile and B-tile (bf16 row-major) into LDS buffers with the
// XOR source-swizzle (T2, rule #21): LDS dest linear, fetched 16B-column
// permuted c16' = (l&7)^(l>>3); readers XOR their 16B slot with (row&7).
// Issues 8 global_load_lds per lane (counted for vmcnt pipelining).
__device__ __forceinline__ void stage2(const short* __restrict__ Ag, size_t lda,
                                       const short* __restrict__ Bg, size_t ldb,
                                       int k0, short* as, short* bs, int w, int l) {
  const int c16 = (l & 7) ^ (l >> 3);
#pragma unroll
  for (int i = 0; i < 4; ++i) {
    int seg = w * 4 + i;
    int row = seg * 8 + (l >> 3);
    gload16(Ag + (size_t)row * lda + k0 + c16 * 8, (char*)as + seg * 1024);
    gload16(Bg + (size_t)row * ldb + k0 + c16 * 8, (char*)bs + seg * 1024);
  }
}

// one 128x128x64 MFMA step from swizzled LDS tiles
__device__ __forceinline__ void mma64(const short* as, const short* bs,
                                      f32x4 (&acc)[4][4],
                                      int wr, int wc, int lr, int lg) {
  const int sa = lr & 7;
#pragma unroll
  for (int ks = 0; ks < 2; ++ks) {
    bf16x8 af[4], bf[4];
#pragma unroll
    for (int mi = 0; mi < 4; ++mi)
      af[mi] = *(const bf16x8*)&as[(wr * 64 + mi * 16 + lr) * 64 +
                                   ((ks * 4 + lg) ^ sa) * 8];
#pragma unroll
    for (int ni = 0; ni < 4; ++ni)
      bf[ni] = *(const bf16x8*)&bs[(wc * 64 + ni * 16 + lr) * 64 +
                                   ((ks * 4 + lg) ^ sa) * 8];
#pragma unroll
    for (int mi = 0; mi < 4; ++mi)
#pragma unroll
      for (int ni = 0; ni < 4; ++ni)
        acc[mi][ni] = __builtin_amdgcn_mfma_f32_16x16x32_bf16(
            af[mi], bf[ni], acc[mi][ni], 0, 0, 0);
  }
}

// L2-resident tiling: each XCD (bid&7) owns 8 contiguous m-tiles.
__device__ __forceinline__ void xcd_tile(int bid, int& mt, int& nt) {
  int xcd = bid & 7;
  int idx = bid >> 3;
  mt = xcd * 8 + (idx & 7);
  nt = idx >> 3;
}

// counted-vmcnt pipelined K-loop (T4): tile t's 8 loads done, t+1's stay
// in flight; raw s_barrier (no compiler vmcnt(0) drain).
template <int NT>
__device__ __forceinline__ void kloop(const short* Ag, size_t lda,
                                      const short* Bg, size_t ldb,
                                      short* As0, short* As1, short* Bs0,
                                      short* Bs1, f32x4 (&acc)[4][4], int w,
                                      int l, int wr, int wc, int lr, int lg) {
  stage2(Ag, lda, Bg, ldb, 0, As0, Bs0, w, l);
  stage2(Ag, lda, Bg, ldb, 64, As1, Bs1, w, l);
#pragma unroll
  for (int t = 0; t < NT; ++t) {
    short* as = (t & 1) ? As1 : As0;
    short* bs = (t & 1) ? Bs1 : Bs0;
    if (t + 1 < NT)
      asm volatile("s_waitcnt vmcnt(8)" ::: "memory");
    else
      asm volatile("s_waitcnt vmcnt(0)" ::: "memory");
    __builtin_amdgcn_s_barrier();
    __builtin_amdgcn_sched_barrier(0);
    mma64(as, bs, acc, wr, wc, lr, lg);
    __builtin_amdgcn_sched_barrier(0);
    __builtin_amdgcn_s_barrier();
    if (t + 2 < NT) stage2(Ag, lda, Bg, ldb, (t + 2) * 64, as, bs, w, l);
  }
}

// ---------------------------------------------------------------------------
// cast fp32 -> bf16, 8 elements/thread
// ---------------------------------------------------------------------------
__global__ __launch_bounds__(256) void k_cast(const float* __restrict__ in,
                                              unsigned short* __restrict__ out,
                                              int n8) {
  int i = blockIdx.x * 256 + threadIdx.x;
  if (i >= n8) return;
  const float4* p = (const float4*)(in + (size_t)i * 8);
  float4 a = p[0], b = p[1];
  union { unsigned short u[8]; uint4 v; } r;
  r.u[0] = f2bf(a.x); r.u[1] = f2bf(a.y); r.u[2] = f2bf(a.z); r.u[3] = f2bf(a.w);
  r.u[4] = f2bf(b.x); r.u[5] = f2bf(b.y); r.u[6] = f2bf(b.z); r.u[7] = f2bf(b.w);
  *(uint4*)(out + (size_t)i * 8) = r.v;
}

// ---------------------------------------------------------------------------
// all weight transposes in ONE launch.
// WT rows: [0,256)=Wq^T [256,512)=Wk^T [512,768)=Wv^T [768,1536)=Wg^T, ld=768
// WoT: Wo^T [768][256], ld=256
// ---------------------------------------------------------------------------
__global__ __launch_bounds__(256) void k_convAll(
    const float* __restrict__ Wq, const float* __restrict__ Wk,
    const float* __restrict__ Wv, const float* __restrict__ Wg,
    const float* __restrict__ Wo, unsigned short* __restrict__ WT,
    unsigned short* __restrict__ WoT) {
  __shared__ float t[32][33];
  int idx = blockIdx.x;
  const float* src;
  unsigned short* out;
  int K, N, n_off, ldo;
  if (idx < 576) {               // Wq/Wk/Wv: [768][256], 192 tiles each
    int z = idx / 192;
    idx %= 192;
    src = (z == 0) ? Wq : (z == 1) ? Wk : Wv;
    out = WT; K = 768; N = 256; n_off = z * 256; ldo = 768;
  } else if (idx < 1152) {       // Wg: [768][768], 576 tiles
    idx -= 576;
    src = Wg; out = WT; K = 768; N = 768; n_off = 768; ldo = 768;
  } else {                       // Wo: [256][768], 192 tiles
    idx -= 1152;
    src = Wo; out = WoT; K = 256; N = 768; n_off = 0; ldo = 256;
  }
  int kt = idx % (K / 32), nt = idx / (K / 32);
  int k0 = kt * 32, n0 = nt * 32;
  const int tx = threadIdx.x, ty = threadIdx.y;
  for (int i = ty; i < 32; i += 8)
    t[i][tx] = src[(size_t)(k0 + i) * N + n0 + tx];
  __syncthreads();
  for (int i = ty; i < 32; i += 8)
    out[(size_t)(n_off + n0 + i) * ldo + k0 + tx] = f2bf(t[tx][i]);
}

// ---------------------------------------------------------------------------
// GEMM1: [QKVG] = x @ [Wq|Wk|Wv|Wg]^T.  M=8192, K=768, N=1536 (B^T input).
// Counted-vmcnt double-buffered pipeline, swizzled tiles, LDS-repack epilogue.
// ---------------------------------------------------------------------------
__global__ __launch_bounds__(256) void k_gemm1(
    const unsigned short* __restrict__ xb, const unsigned short* __restrict__ WT,
    unsigned short* __restrict__ Q, unsigned short* __restrict__ K,
    unsigned short* __restrict__ V, unsigned short* __restrict__ G) {
  __shared__ __align__(16) char smem[65536];
  short* As0 = (short*)smem;
  short* As1 = (short*)(smem + 16384);
  short* Bs0 = (short*)(smem + 32768);
  short* Bs1 = (short*)(smem + 49152);
  const int tid = threadIdx.x;
  const int w = tid >> 6, l = tid & 63;
  const int lr = l & 15, lg = l >> 4;
  const int wr = w >> 1, wc = w & 1;
  int mt, nt;
  xcd_tile(blockIdx.x, mt, nt);
  const int m0 = mt * 128, n0 = nt * 128;
  const short* Ag = (const short*)xb + (size_t)m0 * DM;
  const short* Bg = (const short*)WT + (size_t)n0 * DM;

  f32x4 acc[4][4];
#pragma unroll
  for (int i = 0; i < 4; ++i)
#pragma unroll
    for (int j = 0; j < 4; ++j) acc[i][j] = (f32x4){0.f, 0.f, 0.f, 0.f};

  kloop<DM / 64>(Ag, DM, Bg, DM, As0, As1, Bs0, Bs1, acc, w, l, wr, wc, lr, lg);
  __syncthreads();

  // ---- epilogue: activation + repack through LDS, coalesced 16B stores ----
  const int ttype = (n0 < 512) ? 0 : (n0 < 768) ? 1 : 2;  // eluQK / V / G
  unsigned short* Cs = (unsigned short*)smem;              // 128x128 bf16
#pragma unroll
  for (int mi = 0; mi < 4; ++mi)
#pragma unroll
    for (int ni = 0; ni < 4; ++ni)
#pragma unroll
      for (int r = 0; r < 4; ++r) {
        float v = acc[mi][ni][r];
        if (ttype == 0) v = elu1(v);
        else if (ttype == 2) v = 1.f / (1.f + expf(-v));
        Cs[(wr * 64 + mi * 16 + lg * 4 + r) * 128 + wc * 64 + ni * 16 + lr] =
            f2bf(v);
      }
  __syncthreads();
  unsigned short* dst;
  int ldd, cb;
  if (n0 < 256)      { dst = Q; ldd = DIM; cb = n0; }
  else if (n0 < 512) { dst = K; ldd = DIM; cb = n0 - 256; }
  else if (n0 < 768) { dst = V; ldd = DIM; cb = n0 - 512; }
  else               { dst = G; ldd = DM;  cb = n0 - 768; }
  const uint4* Cv = (const uint4*)Cs;
#pragma unroll
  for (int i = 0; i < 8; ++i) {
    int idx = tid + i * 256;            // 2048 uint4 = 128x128 bf16
    int urow = idx >> 4, uc = idx & 15;
    *(uint4*)(dst + (size_t)(m0 + urow) * ldd + cb + uc * 8) = Cv[idx];
  }
}

// ---------------------------------------------------------------------------
// K2: per-chunk local sums (fp32 vector, bf16 inputs).
// ---------------------------------------------------------------------------
__global__ __launch_bounds__(256) void k_chunksum(
    const unsigned short* __restrict__ K, const unsigned short* __restrict__ V,
    float* __restrict__ Sc, float* __restrict__ zc) {
  __shared__ float Ks[CH][68];
  __shared__ float Vs[CH][68];
  const int c = blockIdx.x, h = blockIdx.y, b = blockIdx.z;
  const int tx = threadIdx.x, ty = threadIdx.y;
  const int tid = ty * 16 + tx;
  const int t0 = c * CH;
#pragma unroll
  for (int l = 0; l < 4; ++l) {
    int idx = tid + l * 256;
    int d4 = idx & 15, t = idx >> 4;
    size_t o = (size_t)(b * Tt + t0 + t) * DIM + h * Dd + d4 * 4;
    short4 k4 = *(const short4*)(K + o);
    short4 v4 = *(const short4*)(V + o);
    Ks[t][d4 * 4 + 0] = bf2f(k4.x); Ks[t][d4 * 4 + 1] = bf2f(k4.y);
    Ks[t][d4 * 4 + 2] = bf2f(k4.z); Ks[t][d4 * 4 + 3] = bf2f(k4.w);
    Vs[t][d4 * 4 + 0] = bf2f(v4.x); Vs[t][d4 * 4 + 1] = bf2f(v4.y);
    Vs[t][d4 * 4 + 2] = bf2f(v4.z); Vs[t][d4 * 4 + 3] = bf2f(v4.w);
  }
  __syncthreads();
  float acc[4][4] = {};
  for (int t = 0; t < CH; ++t) {
    float4 k4 = *(const float4*)&Ks[t][ty * 4];
    float4 v4 = *(const float4*)&Vs[t][tx * 4];
    float kv[4] = {k4.x, k4.y, k4.z, k4.w};
    float vv[4] = {v4.x, v4.y, v4.z, v4.w};
#pragma unroll
    for (int i = 0; i < 4; ++i)
#pragma unroll
      for (int j = 0; j < 4; ++j) acc[i][j] += kv[i] * vv[j];
  }
  const size_t base = ((size_t)(b * Hh + h) * NC + c) * (Dd * Dd);
#pragma unroll
  for (int i = 0; i < 4; ++i) {
    float4 s4 = make_float4(acc[i][0], acc[i][1], acc[i][2], acc[i][3]);
    *(float4*)&Sc[base + (size_t)(ty * 4 + i) * Dd + tx * 4] = s4;
  }
  if (tid < Dd) {
    float s = 0.f;
    for (int t = 0; t < CH; ++t) s += Ks[t][tid];
    zc[((size_t)(b * Hh + h) * NC + c) * Dd + tid] = s;
  }
}

// ---------------------------------------------------------------------------
// K3: exclusive prefix scan over chunks. grid (16 bh, 16 slices) x 256.
// ---------------------------------------------------------------------------
__global__ __launch_bounds__(256) void k_scan(float* __restrict__ Sc,
                                              float* __restrict__ zc) {
  const int bh = blockIdx.x;
  const int o = blockIdx.y * 256 + threadIdx.x;
  const size_t base = (size_t)bh * NC * (Dd * Dd) + o;
  float v[NC];
#pragma unroll
  for (int c = 0; c < NC; ++c) v[c] = Sc[base + (size_t)c * (Dd * Dd)];
  float run = 0.f;
#pragma unroll
  for (int c = 0; c < NC; ++c) {
    Sc[base + (size_t)c * (Dd * Dd)] = run;
    run += v[c];
  }
  if (blockIdx.y == 0 && threadIdx.x < Dd) {
    float rz = 0.f;
    for (int c = 0; c < NC; ++c) {
      size_t oz = ((size_t)bh * NC + c) * Dd + threadIdx.x;
      float cur = zc[oz];
      zc[oz] = rz;
      rz += cur;
    }
  }
}

// ---------------------------------------------------------------------------
// K4: per-chunk output (fp32 vector, bf16 in/out).
// ---------------------------------------------------------------------------
__global__ __launch_bounds__(256) void k_out(
    const unsigned short* __restrict__ Q, const unsigned short* __restrict__ K,
    const unsigned short* __restrict__ V, const float* __restrict__ Sc,
    const float* __restrict__ zc, unsigned short* __restrict__ O) {
  __shared__ float Qs[CH][68];
  __shared__ float KVs[CH * 68];
  __shared__ float As[CH][68];
  __shared__ float Ss[Dd][68];
  __shared__ float zs[Dd];
  __shared__ float dens[CH];
  const int c = blockIdx.x, h = blockIdx.y, b = blockIdx.z;
  const int tx = threadIdx.x, ty = threadIdx.y;
  const int tid = ty * 16 + tx;
  const int t0 = c * CH;

  // load Q [t][d]; K transposed [d][t] (pad 65)
#pragma unroll
  for (int l = 0; l < 4; ++l) {
    int idx = tid + l * 256;
    int d4 = idx & 15, t = idx >> 4;
    size_t o = (size_t)(b * Tt + t0 + t) * DIM + h * Dd + d4 * 4;
    short4 q4 = *(const short4*)(Q + o);
    short4 k4 = *(const short4*)(K + o);
    Qs[t][d4 * 4 + 0] = bf2f(q4.x); Qs[t][d4 * 4 + 1] = bf2f(q4.y);
    Qs[t][d4 * 4 + 2] = bf2f(q4.z); Qs[t][d4 * 4 + 3] = bf2f(q4.w);
    KVs[(d4 * 4 + 0) * 65 + t] = bf2f(k4.x);
    KVs[(d4 * 4 + 1) * 65 + t] = bf2f(k4.y);
    KVs[(d4 * 4 + 2) * 65 + t] = bf2f(k4.z);
    KVs[(d4 * 4 + 3) * 65 + t] = bf2f(k4.w);
  }
  __syncthreads();

  // A[i][j] = sum_d Q[i][d]*K[j][d], masked j<=i
  float acc[4][4] = {};
  for (int d0 = 0; d0 < Dd; d0 += 4) {
    float4 q4[4];
#pragma unroll
    for (int i = 0; i < 4; ++i) q4[i] = *(const float4*)&Qs[ty * 4 + i][d0];
#pragma unroll
    for (int dd = 0; dd < 4; ++dd) {
      int d = d0 + dd;
      float kv[4];
#pragma unroll
      for (int j = 0; j < 4; ++j) kv[j] = KVs[d * 65 + tx * 4 + j];
#pragma unroll
      for (int i = 0; i < 4; ++i) {
        float qv = ((const float*)&q4[i])[dd];
#pragma unroll
        for (int j = 0; j < 4; ++j) acc[i][j] += qv * kv[j];
      }
    }
  }
#pragma unroll
  for (int i = 0; i < 4; ++i)
#pragma unroll
    for (int j = 0; j < 4; ++j) {
      int ti = ty * 4 + i, sj = tx * 4 + j;
      As[ti][sj] = (sj <= ti) ? acc[i][j] : 0.f;
    }
  __syncthreads();

  // V into KVs row-major (pad 68); S_prev, z_prev
#pragma unroll
  for (int l = 0; l < 4; ++l) {
    int idx = tid + l * 256;
    int d4 = idx & 15, t = idx >> 4;
    size_t o = (size_t)(b * Tt + t0 + t) * DIM + h * Dd + d4 * 4;
    short4 v4 = *(const short4*)(V + o);
    KVs[t * 68 + d4 * 4 + 0] = bf2f(v4.x);
    KVs[t * 68 + d4 * 4 + 1] = bf2f(v4.y);
    KVs[t * 68 + d4 * 4 + 2] = bf2f(v4.z);
    KVs[t * 68 + d4 * 4 + 3] = bf2f(v4.w);
  }
  const size_t sbase = ((size_t)(b * Hh + h) * NC + c) * (Dd * Dd);
#pragma unroll
  for (int l = 0; l < 4; ++l) {
    int idx = tid + l * 256;
    int e4 = idx & 15, dd = idx >> 4;
    float4 s4 = *(const float4*)&Sc[sbase + (size_t)dd * Dd + e4 * 4];
    Ss[dd][e4 * 4 + 0] = s4.x; Ss[dd][e4 * 4 + 1] = s4.y;
    Ss[dd][e4 * 4 + 2] = s4.z; Ss[dd][e4 * 4 + 3] = s4.w;
  }
  if (tid < Dd) zs[tid] = zc[((size_t)(b * Hh + h) * NC + c) * Dd + tid];
  __syncthreads();

  if (tid < CH) {
    int i = tid;
    float rs = 0.f;
    for (int j = 0; j < CH; ++j) rs += As[i][j];
    float qz = 0.f;
    for (int d = 0; d < Dd; ++d) qz += Qs[i][d] * zs[d];
    dens[i] = fmaxf(rs + qz, 1e-6f);
  }
  float oacc[4][4] = {};
  for (int j = 0; j < CH; ++j) {
    float4 v4 = *(const float4*)&KVs[j * 68 + tx * 4];
    float vv[4] = {v4.x, v4.y, v4.z, v4.w};
    float av[4];
#pragma unroll
    for (int i = 0; i < 4; ++i) av[i] = As[ty * 4 + i][j];
#pragma unroll
    for (int i = 0; i < 4; ++i)
#pragma unroll
      for (int jj = 0; jj < 4; ++jj) oacc[i][jj] += av[i] * vv[jj];
  }
  for (int d = 0; d < Dd; ++d) {
    float4 s4 = *(const float4*)&Ss[d][tx * 4];
    float sv[4] = {s4.x, s4.y, s4.z, s4.w};
    float qv[4];
#pragma unroll
    for (int i = 0; i < 4; ++i) qv[i] = Qs[ty * 4 + i][d];
#pragma unroll
    for (int i = 0; i < 4; ++i)
#pragma unroll
      for (int jj = 0; jj < 4; ++jj) oacc[i][jj] += qv[i] * sv[jj];
  }
  __syncthreads();
#pragma unroll
  for (int i = 0; i < 4; ++i) {
    float inv = 1.f / dens[ty * 4 + i];
#pragma unroll
    for (int jj = 0; jj < 4; ++jj) {
      O[(size_t)(b * Tt + t0 + ty * 4 + i) * DIM + h * Dd + tx * 4 + jj] =
          f2bf(oacc[i][jj] * inv);
    }
  }
}

// ---------------------------------------------------------------------------
// GEMM2: out = (O @ Wo) * G.  M=8192, K=256, N=768.
// Counted-vmcnt pipeline; fp32 LDS-repack epilogue with gate multiply.
// ---------------------------------------------------------------------------
__global__ __launch_bounds__(256) void k_gemm2(
    const unsigned short* __restrict__ Ob, const unsigned short* __restrict__ WoT,
    const unsigned short* __restrict__ G, float* __restrict__ out) {
  __shared__ __align__(16) char smem[65536];
  short* As0 = (short*)smem;
  short* As1 = (short*)(smem + 16384);
  short* Bs0 = (short*)(smem + 32768);
  short* Bs1 = (short*)(smem + 49152);
  const int tid = threadIdx.x;
  const int w = tid >> 6, l = tid & 63;
  const int lr = l & 15, lg = l >> 4;
  const int wr = w >> 1, wc = w & 1;
  int mt, nt;
  xcd_tile(blockIdx.x, mt, nt);
  const int m0 = mt * 128, n0 = nt * 128;
  const short* Ag = (const short*)Ob + (size_t)m0 * DIM;
  const short* Bg = (const short*)WoT + (size_t)n0 * DIM;

  f32x4 acc[4][4];
#pragma unroll
  for (int i = 0; i < 4; ++i)
#pragma unroll
    for (int j = 0; j < 4; ++j) acc[i][j] = (f32x4){0.f, 0.f, 0.f, 0.f};

  kloop<DIM / 64>(Ag, DIM, Bg, DIM, As0, As1, Bs0, Bs1, acc, w, l, wr, wc, lr, lg);
  __syncthreads();

  // ---- epilogue: fp32 repack through LDS, gate multiply, 16B stores ----
  float* Cf = (float*)smem;  // 128x128 fp32 = 64KB
#pragma unroll
  for (int mi = 0; mi < 4; ++mi)
#pragma unroll
    for (int ni = 0; ni < 4; ++ni)
#pragma unroll
      for (int r = 0; r < 4; ++r)
        Cf[(wr * 64 + mi * 16 + lg * 4 + r) * 128 + wc * 64 + ni * 16 + lr] =
            acc[mi][ni][r];
  __syncthreads();
  const float4* Cv = (const float4*)Cf;
#pragma unroll
  for (int i = 0; i < 16; ++i) {
    int idx = tid + i * 256;            // 4096 float4 = 128x128 fp32
    int urow = idx >> 5, uc = idx & 31;
    float4 cv = Cv[idx];
    size_t go = (size_t)(m0 + urow) * DM + n0 + uc * 4;
    short4 g4 = *(const short4*)(G + go);
    float4 ov;
    ov.x = cv.x * bf2f(g4.x);
    ov.y = cv.y * bf2f(g4.y);
    ov.z = cv.z * bf2f(g4.z);
    ov.w = cv.w * bf2f(g4.w);
    *(float4*)(out + go) = ov;
  }
}

// ---------------------------------------------------------------------------
extern "C" void kernel_launch(void* const* d_in, const int* in_sizes, int n_in,
                              void* d_out, int out_size, void* d_ws,
                              size_t ws_size, hipStream_t stream) {
  const float* x  = (const float*)d_in[0];
  const float* Wq = (const float*)d_in[1];
  const float* Wk = (const float*)d_in[2];
  const float* Wv = (const float*)d_in[3];
  const float* Wo = (const float*)d_in[4];
  const float* Wg = (const float*)d_in[5];
  float* out = (float*)d_out;

  char* p = (char*)d_ws;
  size_t off = 0;
  auto alloc = [&](size_t bytes) {
    void* r = p + off;
    off = (off + bytes + 255) & ~(size_t)255;
    return r;
  };
  unsigned short* xb  = (unsigned short*)alloc((size_t)BT * DM * 2);
  unsigned short* WT  = (unsigned short*)alloc((size_t)NQKVG * DM * 2);
  unsigned short* WoT = (unsigned short*)alloc((size_t)DM * DIM * 2);
  unsigned short* Q   = (unsigned short*)alloc((size_t)BT * DIM * 2);
  unsigned short* Kf  = (unsigned short*)alloc((size_t)BT * DIM * 2);
  unsigned short* Vf  = (unsigned short*)alloc((size_t)BT * DIM * 2);
  unsigned short* G   = (unsigned short*)alloc((size_t)BT * DM * 2);
  unsigned short* Ob  = (unsigned short*)alloc((size_t)BT * DIM * 2);
  float* Sc = (float*)alloc((size_t)Bb * Hh * NC * Dd * Dd * 4);
  float* zc = (float*)alloc((size_t)Bb * Hh * NC * Dd * 4);

  // 1. input cast + all weight transposes (one launch each)
  k_cast<<<dim3((BT * DM / 8 + 255) / 256), dim3(256), 0, stream>>>(x, xb, BT * DM / 8);
  k_convAll<<<dim3(1344), dim3(32, 8), 0, stream>>>(Wq, Wk, Wv, Wg, Wo, WT, WoT);

  // 2. fused QKV + gate projection (MFMA), N=1536
  k_gemm1<<<dim3(MT * (NQKVG / 128)), dim3(256), 0, stream>>>(
      xb, WT, Q, Kf, Vf, G);

  // 3. chunked linear attention
  dim3 blk(16, 16);
  k_chunksum<<<dim3(NC, Hh, Bb), blk, 0, stream>>>(Kf, Vf, Sc, zc);
  k_scan<<<dim3(Bb * Hh, Dd * Dd / 256), dim3(256), 0, stream>>>(Sc, zc);
  k_out<<<dim3(NC, Hh, Bb), blk, 0, stream>>>(Q, Kf, Vf, Sc, zc, Ob);

  // 4. output GEMM * gate (MFMA)
  k_gemm2<<<dim3(MT * (DM / 128)), dim3(256), 0, stream>>>(Ob, WoT, G, out);
}

// Round 8
// 86.806 us; speedup vs baseline: 1.3711x; 1.0410x over previous
//
#include <hip/hip_runtime.h>
#include <math.h>

typedef __attribute__((ext_vector_type(8))) short bf16x8;
typedef __attribute__((ext_vector_type(4))) float f32x4;

namespace {
constexpr int Bb  = 4;
constexpr int Tt  = 2048;
constexpr int DM  = 768;
constexpr int Hh  = 4;
constexpr int Dd  = 64;
constexpr int DIM = 256;          // H*D
constexpr int BT  = Bb * Tt;      // 8192
constexpr int CH  = 64;           // chunk length
constexpr int NC  = Tt / CH;      // 32 chunks
constexpr int NQKVG = 1536;       // QKV (768) + gate (768) output cols
constexpr int MT  = BT / 128;     // 64 m-tiles
}

__device__ __forceinline__ float elu1(float x) { return x > 0.f ? x + 1.f : expf(x); }

// fp32 -> bf16, round-to-nearest-even
__device__ __forceinline__ unsigned short f2bf(float f) {
  unsigned int x = __float_as_uint(f);
  unsigned int r = (x + 0x7fffu + ((x >> 16) & 1u)) >> 16;
  return (unsigned short)r;
}
__device__ __forceinline__ float bf2f(unsigned short u) {
  return __uint_as_float((unsigned int)u << 16);
}

__device__ __forceinline__ void gload16(const void* g, void* l) {
  __builtin_amdgcn_global_load_lds(
      (const __attribute__((address_space(1))) void*)g,
      (__attribute__((address_space(3))) void*)l, 16, 0, 0);
}

// Per-lane hoisted staging pointers (XOR source-swizzle, T2 rule #21):
// LDS dest linear; fetched 16B-column permuted c16' = (l&7)^(l>>3).
// Readers XOR their 16B slot with (row&7).
struct Stage {
  const short* a[4];
  const short* b[4];
  int seg;
  __device__ __forceinline__ void init(const short* Ag, size_t lda,
                                       const short* Bg, size_t ldb, int w, int l) {
    const int c16 = (l & 7) ^ (l >> 3);
    seg = w * 4;
#pragma unroll
    for (int i = 0; i < 4; ++i) {
      int row = (seg + i) * 8 + (l >> 3);
      a[i] = Ag + (size_t)row * lda + c16 * 8;
      b[i] = Bg + (size_t)row * ldb + c16 * 8;
    }
  }
  // 8 global_load_lds (counted for vmcnt pipelining)
  __device__ __forceinline__ void issue(int k0, short* as, short* bs) const {
#pragma unroll
    for (int i = 0; i < 4; ++i) {
      gload16(a[i] + k0, (char*)as + (seg + i) * 1024);
      gload16(b[i] + k0, (char*)bs + (seg + i) * 1024);
    }
  }
};

// L2-resident tiling: each XCD (bid&7) owns 8 contiguous m-tiles.
__device__ __forceinline__ void xcd_tile(int bid, int& mt, int& nt) {
  int xcd = bid & 7;
  int idx = bid >> 3;
  mt = xcd * 8 + (idx & 7);
  nt = idx >> 3;
}

// Interleaved counted-vmcnt K-loop:
//   vmcnt(8) -> barrier -> frag reads -> lgkm0 -> barrier ->
//   stage-issue (overlaps) -> setprio(1) MFMA setprio(0)
template <int NT>
__device__ __forceinline__ void kloop(const Stage& st, short* As0, short* As1,
                                      short* Bs0, short* Bs1,
                                      f32x4 (&acc)[4][4], int wr, int wc,
                                      int lr, int lg) {
  const int sa = lr & 7;
  st.issue(0, As0, Bs0);
  st.issue(64, As1, Bs1);
#pragma unroll
  for (int t = 0; t < NT; ++t) {
    short* as = (t & 1) ? As1 : As0;
    short* bs = (t & 1) ? Bs1 : Bs0;
    if (t + 1 < NT)
      asm volatile("s_waitcnt vmcnt(8)" ::: "memory");
    else
      asm volatile("s_waitcnt vmcnt(0)" ::: "memory");
    __builtin_amdgcn_s_barrier();
    bf16x8 af[2][4], bf[2][4];
#pragma unroll
    for (int ks = 0; ks < 2; ++ks) {
#pragma unroll
      for (int mi = 0; mi < 4; ++mi)
        af[ks][mi] = *(const bf16x8*)&as[(wr * 64 + mi * 16 + lr) * 64 +
                                         ((ks * 4 + lg) ^ sa) * 8];
#pragma unroll
      for (int ni = 0; ni < 4; ++ni)
        bf[ks][ni] = *(const bf16x8*)&bs[(wc * 64 + ni * 16 + lr) * 64 +
                                         ((ks * 4 + lg) ^ sa) * 8];
    }
    asm volatile("s_waitcnt lgkmcnt(0)" ::: "memory");
    __builtin_amdgcn_sched_barrier(0);
    __builtin_amdgcn_s_barrier();
    if (t + 2 < NT) st.issue((t + 2) * 64, as, bs);  // just-freed buffer
    __builtin_amdgcn_s_setprio(1);
#pragma unroll
    for (int ks = 0; ks < 2; ++ks)
#pragma unroll
      for (int mi = 0; mi < 4; ++mi)
#pragma unroll
        for (int ni = 0; ni < 4; ++ni)
          acc[mi][ni] = __builtin_amdgcn_mfma_f32_16x16x32_bf16(
              af[ks][mi], bf[ks][ni], acc[mi][ni], 0, 0, 0);
    __builtin_amdgcn_s_setprio(0);
  }
}

// ---------------------------------------------------------------------------
// k_prep: fused input cast (blocks [0,3072)) + weight transposes [3072,4416).
// WT rows: [0,256)=Wq^T [256,512)=Wk^T [512,768)=Wv^T [768,1536)=Wg^T, ld=768
// WoT: Wo^T [768][256], ld=256
// ---------------------------------------------------------------------------
__global__ __launch_bounds__(256) void k_prep(
    const float* __restrict__ x, const float* __restrict__ Wq,
    const float* __restrict__ Wk, const float* __restrict__ Wv,
    const float* __restrict__ Wg, const float* __restrict__ Wo,
    unsigned short* __restrict__ xb, unsigned short* __restrict__ WT,
    unsigned short* __restrict__ WoT) {
  int bid = blockIdx.x;
  if (bid < 3072) {  // cast: 8 elements/thread, 786432 total
    int i = bid * 256 + threadIdx.x;
    const float4* p = (const float4*)(x + (size_t)i * 8);
    float4 a = p[0], b = p[1];
    union { unsigned short u[8]; uint4 v; } r;
    r.u[0] = f2bf(a.x); r.u[1] = f2bf(a.y); r.u[2] = f2bf(a.z); r.u[3] = f2bf(a.w);
    r.u[4] = f2bf(b.x); r.u[5] = f2bf(b.y); r.u[6] = f2bf(b.z); r.u[7] = f2bf(b.w);
    *(uint4*)(xb + (size_t)i * 8) = r.v;
    return;
  }
  __shared__ float t[32][33];
  int idx = bid - 3072;
  const float* src;
  unsigned short* out;
  int K, N, n_off, ldo;
  if (idx < 576) {               // Wq/Wk/Wv: [768][256], 192 tiles each
    int z = idx / 192;
    idx %= 192;
    src = (z == 0) ? Wq : (z == 1) ? Wk : Wv;
    out = WT; K = 768; N = 256; n_off = z * 256; ldo = 768;
  } else if (idx < 1152) {       // Wg: [768][768], 576 tiles
    idx -= 576;
    src = Wg; out = WT; K = 768; N = 768; n_off = 768; ldo = 768;
  } else {                       // Wo: [256][768], 192 tiles
    idx -= 1152;
    src = Wo; out = WoT; K = 256; N = 768; n_off = 0; ldo = 256;
  }
  int kt = idx % (K / 32), nt = idx / (K / 32);
  int k0 = kt * 32, n0 = nt * 32;
  const int tx = threadIdx.x & 31, ty = threadIdx.x >> 5;
  for (int i = ty; i < 32; i += 8)
    t[i][tx] = src[(size_t)(k0 + i) * N + n0 + tx];
  __syncthreads();
  for (int i = ty; i < 32; i += 8)
    out[(size_t)(n_off + n0 + i) * ldo + k0 + tx] = f2bf(t[tx][i]);
}

// ---------------------------------------------------------------------------
// GEMM1: [QKVG] = x @ [Wq|Wk|Wv|Wg]^T.  M=8192, K=768, N=1536 (B^T input).
// Interleaved pipeline, swizzled tiles, LDS-repack coalesced epilogue.
// ---------------------------------------------------------------------------
__global__ __launch_bounds__(256) void k_gemm1(
    const unsigned short* __restrict__ xb, const unsigned short* __restrict__ WT,
    unsigned short* __restrict__ Q, unsigned short* __restrict__ K,
    unsigned short* __restrict__ V, unsigned short* __restrict__ G) {
  __shared__ __align__(16) char smem[65536];
  short* As0 = (short*)smem;
  short* As1 = (short*)(smem + 16384);
  short* Bs0 = (short*)(smem + 32768);
  short* Bs1 = (short*)(smem + 49152);
  const int tid = threadIdx.x;
  const int w = tid >> 6, l = tid & 63;
  const int lr = l & 15, lg = l >> 4;
  const int wr = w >> 1, wc = w & 1;
  int mt, nt;
  xcd_tile(blockIdx.x, mt, nt);
  const int m0 = mt * 128, n0 = nt * 128;

  Stage st;
  st.init((const short*)xb + (size_t)m0 * DM, DM,
          (const short*)WT + (size_t)n0 * DM, DM, w, l);

  f32x4 acc[4][4];
#pragma unroll
  for (int i = 0; i < 4; ++i)
#pragma unroll
    for (int j = 0; j < 4; ++j) acc[i][j] = (f32x4){0.f, 0.f, 0.f, 0.f};

  kloop<DM / 64>(st, As0, As1, Bs0, Bs1, acc, wr, wc, lr, lg);
  __syncthreads();

  // ---- epilogue: activation + repack through LDS, coalesced 16B stores ----
  const int ttype = (n0 < 512) ? 0 : (n0 < 768) ? 1 : 2;  // eluQK / V / G
  unsigned short* Cs = (unsigned short*)smem;              // 128x128 bf16
#pragma unroll
  for (int mi = 0; mi < 4; ++mi)
#pragma unroll
    for (int ni = 0; ni < 4; ++ni)
#pragma unroll
      for (int r = 0; r < 4; ++r) {
        float v = acc[mi][ni][r];
        if (ttype == 0) v = elu1(v);
        else if (ttype == 2) v = 1.f / (1.f + expf(-v));
        Cs[(wr * 64 + mi * 16 + lg * 4 + r) * 128 + wc * 64 + ni * 16 + lr] =
            f2bf(v);
      }
  __syncthreads();
  unsigned short* dst;
  int ldd, cb;
  if (n0 < 256)      { dst = Q; ldd = DIM; cb = n0; }
  else if (n0 < 512) { dst = K; ldd = DIM; cb = n0 - 256; }
  else if (n0 < 768) { dst = V; ldd = DIM; cb = n0 - 512; }
  else               { dst = G; ldd = DM;  cb = n0 - 768; }
  const uint4* Cv = (const uint4*)Cs;
#pragma unroll
  for (int i = 0; i < 8; ++i) {
    int idx = tid + i * 256;            // 2048 uint4 = 128x128 bf16
    int urow = idx >> 4, uc = idx & 15;
    *(uint4*)(dst + (size_t)(m0 + urow) * ldd + cb + uc * 8) = Cv[idx];
  }
}

// ---------------------------------------------------------------------------
// K2: per-chunk local sums (fp32 vector, bf16 inputs).
// ---------------------------------------------------------------------------
__global__ __launch_bounds__(256) void k_chunksum(
    const unsigned short* __restrict__ K, const unsigned short* __restrict__ V,
    float* __restrict__ Sc, float* __restrict__ zc) {
  __shared__ float Ks[CH][68];
  __shared__ float Vs[CH][68];
  const int c = blockIdx.x, h = blockIdx.y, b = blockIdx.z;
  const int tx = threadIdx.x, ty = threadIdx.y;
  const int tid = ty * 16 + tx;
  const int t0 = c * CH;
#pragma unroll
  for (int l = 0; l < 4; ++l) {
    int idx = tid + l * 256;
    int d4 = idx & 15, t = idx >> 4;
    size_t o = (size_t)(b * Tt + t0 + t) * DIM + h * Dd + d4 * 4;
    short4 k4 = *(const short4*)(K + o);
    short4 v4 = *(const short4*)(V + o);
    Ks[t][d4 * 4 + 0] = bf2f(k4.x); Ks[t][d4 * 4 + 1] = bf2f(k4.y);
    Ks[t][d4 * 4 + 2] = bf2f(k4.z); Ks[t][d4 * 4 + 3] = bf2f(k4.w);
    Vs[t][d4 * 4 + 0] = bf2f(v4.x); Vs[t][d4 * 4 + 1] = bf2f(v4.y);
    Vs[t][d4 * 4 + 2] = bf2f(v4.z); Vs[t][d4 * 4 + 3] = bf2f(v4.w);
  }
  __syncthreads();
  float acc[4][4] = {};
  for (int t = 0; t < CH; ++t) {
    float4 k4 = *(const float4*)&Ks[t][ty * 4];
    float4 v4 = *(const float4*)&Vs[t][tx * 4];
    float kv[4] = {k4.x, k4.y, k4.z, k4.w};
    float vv[4] = {v4.x, v4.y, v4.z, v4.w};
#pragma unroll
    for (int i = 0; i < 4; ++i)
#pragma unroll
      for (int j = 0; j < 4; ++j) acc[i][j] += kv[i] * vv[j];
  }
  const size_t base = ((size_t)(b * Hh + h) * NC + c) * (Dd * Dd);
#pragma unroll
  for (int i = 0; i < 4; ++i) {
    float4 s4 = make_float4(acc[i][0], acc[i][1], acc[i][2], acc[i][3]);
    *(float4*)&Sc[base + (size_t)(ty * 4 + i) * Dd + tx * 4] = s4;
  }
  if (tid < Dd) {
    float s = 0.f;
    for (int t = 0; t < CH; ++t) s += Ks[t][tid];
    zc[((size_t)(b * Hh + h) * NC + c) * Dd + tid] = s;
  }
}

// ---------------------------------------------------------------------------
// K3: exclusive prefix scan over chunks. grid (16 bh, 16 slices) x 256.
// ---------------------------------------------------------------------------
__global__ __launch_bounds__(256) void k_scan(float* __restrict__ Sc,
                                              float* __restrict__ zc) {
  const int bh = blockIdx.x;
  const int o = blockIdx.y * 256 + threadIdx.x;
  const size_t base = (size_t)bh * NC * (Dd * Dd) + o;
  float v[NC];
#pragma unroll
  for (int c = 0; c < NC; ++c) v[c] = Sc[base + (size_t)c * (Dd * Dd)];
  float run = 0.f;
#pragma unroll
  for (int c = 0; c < NC; ++c) {
    Sc[base + (size_t)c * (Dd * Dd)] = run;
    run += v[c];
  }
  if (blockIdx.y == 0 && threadIdx.x < Dd) {
    float rz = 0.f;
    for (int c = 0; c < NC; ++c) {
      size_t oz = ((size_t)bh * NC + c) * Dd + threadIdx.x;
      float cur = zc[oz];
      zc[oz] = rz;
      rz += cur;
    }
  }
}

// ---------------------------------------------------------------------------
// K4: per-chunk output (fp32 vector, bf16 in/out).
// ---------------------------------------------------------------------------
__global__ __launch_bounds__(256) void k_out(
    const unsigned short* __restrict__ Q, const unsigned short* __restrict__ K,
    const unsigned short* __restrict__ V, const float* __restrict__ Sc,
    const float* __restrict__ zc, unsigned short* __restrict__ O) {
  __shared__ float Qs[CH][68];
  __shared__ float KVs[CH * 68];
  __shared__ float As[CH][68];
  __shared__ float Ss[Dd][68];
  __shared__ float zs[Dd];
  __shared__ float dens[CH];
  const int c = blockIdx.x, h = blockIdx.y, b = blockIdx.z;
  const int tx = threadIdx.x, ty = threadIdx.y;
  const int tid = ty * 16 + tx;
  const int t0 = c * CH;

  // load Q [t][d]; K transposed [d][t] (pad 65)
#pragma unroll
  for (int l = 0; l < 4; ++l) {
    int idx = tid + l * 256;
    int d4 = idx & 15, t = idx >> 4;
    size_t o = (size_t)(b * Tt + t0 + t) * DIM + h * Dd + d4 * 4;
    short4 q4 = *(const short4*)(Q + o);
    short4 k4 = *(const short4*)(K + o);
    Qs[t][d4 * 4 + 0] = bf2f(q4.x); Qs[t][d4 * 4 + 1] = bf2f(q4.y);
    Qs[t][d4 * 4 + 2] = bf2f(q4.z); Qs[t][d4 * 4 + 3] = bf2f(q4.w);
    KVs[(d4 * 4 + 0) * 65 + t] = bf2f(k4.x);
    KVs[(d4 * 4 + 1) * 65 + t] = bf2f(k4.y);
    KVs[(d4 * 4 + 2) * 65 + t] = bf2f(k4.z);
    KVs[(d4 * 4 + 3) * 65 + t] = bf2f(k4.w);
  }
  __syncthreads();

  // A[i][j] = sum_d Q[i][d]*K[j][d], masked j<=i
  float acc[4][4] = {};
  for (int d0 = 0; d0 < Dd; d0 += 4) {
    float4 q4[4];
#pragma unroll
    for (int i = 0; i < 4; ++i) q4[i] = *(const float4*)&Qs[ty * 4 + i][d0];
#pragma unroll
    for (int dd = 0; dd < 4; ++dd) {
      int d = d0 + dd;
      float kv[4];
#pragma unroll
      for (int j = 0; j < 4; ++j) kv[j] = KVs[d * 65 + tx * 4 + j];
#pragma unroll
      for (int i = 0; i < 4; ++i) {
        float qv = ((const float*)&q4[i])[dd];
#pragma unroll
        for (int j = 0; j < 4; ++j) acc[i][j] += qv * kv[j];
      }
    }
  }
#pragma unroll
  for (int i = 0; i < 4; ++i)
#pragma unroll
    for (int j = 0; j < 4; ++j) {
      int ti = ty * 4 + i, sj = tx * 4 + j;
      As[ti][sj] = (sj <= ti) ? acc[i][j] : 0.f;
    }
  __syncthreads();

  // V into KVs row-major (pad 68); S_prev, z_prev
#pragma unroll
  for (int l = 0; l < 4; ++l) {
    int idx = tid + l * 256;
    int d4 = idx & 15, t = idx >> 4;
    size_t o = (size_t)(b * Tt + t0 + t) * DIM + h * Dd + d4 * 4;
    short4 v4 = *(const short4*)(V + o);
    KVs[t * 68 + d4 * 4 + 0] = bf2f(v4.x);
    KVs[t * 68 + d4 * 4 + 1] = bf2f(v4.y);
    KVs[t * 68 + d4 * 4 + 2] = bf2f(v4.z);
    KVs[t * 68 + d4 * 4 + 3] = bf2f(v4.w);
  }
  const size_t sbase = ((size_t)(b * Hh + h) * NC + c) * (Dd * Dd);
#pragma unroll
  for (int l = 0; l < 4; ++l) {
    int idx = tid + l * 256;
    int e4 = idx & 15, dd = idx >> 4;
    float4 s4 = *(const float4*)&Sc[sbase + (size_t)dd * Dd + e4 * 4];
    Ss[dd][e4 * 4 + 0] = s4.x; Ss[dd][e4 * 4 + 1] = s4.y;
    Ss[dd][e4 * 4 + 2] = s4.z; Ss[dd][e4 * 4 + 3] = s4.w;
  }
  if (tid < Dd) zs[tid] = zc[((size_t)(b * Hh + h) * NC + c) * Dd + tid];
  __syncthreads();

  if (tid < CH) {
    int i = tid;
    float rs = 0.f;
    for (int j = 0; j < CH; ++j) rs += As[i][j];
    float qz = 0.f;
    for (int d = 0; d < Dd; ++d) qz += Qs[i][d] * zs[d];
    dens[i] = fmaxf(rs + qz, 1e-6f);
  }
  float oacc[4][4] = {};
  for (int j = 0; j < CH; ++j) {
    float4 v4 = *(const float4*)&KVs[j * 68 + tx * 4];
    float vv[4] = {v4.x, v4.y, v4.z, v4.w};
    float av[4];
#pragma unroll
    for (int i = 0; i < 4; ++i) av[i] = As[ty * 4 + i][j];
#pragma unroll
    for (int i = 0; i < 4; ++i)
#pragma unroll
      for (int jj = 0; jj < 4; ++jj) oacc[i][jj] += av[i] * vv[jj];
  }
  for (int d = 0; d < Dd; ++d) {
    float4 s4 = *(const float4*)&Ss[d][tx * 4];
    float sv[4] = {s4.x, s4.y, s4.z, s4.w};
    float qv[4];
#pragma unroll
    for (int i = 0; i < 4; ++i) qv[i] = Qs[ty * 4 + i][d];
#pragma unroll
    for (int i = 0; i < 4; ++i)
#pragma unroll
      for (int jj = 0; jj < 4; ++jj) oacc[i][jj] += qv[i] * sv[jj];
  }
  __syncthreads();
#pragma unroll
  for (int i = 0; i < 4; ++i) {
    float inv = 1.f / dens[ty * 4 + i];
#pragma unroll
    for (int jj = 0; jj < 4; ++jj) {
      O[(size_t)(b * Tt + t0 + ty * 4 + i) * DIM + h * Dd + tx * 4 + jj] =
          f2bf(oacc[i][jj] * inv);
    }
  }
}

// ---------------------------------------------------------------------------
// GEMM2: out = (O @ Wo) * G.  M=8192, K=256, N=768.
// Interleaved pipeline; fp32 LDS-repack epilogue with gate multiply.
// ---------------------------------------------------------------------------
__global__ __launch_bounds__(256) void k_gemm2(
    const unsigned short* __restrict__ Ob, const unsigned short* __restrict__ WoT,
    const unsigned short* __restrict__ G, float* __restrict__ out) {
  __shared__ __align__(16) char smem[65536];
  short* As0 = (short*)smem;
  short* As1 = (short*)(smem + 16384);
  short* Bs0 = (short*)(smem + 32768);
  short* Bs1 = (short*)(smem + 49152);
  const int tid = threadIdx.x;
  const int w = tid >> 6, l = tid & 63;
  const int lr = l & 15, lg = l >> 4;
  const int wr = w >> 1, wc = w & 1;
  int mt, nt;
  xcd_tile(blockIdx.x, mt, nt);
  const int m0 = mt * 128, n0 = nt * 128;

  Stage st;
  st.init((const short*)Ob + (size_t)m0 * DIM, DIM,
          (const short*)WoT + (size_t)n0 * DIM, DIM, w, l);

  f32x4 acc[4][4];
#pragma unroll
  for (int i = 0; i < 4; ++i)
#pragma unroll
    for (int j = 0; j < 4; ++j) acc[i][j] = (f32x4){0.f, 0.f, 0.f, 0.f};

  kloop<DIM / 64>(st, As0, As1, Bs0, Bs1, acc, wr, wc, lr, lg);
  __syncthreads();

  // ---- epilogue: fp32 repack through LDS, gate multiply, 16B stores ----
  float* Cf = (float*)smem;  // 128x128 fp32 = 64KB
#pragma unroll
  for (int mi = 0; mi < 4; ++mi)
#pragma unroll
    for (int ni = 0; ni < 4; ++ni)
#pragma unroll
      for (int r = 0; r < 4; ++r)
        Cf[(wr * 64 + mi * 16 + lg * 4 + r) * 128 + wc * 64 + ni * 16 + lr] =
            acc[mi][ni][r];
  __syncthreads();
  const float4* Cv = (const float4*)Cf;
#pragma unroll
  for (int i = 0; i < 16; ++i) {
    int idx = tid + i * 256;            // 4096 float4 = 128x128 fp32
    int urow = idx >> 5, uc = idx & 31;
    float4 cv = Cv[idx];
    size_t go = (size_t)(m0 + urow) * DM + n0 + uc * 4;
    short4 g4 = *(const short4*)(G + go);
    float4 ov;
    ov.x = cv.x * bf2f(g4.x);
    ov.y = cv.y * bf2f(g4.y);
    ov.z = cv.z * bf2f(g4.z);
    ov.w = cv.w * bf2f(g4.w);
    *(float4*)(out + go) = ov;
  }
}

// ---------------------------------------------------------------------------
extern "C" void kernel_launch(void* const* d_in, const int* in_sizes, int n_in,
                              void* d_out, int out_size, void* d_ws,
                              size_t ws_size, hipStream_t stream) {
  const float* x  = (const float*)d_in[0];
  const float* Wq = (const float*)d_in[1];
  const float* Wk = (const float*)d_in[2];
  const float* Wv = (const float*)d_in[3];
  const float* Wo = (const float*)d_in[4];
  const float* Wg = (const float*)d_in[5];
  float* out = (float*)d_out;

  char* p = (char*)d_ws;
  size_t off = 0;
  auto alloc = [&](size_t bytes) {
    void* r = p + off;
    off = (off + bytes + 255) & ~(size_t)255;
    return r;
  };
  unsigned short* xb  = (unsigned short*)alloc((size_t)BT * DM * 2);
  unsigned short* WT  = (unsigned short*)alloc((size_t)NQKVG * DM * 2);
  unsigned short* WoT = (unsigned short*)alloc((size_t)DM * DIM * 2);
  unsigned short* Q   = (unsigned short*)alloc((size_t)BT * DIM * 2);
  unsigned short* Kf  = (unsigned short*)alloc((size_t)BT * DIM * 2);
  unsigned short* Vf  = (unsigned short*)alloc((size_t)BT * DIM * 2);
  unsigned short* G   = (unsigned short*)alloc((size_t)BT * DM * 2);
  unsigned short* Ob  = (unsigned short*)alloc((size_t)BT * DIM * 2);
  float* Sc = (float*)alloc((size_t)Bb * Hh * NC * Dd * Dd * 4);
  float* zc = (float*)alloc((size_t)Bb * Hh * NC * Dd * 4);

  // 1. fused input cast + weight transposes
  k_prep<<<dim3(3072 + 1344), dim3(256), 0, stream>>>(x, Wq, Wk, Wv, Wg, Wo,
                                                      xb, WT, WoT);

  // 2. fused QKV + gate projection (MFMA), N=1536
  k_gemm1<<<dim3(MT * (NQKVG / 128)), dim3(256), 0, stream>>>(
      xb, WT, Q, Kf, Vf, G);

  // 3. chunked linear attention
  dim3 blk(16, 16);
  k_chunksum<<<dim3(NC, Hh, Bb), blk, 0, stream>>>(Kf, Vf, Sc, zc);
  k_scan<<<dim3(Bb * Hh, Dd * Dd / 256), dim3(256), 0, stream>>>(Sc, zc);
  k_out<<<dim3(NC, Hh, Bb), blk, 0, stream>>>(Q, Kf, Vf, Sc, zc, Ob);

  // 4. output GEMM * gate (MFMA)
  k_gemm2<<<dim3(MT * (DM / 128)), dim3(256), 0, stream>>>(Ob, WoT, G, out);
}

// Round 9
// 86.450 us; speedup vs baseline: 1.3767x; 1.0041x over previous
//
#include <hip/hip_runtime.h>
#include <math.h>

typedef __attribute__((ext_vector_type(8))) short bf16x8;
typedef __attribute__((ext_vector_type(4))) float f32x4;

namespace {
constexpr int Bb  = 4;
constexpr int Tt  = 2048;
constexpr int DM  = 768;
constexpr int Hh  = 4;
constexpr int Dd  = 64;
constexpr int DIM = 256;          // H*D
constexpr int BT  = Bb * Tt;      // 8192
constexpr int CH  = 64;           // chunk length
constexpr int NC  = Tt / CH;      // 32 chunks
constexpr int NQKVG = 1536;       // QKV (768) + gate (768) output cols
constexpr int MT  = BT / 128;     // 64 m-tiles
}

__device__ __forceinline__ float elu1(float x) { return x > 0.f ? x + 1.f : expf(x); }

// fp32 -> bf16, round-to-nearest-even
__device__ __forceinline__ unsigned short f2bf(float f) {
  unsigned int x = __float_as_uint(f);
  unsigned int r = (x + 0x7fffu + ((x >> 16) & 1u)) >> 16;
  return (unsigned short)r;
}
__device__ __forceinline__ float bf2f(unsigned short u) {
  return __uint_as_float((unsigned int)u << 16);
}

__device__ __forceinline__ void gload16(const void* g, void* l) {
  __builtin_amdgcn_global_load_lds(
      (const __attribute__((address_space(1))) void*)g,
      (__attribute__((address_space(3))) void*)l, 16, 0, 0);
}

// BK=32 staging (tile = 128 rows x 32 bf16 = 8KB, 8 segs of 1KB).
// XOR source-swizzle (T2, rule #21): LDS dest linear; the 16B-column a lane
// fetches is permuted c16' = (l&3) ^ ((l>>3)&3)  (row-group g = l>>2, the
// XOR key (g>>1)&3 is uniform within a 4-lane row group).
// Readers XOR their 16B slot with ((row>>1)&3) -> 8 distinct positions per
// 8 rows = free 2-way bank aliasing.
struct Stage32 {
  const short* a[2];
  const short* b[2];
  int seg;  // w*2
  __device__ __forceinline__ void init(const short* Ag, size_t lda,
                                       const short* Bg, size_t ldb, int w, int l) {
    const int c16 = (l & 3) ^ ((l >> 3) & 3);
    seg = w * 2;
#pragma unroll
    for (int j = 0; j < 2; ++j) {
      int row = (seg + j) * 16 + (l >> 2);
      a[j] = Ag + (size_t)row * lda + c16 * 8;
      b[j] = Bg + (size_t)row * ldb + c16 * 8;
    }
  }
  // 4 global_load_lds per lane (counted for vmcnt pipelining)
  __device__ __forceinline__ void issue(int k0, short* as, short* bs) const {
#pragma unroll
    for (int j = 0; j < 2; ++j) {
      gload16(a[j] + k0, (char*)as + (seg + j) * 1024);
      gload16(b[j] + k0, (char*)bs + (seg + j) * 1024);
    }
  }
};

// L2-resident tiling: each XCD (bid&7) owns 8 contiguous m-tiles.
__device__ __forceinline__ void xcd_tile(int bid, int& mt, int& nt) {
  int xcd = bid & 7;
  int idx = bid >> 3;
  mt = xcd * 8 + (idx & 7);
  nt = idx >> 3;
}

// Interleaved counted-vmcnt K-loop, BK=32:
//   vmcnt(4) -> barrier -> 8 frag reads -> lgkm0 -> barrier ->
//   stage-issue t+2 (overlaps) -> setprio(1) 16 MFMA setprio(0)
template <int NT>
__device__ __forceinline__ void kloop32(const Stage32& st, short* As0, short* As1,
                                        short* Bs0, short* Bs1,
                                        f32x4 (&acc)[4][4], int wr, int wc,
                                        int lr, int lg) {
  st.issue(0, As0, Bs0);
  st.issue(32, As1, Bs1);
#pragma unroll
  for (int t = 0; t < NT; ++t) {
    short* as = (t & 1) ? As1 : As0;
    short* bs = (t & 1) ? Bs1 : Bs0;
    if (t + 1 < NT)
      asm volatile("s_waitcnt vmcnt(4)" ::: "memory");
    else
      asm volatile("s_waitcnt vmcnt(0)" ::: "memory");
    __builtin_amdgcn_s_barrier();
    bf16x8 af[4], bf[4];
#pragma unroll
    for (int mi = 0; mi < 4; ++mi) {
      int r = wr * 64 + mi * 16 + lr;
      af[mi] = *(const bf16x8*)&as[r * 32 + (lg ^ ((r >> 1) & 3)) * 8];
    }
#pragma unroll
    for (int ni = 0; ni < 4; ++ni) {
      int r = wc * 64 + ni * 16 + lr;
      bf[ni] = *(const bf16x8*)&bs[r * 32 + (lg ^ ((r >> 1) & 3)) * 8];
    }
    asm volatile("s_waitcnt lgkmcnt(0)" ::: "memory");
    __builtin_amdgcn_sched_barrier(0);
    __builtin_amdgcn_s_barrier();
    if (t + 2 < NT) st.issue((t + 2) * 32, as, bs);  // just-freed buffer
    __builtin_amdgcn_s_setprio(1);
#pragma unroll
    for (int mi = 0; mi < 4; ++mi)
#pragma unroll
      for (int ni = 0; ni < 4; ++ni)
        acc[mi][ni] = __builtin_amdgcn_mfma_f32_16x16x32_bf16(
            af[mi], bf[ni], acc[mi][ni], 0, 0, 0);
    __builtin_amdgcn_s_setprio(0);
  }
}

// ---------------------------------------------------------------------------
// k_prep: fused input cast (blocks [0,3072)) + weight transposes [3072,4416).
// WT rows: [0,256)=Wq^T [256,512)=Wk^T [512,768)=Wv^T [768,1536)=Wg^T, ld=768
// WoT: Wo^T [768][256], ld=256
// ---------------------------------------------------------------------------
__global__ __launch_bounds__(256) void k_prep(
    const float* __restrict__ x, const float* __restrict__ Wq,
    const float* __restrict__ Wk, const float* __restrict__ Wv,
    const float* __restrict__ Wg, const float* __restrict__ Wo,
    unsigned short* __restrict__ xb, unsigned short* __restrict__ WT,
    unsigned short* __restrict__ WoT) {
  int bid = blockIdx.x;
  if (bid < 3072) {  // cast: 8 elements/thread, 786432 total
    int i = bid * 256 + threadIdx.x;
    const float4* p = (const float4*)(x + (size_t)i * 8);
    float4 a = p[0], b = p[1];
    union { unsigned short u[8]; uint4 v; } r;
    r.u[0] = f2bf(a.x); r.u[1] = f2bf(a.y); r.u[2] = f2bf(a.z); r.u[3] = f2bf(a.w);
    r.u[4] = f2bf(b.x); r.u[5] = f2bf(b.y); r.u[6] = f2bf(b.z); r.u[7] = f2bf(b.w);
    *(uint4*)(xb + (size_t)i * 8) = r.v;
    return;
  }
  __shared__ float t[32][33];
  int idx = bid - 3072;
  const float* src;
  unsigned short* out;
  int K, N, n_off, ldo;
  if (idx < 576) {               // Wq/Wk/Wv: [768][256], 192 tiles each
    int z = idx / 192;
    idx %= 192;
    src = (z == 0) ? Wq : (z == 1) ? Wk : Wv;
    out = WT; K = 768; N = 256; n_off = z * 256; ldo = 768;
  } else if (idx < 1152) {       // Wg: [768][768], 576 tiles
    idx -= 576;
    src = Wg; out = WT; K = 768; N = 768; n_off = 768; ldo = 768;
  } else {                       // Wo: [256][768], 192 tiles
    idx -= 1152;
    src = Wo; out = WoT; K = 256; N = 768; n_off = 0; ldo = 256;
  }
  int kt = idx % (K / 32), nt = idx / (K / 32);
  int k0 = kt * 32, n0 = nt * 32;
  const int tx = threadIdx.x & 31, ty = threadIdx.x >> 5;
  for (int i = ty; i < 32; i += 8)
    t[i][tx] = src[(size_t)(k0 + i) * N + n0 + tx];
  __syncthreads();
  for (int i = ty; i < 32; i += 8)
    out[(size_t)(n_off + n0 + i) * ldo + k0 + tx] = f2bf(t[tx][i]);
}

// ---------------------------------------------------------------------------
// GEMM1: [QKVG] = x @ [Wq|Wk|Wv|Wg]^T.  M=8192, K=768, N=1536 (B^T input).
// BK=32, 32KB LDS -> 4 blocks/CU fully-resident grid; counted-vmcnt pipeline.
// ---------------------------------------------------------------------------
__global__ __launch_bounds__(256, 4) void k_gemm1(
    const unsigned short* __restrict__ xb, const unsigned short* __restrict__ WT,
    unsigned short* __restrict__ Q, unsigned short* __restrict__ K,
    unsigned short* __restrict__ V, unsigned short* __restrict__ G) {
  __shared__ __align__(16) char smem[32768];
  short* As0 = (short*)smem;
  short* As1 = (short*)(smem + 8192);
  short* Bs0 = (short*)(smem + 16384);
  short* Bs1 = (short*)(smem + 24576);
  const int tid = threadIdx.x;
  const int w = tid >> 6, l = tid & 63;
  const int lr = l & 15, lg = l >> 4;
  const int wr = w >> 1, wc = w & 1;
  int mt, nt;
  xcd_tile(blockIdx.x, mt, nt);
  const int m0 = mt * 128, n0 = nt * 128;

  Stage32 st;
  st.init((const short*)xb + (size_t)m0 * DM, DM,
          (const short*)WT + (size_t)n0 * DM, DM, w, l);

  f32x4 acc[4][4];
#pragma unroll
  for (int i = 0; i < 4; ++i)
#pragma unroll
    for (int j = 0; j < 4; ++j) acc[i][j] = (f32x4){0.f, 0.f, 0.f, 0.f};

  kloop32<DM / 32>(st, As0, As1, Bs0, Bs1, acc, wr, wc, lr, lg);
  __syncthreads();

  // ---- epilogue: activation + repack through LDS (32KB), 16B stores ----
  const int ttype = (n0 < 512) ? 0 : (n0 < 768) ? 1 : 2;  // eluQK / V / G
  unsigned short* Cs = (unsigned short*)smem;              // 128x128 bf16
#pragma unroll
  for (int mi = 0; mi < 4; ++mi)
#pragma unroll
    for (int ni = 0; ni < 4; ++ni)
#pragma unroll
      for (int r = 0; r < 4; ++r) {
        float v = acc[mi][ni][r];
        if (ttype == 0) v = elu1(v);
        else if (ttype == 2) v = 1.f / (1.f + expf(-v));
        Cs[(wr * 64 + mi * 16 + lg * 4 + r) * 128 + wc * 64 + ni * 16 + lr] =
            f2bf(v);
      }
  __syncthreads();
  unsigned short* dst;
  int ldd, cb;
  if (n0 < 256)      { dst = Q; ldd = DIM; cb = n0; }
  else if (n0 < 512) { dst = K; ldd = DIM; cb = n0 - 256; }
  else if (n0 < 768) { dst = V; ldd = DIM; cb = n0 - 512; }
  else               { dst = G; ldd = DM;  cb = n0 - 768; }
  const uint4* Cv = (const uint4*)Cs;
#pragma unroll
  for (int i = 0; i < 8; ++i) {
    int idx = tid + i * 256;            // 2048 uint4 = 128x128 bf16
    int urow = idx >> 4, uc = idx & 15;
    *(uint4*)(dst + (size_t)(m0 + urow) * ldd + cb + uc * 8) = Cv[idx];
  }
}

// ---------------------------------------------------------------------------
// K2: per-chunk local sums (fp32 vector, bf16 inputs).
// ---------------------------------------------------------------------------
__global__ __launch_bounds__(256) void k_chunksum(
    const unsigned short* __restrict__ K, const unsigned short* __restrict__ V,
    float* __restrict__ Sc, float* __restrict__ zc) {
  __shared__ float Ks[CH][68];
  __shared__ float Vs[CH][68];
  const int c = blockIdx.x, h = blockIdx.y, b = blockIdx.z;
  const int tx = threadIdx.x, ty = threadIdx.y;
  const int tid = ty * 16 + tx;
  const int t0 = c * CH;
#pragma unroll
  for (int l = 0; l < 4; ++l) {
    int idx = tid + l * 256;
    int d4 = idx & 15, t = idx >> 4;
    size_t o = (size_t)(b * Tt + t0 + t) * DIM + h * Dd + d4 * 4;
    short4 k4 = *(const short4*)(K + o);
    short4 v4 = *(const short4*)(V + o);
    Ks[t][d4 * 4 + 0] = bf2f(k4.x); Ks[t][d4 * 4 + 1] = bf2f(k4.y);
    Ks[t][d4 * 4 + 2] = bf2f(k4.z); Ks[t][d4 * 4 + 3] = bf2f(k4.w);
    Vs[t][d4 * 4 + 0] = bf2f(v4.x); Vs[t][d4 * 4 + 1] = bf2f(v4.y);
    Vs[t][d4 * 4 + 2] = bf2f(v4.z); Vs[t][d4 * 4 + 3] = bf2f(v4.w);
  }
  __syncthreads();
  float acc[4][4] = {};
  for (int t = 0; t < CH; ++t) {
    float4 k4 = *(const float4*)&Ks[t][ty * 4];
    float4 v4 = *(const float4*)&Vs[t][tx * 4];
    float kv[4] = {k4.x, k4.y, k4.z, k4.w};
    float vv[4] = {v4.x, v4.y, v4.z, v4.w};
#pragma unroll
    for (int i = 0; i < 4; ++i)
#pragma unroll
      for (int j = 0; j < 4; ++j) acc[i][j] += kv[i] * vv[j];
  }
  const size_t base = ((size_t)(b * Hh + h) * NC + c) * (Dd * Dd);
#pragma unroll
  for (int i = 0; i < 4; ++i) {
    float4 s4 = make_float4(acc[i][0], acc[i][1], acc[i][2], acc[i][3]);
    *(float4*)&Sc[base + (size_t)(ty * 4 + i) * Dd + tx * 4] = s4;
  }
  if (tid < Dd) {
    float s = 0.f;
    for (int t = 0; t < CH; ++t) s += Ks[t][tid];
    zc[((size_t)(b * Hh + h) * NC + c) * Dd + tid] = s;
  }
}

// ---------------------------------------------------------------------------
// K3: exclusive prefix scan over chunks. grid (16 bh, 16 slices) x 256.
// ---------------------------------------------------------------------------
__global__ __launch_bounds__(256) void k_scan(float* __restrict__ Sc,
                                              float* __restrict__ zc) {
  const int bh = blockIdx.x;
  const int o = blockIdx.y * 256 + threadIdx.x;
  const size_t base = (size_t)bh * NC * (Dd * Dd) + o;
  float v[NC];
#pragma unroll
  for (int c = 0; c < NC; ++c) v[c] = Sc[base + (size_t)c * (Dd * Dd)];
  float run = 0.f;
#pragma unroll
  for (int c = 0; c < NC; ++c) {
    Sc[base + (size_t)c * (Dd * Dd)] = run;
    run += v[c];
  }
  if (blockIdx.y == 0 && threadIdx.x < Dd) {
    float rz = 0.f;
    for (int c = 0; c < NC; ++c) {
      size_t oz = ((size_t)bh * NC + c) * Dd + threadIdx.x;
      float cur = zc[oz];
      zc[oz] = rz;
      rz += cur;
    }
  }
}

// ---------------------------------------------------------------------------
// K4: per-chunk output (fp32 vector, bf16 in/out).
// ---------------------------------------------------------------------------
__global__ __launch_bounds__(256) void k_out(
    const unsigned short* __restrict__ Q, const unsigned short* __restrict__ K,
    const unsigned short* __restrict__ V, const float* __restrict__ Sc,
    const float* __restrict__ zc, unsigned short* __restrict__ O) {
  __shared__ float Qs[CH][68];
  __shared__ float KVs[CH * 68];
  __shared__ float As[CH][68];
  __shared__ float Ss[Dd][68];
  __shared__ float zs[Dd];
  __shared__ float dens[CH];
  const int c = blockIdx.x, h = blockIdx.y, b = blockIdx.z;
  const int tx = threadIdx.x, ty = threadIdx.y;
  const int tid = ty * 16 + tx;
  const int t0 = c * CH;

  // load Q [t][d]; K transposed [d][t] (pad 65)
#pragma unroll
  for (int l = 0; l < 4; ++l) {
    int idx = tid + l * 256;
    int d4 = idx & 15, t = idx >> 4;
    size_t o = (size_t)(b * Tt + t0 + t) * DIM + h * Dd + d4 * 4;
    short4 q4 = *(const short4*)(Q + o);
    short4 k4 = *(const short4*)(K + o);
    Qs[t][d4 * 4 + 0] = bf2f(q4.x); Qs[t][d4 * 4 + 1] = bf2f(q4.y);
    Qs[t][d4 * 4 + 2] = bf2f(q4.z); Qs[t][d4 * 4 + 3] = bf2f(q4.w);
    KVs[(d4 * 4 + 0) * 65 + t] = bf2f(k4.x);
    KVs[(d4 * 4 + 1) * 65 + t] = bf2f(k4.y);
    KVs[(d4 * 4 + 2) * 65 + t] = bf2f(k4.z);
    KVs[(d4 * 4 + 3) * 65 + t] = bf2f(k4.w);
  }
  __syncthreads();

  // A[i][j] = sum_d Q[i][d]*K[j][d], masked j<=i
  float acc[4][4] = {};
  for (int d0 = 0; d0 < Dd; d0 += 4) {
    float4 q4[4];
#pragma unroll
    for (int i = 0; i < 4; ++i) q4[i] = *(const float4*)&Qs[ty * 4 + i][d0];
#pragma unroll
    for (int dd = 0; dd < 4; ++dd) {
      int d = d0 + dd;
      float kv[4];
#pragma unroll
      for (int j = 0; j < 4; ++j) kv[j] = KVs[d * 65 + tx * 4 + j];
#pragma unroll
      for (int i = 0; i < 4; ++i) {
        float qv = ((const float*)&q4[i])[dd];
#pragma unroll
        for (int j = 0; j < 4; ++j) acc[i][j] += qv * kv[j];
      }
    }
  }
#pragma unroll
  for (int i = 0; i < 4; ++i)
#pragma unroll
    for (int j = 0; j < 4; ++j) {
      int ti = ty * 4 + i, sj = tx * 4 + j;
      As[ti][sj] = (sj <= ti) ? acc[i][j] : 0.f;
    }
  __syncthreads();

  // V into KVs row-major (pad 68); S_prev, z_prev
#pragma unroll
  for (int l = 0; l < 4; ++l) {
    int idx = tid + l * 256;
    int d4 = idx & 15, t = idx >> 4;
    size_t o = (size_t)(b * Tt + t0 + t) * DIM + h * Dd + d4 * 4;
    short4 v4 = *(const short4*)(V + o);
    KVs[t * 68 + d4 * 4 + 0] = bf2f(v4.x);
    KVs[t * 68 + d4 * 4 + 1] = bf2f(v4.y);
    KVs[t * 68 + d4 * 4 + 2] = bf2f(v4.z);
    KVs[t * 68 + d4 * 4 + 3] = bf2f(v4.w);
  }
  const size_t sbase = ((size_t)(b * Hh + h) * NC + c) * (Dd * Dd);
#pragma unroll
  for (int l = 0; l < 4; ++l) {
    int idx = tid + l * 256;
    int e4 = idx & 15, dd = idx >> 4;
    float4 s4 = *(const float4*)&Sc[sbase + (size_t)dd * Dd + e4 * 4];
    Ss[dd][e4 * 4 + 0] = s4.x; Ss[dd][e4 * 4 + 1] = s4.y;
    Ss[dd][e4 * 4 + 2] = s4.z; Ss[dd][e4 * 4 + 3] = s4.w;
  }
  if (tid < Dd) zs[tid] = zc[((size_t)(b * Hh + h) * NC + c) * Dd + tid];
  __syncthreads();

  if (tid < CH) {
    int i = tid;
    float rs = 0.f;
    for (int j = 0; j < CH; ++j) rs += As[i][j];
    float qz = 0.f;
    for (int d = 0; d < Dd; ++d) qz += Qs[i][d] * zs[d];
    dens[i] = fmaxf(rs + qz, 1e-6f);
  }
  float oacc[4][4] = {};
  for (int j = 0; j < CH; ++j) {
    float4 v4 = *(const float4*)&KVs[j * 68 + tx * 4];
    float vv[4] = {v4.x, v4.y, v4.z, v4.w};
    float av[4];
#pragma unroll
    for (int i = 0; i < 4; ++i) av[i] = As[ty * 4 + i][j];
#pragma unroll
    for (int i = 0; i < 4; ++i)
#pragma unroll
      for (int jj = 0; jj < 4; ++jj) oacc[i][jj] += av[i] * vv[jj];
  }
  for (int d = 0; d < Dd; ++d) {
    float4 s4 = *(const float4*)&Ss[d][tx * 4];
    float sv[4] = {s4.x, s4.y, s4.z, s4.w};
    float qv[4];
#pragma unroll
    for (int i = 0; i < 4; ++i) qv[i] = Qs[ty * 4 + i][d];
#pragma unroll
    for (int i = 0; i < 4; ++i)
#pragma unroll
      for (int jj = 0; jj < 4; ++jj) oacc[i][jj] += qv[i] * sv[jj];
  }
  __syncthreads();
#pragma unroll
  for (int i = 0; i < 4; ++i) {
    float inv = 1.f / dens[ty * 4 + i];
#pragma unroll
    for (int jj = 0; jj < 4; ++jj) {
      O[(size_t)(b * Tt + t0 + ty * 4 + i) * DIM + h * Dd + tx * 4 + jj] =
          f2bf(oacc[i][jj] * inv);
    }
  }
}

// ---------------------------------------------------------------------------
// GEMM2: out = (O @ Wo) * G.  M=8192, K=256, N=768.
// BK=32, 32KB LDS; two-pass fp32 LDS-repack epilogue with gate multiply.
// ---------------------------------------------------------------------------
__global__ __launch_bounds__(256, 4) void k_gemm2(
    const unsigned short* __restrict__ Ob, const unsigned short* __restrict__ WoT,
    const unsigned short* __restrict__ G, float* __restrict__ out) {
  __shared__ __align__(16) char smem[32768];
  short* As0 = (short*)smem;
  short* As1 = (short*)(smem + 8192);
  short* Bs0 = (short*)(smem + 16384);
  short* Bs1 = (short*)(smem + 24576);
  const int tid = threadIdx.x;
  const int w = tid >> 6, l = tid & 63;
  const int lr = l & 15, lg = l >> 4;
  const int wr = w >> 1, wc = w & 1;
  int mt, nt;
  xcd_tile(blockIdx.x, mt, nt);
  const int m0 = mt * 128, n0 = nt * 128;

  Stage32 st;
  st.init((const short*)Ob + (size_t)m0 * DIM, DIM,
          (const short*)WoT + (size_t)n0 * DIM, DIM, w, l);

  f32x4 acc[4][4];
#pragma unroll
  for (int i = 0; i < 4; ++i)
#pragma unroll
    for (int j = 0; j < 4; ++j) acc[i][j] = (f32x4){0.f, 0.f, 0.f, 0.f};

  kloop32<DIM / 32>(st, As0, As1, Bs0, Bs1, acc, wr, wc, lr, lg);

  // ---- epilogue: two-pass fp32 repack (64x128 = 32KB per pass) ----
  float* Cf = (float*)smem;
#pragma unroll
  for (int half = 0; half < 2; ++half) {
    __syncthreads();
    if (wr == half) {
#pragma unroll
      for (int mi = 0; mi < 4; ++mi)
#pragma unroll
        for (int ni = 0; ni < 4; ++ni)
#pragma unroll
          for (int r = 0; r < 4; ++r)
            Cf[(mi * 16 + lg * 4 + r) * 128 + wc * 64 + ni * 16 + lr] =
                acc[mi][ni][r];
    }
    __syncthreads();
    const float4* Cv = (const float4*)Cf;
#pragma unroll
    for (int i = 0; i < 8; ++i) {
      int idx = tid + i * 256;          // 2048 float4 = 64x128 fp32
      int urow = idx >> 5, uc = idx & 31;
      float4 cv = Cv[idx];
      size_t go = (size_t)(m0 + half * 64 + urow) * DM + n0 + uc * 4;
      short4 g4 = *(const short4*)(G + go);
      float4 ov;
      ov.x = cv.x * bf2f(g4.x);
      ov.y = cv.y * bf2f(g4.y);
      ov.z = cv.z * bf2f(g4.z);
      ov.w = cv.w * bf2f(g4.w);
      *(float4*)(out + go) = ov;
    }
  }
}

// ---------------------------------------------------------------------------
extern "C" void kernel_launch(void* const* d_in, const int* in_sizes, int n_in,
                              void* d_out, int out_size, void* d_ws,
                              size_t ws_size, hipStream_t stream) {
  const float* x  = (const float*)d_in[0];
  const float* Wq = (const float*)d_in[1];
  const float* Wk = (const float*)d_in[2];
  const float* Wv = (const float*)d_in[3];
  const float* Wo = (const float*)d_in[4];
  const float* Wg = (const float*)d_in[5];
  float* out = (float*)d_out;

  char* p = (char*)d_ws;
  size_t off = 0;
  auto alloc = [&](size_t bytes) {
    void* r = p + off;
    off = (off + bytes + 255) & ~(size_t)255;
    return r;
  };
  unsigned short* xb  = (unsigned short*)alloc((size_t)BT * DM * 2);
  unsigned short* WT  = (unsigned short*)alloc((size_t)NQKVG * DM * 2);
  unsigned short* WoT = (unsigned short*)alloc((size_t)DM * DIM * 2);
  unsigned short* Q   = (unsigned short*)alloc((size_t)BT * DIM * 2);
  unsigned short* Kf  = (unsigned short*)alloc((size_t)BT * DIM * 2);
  unsigned short* Vf  = (unsigned short*)alloc((size_t)BT * DIM * 2);
  unsigned short* G   = (unsigned short*)alloc((size_t)BT * DM * 2);
  unsigned short* Ob  = (unsigned short*)alloc((size_t)BT * DIM * 2);
  float* Sc = (float*)alloc((size_t)Bb * Hh * NC * Dd * Dd * 4);
  float* zc = (float*)alloc((size_t)Bb * Hh * NC * Dd * 4);

  // 1. fused input cast + weight transposes
  k_prep<<<dim3(3072 + 1344), dim3(256), 0, stream>>>(x, Wq, Wk, Wv, Wg, Wo,
                                                      xb, WT, WoT);

  // 2. fused QKV + gate projection (MFMA), N=1536
  k_gemm1<<<dim3(MT * (NQKVG / 128)), dim3(256), 0, stream>>>(
      xb, WT, Q, Kf, Vf, G);

  // 3. chunked linear attention
  dim3 blk(16, 16);
  k_chunksum<<<dim3(NC, Hh, Bb), blk, 0, stream>>>(Kf, Vf, Sc, zc);
  k_scan<<<dim3(Bb * Hh, Dd * Dd / 256), dim3(256), 0, stream>>>(Sc, zc);
  k_out<<<dim3(NC, Hh, Bb), blk, 0, stream>>>(Q, Kf, Vf, Sc, zc, Ob);

  // 4. output GEMM * gate (MFMA)
  k_gemm2<<<dim3(MT * (DM / 128)), dim3(256), 0, stream>>>(Ob, WoT, G, out);
}

// Round 10
// 76.954 us; speedup vs baseline: 1.5466x; 1.1234x over previous
//
#include <hip/hip_runtime.h>
#include <math.h>

typedef __attribute__((ext_vector_type(8))) short bf16x8;
typedef __attribute__((ext_vector_type(4))) float f32x4;

namespace {
constexpr int Bb  = 4;
constexpr int Tt  = 2048;
constexpr int DM  = 768;
constexpr int Hh  = 4;
constexpr int Dd  = 64;
constexpr int DIM = 256;          // H*D
constexpr int BT  = Bb * Tt;      // 8192
constexpr int CH  = 64;           // chunk length
constexpr int NC  = Tt / CH;      // 32 chunks
constexpr int NQKVG = 1536;       // QKV (768) + gate (768) output cols
constexpr int MT  = BT / 128;     // 64 m-tiles
}

__device__ __forceinline__ float elu1(float x) { return x > 0.f ? x + 1.f : expf(x); }

// fp32 -> bf16, round-to-nearest-even
__device__ __forceinline__ unsigned short f2bf(float f) {
  unsigned int x = __float_as_uint(f);
  unsigned int r = (x + 0x7fffu + ((x >> 16) & 1u)) >> 16;
  return (unsigned short)r;
}
__device__ __forceinline__ float bf2f(unsigned short u) {
  return __uint_as_float((unsigned int)u << 16);
}

__device__ __forceinline__ void gload16(const void* g, void* l) {
  __builtin_amdgcn_global_load_lds(
      (const __attribute__((address_space(1))) void*)g,
      (__attribute__((address_space(3))) void*)l, 16, 0, 0);
}

// ===================== GEMM machinery (unchanged, round 9) =====================
struct Stage32 {
  const short* a[2];
  const short* b[2];
  int seg;
  __device__ __forceinline__ void init(const short* Ag, size_t lda,
                                       const short* Bg, size_t ldb, int w, int l) {
    const int c16 = (l & 3) ^ ((l >> 3) & 3);
    seg = w * 2;
#pragma unroll
    for (int j = 0; j < 2; ++j) {
      int row = (seg + j) * 16 + (l >> 2);
      a[j] = Ag + (size_t)row * lda + c16 * 8;
      b[j] = Bg + (size_t)row * ldb + c16 * 8;
    }
  }
  __device__ __forceinline__ void issue(int k0, short* as, short* bs) const {
#pragma unroll
    for (int j = 0; j < 2; ++j) {
      gload16(a[j] + k0, (char*)as + (seg + j) * 1024);
      gload16(b[j] + k0, (char*)bs + (seg + j) * 1024);
    }
  }
};

__device__ __forceinline__ void xcd_tile(int bid, int& mt, int& nt) {
  int xcd = bid & 7;
  int idx = bid >> 3;
  mt = xcd * 8 + (idx & 7);
  nt = idx >> 3;
}

template <int NT>
__device__ __forceinline__ void kloop32(const Stage32& st, short* As0, short* As1,
                                        short* Bs0, short* Bs1,
                                        f32x4 (&acc)[4][4], int wr, int wc,
                                        int lr, int lg) {
  st.issue(0, As0, Bs0);
  st.issue(32, As1, Bs1);
#pragma unroll
  for (int t = 0; t < NT; ++t) {
    short* as = (t & 1) ? As1 : As0;
    short* bs = (t & 1) ? Bs1 : Bs0;
    if (t + 1 < NT)
      asm volatile("s_waitcnt vmcnt(4)" ::: "memory");
    else
      asm volatile("s_waitcnt vmcnt(0)" ::: "memory");
    __builtin_amdgcn_s_barrier();
    bf16x8 af[4], bf[4];
#pragma unroll
    for (int mi = 0; mi < 4; ++mi) {
      int r = wr * 64 + mi * 16 + lr;
      af[mi] = *(const bf16x8*)&as[r * 32 + (lg ^ ((r >> 1) & 3)) * 8];
    }
#pragma unroll
    for (int ni = 0; ni < 4; ++ni) {
      int r = wc * 64 + ni * 16 + lr;
      bf[ni] = *(const bf16x8*)&bs[r * 32 + (lg ^ ((r >> 1) & 3)) * 8];
    }
    asm volatile("s_waitcnt lgkmcnt(0)" ::: "memory");
    __builtin_amdgcn_sched_barrier(0);
    __builtin_amdgcn_s_barrier();
    if (t + 2 < NT) st.issue((t + 2) * 32, as, bs);
    __builtin_amdgcn_s_setprio(1);
#pragma unroll
    for (int mi = 0; mi < 4; ++mi)
#pragma unroll
      for (int ni = 0; ni < 4; ++ni)
        acc[mi][ni] = __builtin_amdgcn_mfma_f32_16x16x32_bf16(
            af[mi], bf[ni], acc[mi][ni], 0, 0, 0);
    __builtin_amdgcn_s_setprio(0);
  }
}

// ---------------------------------------------------------------------------
// k_prep: fused input cast + weight transposes (unchanged).
// ---------------------------------------------------------------------------
__global__ __launch_bounds__(256) void k_prep(
    const float* __restrict__ x, const float* __restrict__ Wq,
    const float* __restrict__ Wk, const float* __restrict__ Wv,
    const float* __restrict__ Wg, const float* __restrict__ Wo,
    unsigned short* __restrict__ xb, unsigned short* __restrict__ WT,
    unsigned short* __restrict__ WoT) {
  int bid = blockIdx.x;
  if (bid < 3072) {
    int i = bid * 256 + threadIdx.x;
    const float4* p = (const float4*)(x + (size_t)i * 8);
    float4 a = p[0], b = p[1];
    union { unsigned short u[8]; uint4 v; } r;
    r.u[0] = f2bf(a.x); r.u[1] = f2bf(a.y); r.u[2] = f2bf(a.z); r.u[3] = f2bf(a.w);
    r.u[4] = f2bf(b.x); r.u[5] = f2bf(b.y); r.u[6] = f2bf(b.z); r.u[7] = f2bf(b.w);
    *(uint4*)(xb + (size_t)i * 8) = r.v;
    return;
  }
  __shared__ float t[32][33];
  int idx = bid - 3072;
  const float* src;
  unsigned short* out;
  int K, N, n_off, ldo;
  if (idx < 576) {
    int z = idx / 192;
    idx %= 192;
    src = (z == 0) ? Wq : (z == 1) ? Wk : Wv;
    out = WT; K = 768; N = 256; n_off = z * 256; ldo = 768;
  } else if (idx < 1152) {
    idx -= 576;
    src = Wg; out = WT; K = 768; N = 768; n_off = 768; ldo = 768;
  } else {
    idx -= 1152;
    src = Wo; out = WoT; K = 256; N = 768; n_off = 0; ldo = 256;
  }
  int kt = idx % (K / 32), nt = idx / (K / 32);
  int k0 = kt * 32, n0 = nt * 32;
  const int tx = threadIdx.x & 31, ty = threadIdx.x >> 5;
  for (int i = ty; i < 32; i += 8)
    t[i][tx] = src[(size_t)(k0 + i) * N + n0 + tx];
  __syncthreads();
  for (int i = ty; i < 32; i += 8)
    out[(size_t)(n_off + n0 + i) * ldo + k0 + tx] = f2bf(t[tx][i]);
}

// ---------------------------------------------------------------------------
// GEMM1 (unchanged, round 9).
// ---------------------------------------------------------------------------
__global__ __launch_bounds__(256, 4) void k_gemm1(
    const unsigned short* __restrict__ xb, const unsigned short* __restrict__ WT,
    unsigned short* __restrict__ Q, unsigned short* __restrict__ K,
    unsigned short* __restrict__ V, unsigned short* __restrict__ G) {
  __shared__ __align__(16) char smem[32768];
  short* As0 = (short*)smem;
  short* As1 = (short*)(smem + 8192);
  short* Bs0 = (short*)(smem + 16384);
  short* Bs1 = (short*)(smem + 24576);
  const int tid = threadIdx.x;
  const int w = tid >> 6, l = tid & 63;
  const int lr = l & 15, lg = l >> 4;
  const int wr = w >> 1, wc = w & 1;
  int mt, nt;
  xcd_tile(blockIdx.x, mt, nt);
  const int m0 = mt * 128, n0 = nt * 128;

  Stage32 st;
  st.init((const short*)xb + (size_t)m0 * DM, DM,
          (const short*)WT + (size_t)n0 * DM, DM, w, l);

  f32x4 acc[4][4];
#pragma unroll
  for (int i = 0; i < 4; ++i)
#pragma unroll
    for (int j = 0; j < 4; ++j) acc[i][j] = (f32x4){0.f, 0.f, 0.f, 0.f};

  kloop32<DM / 32>(st, As0, As1, Bs0, Bs1, acc, wr, wc, lr, lg);
  __syncthreads();

  const int ttype = (n0 < 512) ? 0 : (n0 < 768) ? 1 : 2;
  unsigned short* Cs = (unsigned short*)smem;
#pragma unroll
  for (int mi = 0; mi < 4; ++mi)
#pragma unroll
    for (int ni = 0; ni < 4; ++ni)
#pragma unroll
      for (int r = 0; r < 4; ++r) {
        float v = acc[mi][ni][r];
        if (ttype == 0) v = elu1(v);
        else if (ttype == 2) v = 1.f / (1.f + expf(-v));
        Cs[(wr * 64 + mi * 16 + lg * 4 + r) * 128 + wc * 64 + ni * 16 + lr] =
            f2bf(v);
      }
  __syncthreads();
  unsigned short* dst;
  int ldd, cb;
  if (n0 < 256)      { dst = Q; ldd = DIM; cb = n0; }
  else if (n0 < 512) { dst = K; ldd = DIM; cb = n0 - 256; }
  else if (n0 < 768) { dst = V; ldd = DIM; cb = n0 - 512; }
  else               { dst = G; ldd = DM;  cb = n0 - 768; }
  const uint4* Cv = (const uint4*)Cs;
#pragma unroll
  for (int i = 0; i < 8; ++i) {
    int idx = tid + i * 256;
    int urow = idx >> 4, uc = idx & 15;
    *(uint4*)(dst + (size_t)(m0 + urow) * ldd + cb + uc * 8) = Cv[idx];
  }
}

// ---------------------------------------------------------------------------
// K2 (MFMA): S_c = K^T V per chunk; z_c = colsum(K). One block per (c,h,b).
// K^T, V^T staged transposed in LDS with XOR swizzle ([64] rows x 128B,
// 16B slot ^= row&7). 4 waves x {1 m-frag x 4 n-frags x 2 kslices} = 8 MFMA.
// ---------------------------------------------------------------------------
__global__ __launch_bounds__(256) void k_chunksum(
    const unsigned short* __restrict__ K, const unsigned short* __restrict__ V,
    float* __restrict__ Sc, float* __restrict__ zc) {
  __shared__ __align__(16) char smem[16384];
  short* Kt = (short*)smem;            // [64 d][64 t] swz
  short* Vt = (short*)(smem + 8192);   // [64 e][64 t] swz
  const int c = blockIdx.x, h = blockIdx.y, b = blockIdx.z;
  const int tid = threadIdx.x;
  const int w = tid >> 6, l = tid & 63;
  const int lr = l & 15, lg = l >> 4;
  const size_t rowbase = ((size_t)(b * Tt + c * CH)) * DIM + h * Dd;

  // reg-stage K,V and write transposed+swizzled
#pragma unroll
  for (int it = 0; it < 4; ++it) {
    int idx = tid + it * 256;
    int t = idx >> 4, d4 = idx & 15;
    short4 k4 = *(const short4*)((const short*)K + rowbase + (size_t)t * DIM + d4 * 4);
    short4 v4 = *(const short4*)((const short*)V + rowbase + (size_t)t * DIM + d4 * 4);
    const short* kk = (const short*)&k4;
    const short* vv = (const short*)&v4;
#pragma unroll
    for (int j = 0; j < 4; ++j) {
      int e = d4 * 4 + j;
      int sl = ((t >> 3) ^ (e & 7)) * 16 + (t & 7) * 2;
      *(short*)((char*)Kt + e * 128 + sl) = kk[j];
      *(short*)((char*)Vt + e * 128 + sl) = vv[j];
    }
  }
  __syncthreads();

  // z_c: d=tid<64 sums K^T row d over t (overlaps other waves' MFMA)
  if (tid < Dd) {
    float s = 0.f;
    for (int t = 0; t < CH; ++t) {
      unsigned short u = *(const unsigned short*)(
          (char*)Kt + tid * 128 + (((t >> 3) ^ (tid & 7)) * 16) + (t & 7) * 2);
      s += bf2f(u);
    }
    zc[((size_t)(b * Hh + h) * NC + c) * Dd + tid] = s;
  }

  f32x4 a[4];
#pragma unroll
  for (int nf = 0; nf < 4; ++nf) a[nf] = (f32x4){0.f, 0.f, 0.f, 0.f};
  const int rd = w * 16 + lr;
#pragma unroll
  for (int ks = 0; ks < 2; ++ks) {
    bf16x8 af = *(const bf16x8*)((char*)Kt + rd * 128 +
                                 (((ks * 4 + lg) ^ (rd & 7)) * 16));
#pragma unroll
    for (int nf = 0; nf < 4; ++nf) {
      int re = nf * 16 + lr;
      bf16x8 bf = *(const bf16x8*)((char*)Vt + re * 128 +
                                   (((ks * 4 + lg) ^ (re & 7)) * 16));
      a[nf] = __builtin_amdgcn_mfma_f32_16x16x32_bf16(af, bf, a[nf], 0, 0, 0);
    }
  }
  __syncthreads();

  // repack fp32 through LDS (16KB), coalesced float4 stores
  float* Cf = (float*)smem;
#pragma unroll
  for (int nf = 0; nf < 4; ++nf)
#pragma unroll
    for (int r = 0; r < 4; ++r)
      Cf[(w * 16 + lg * 4 + r) * 64 + nf * 16 + lr] = a[nf][r];
  __syncthreads();
  const size_t base = ((size_t)(b * Hh + h) * NC + c) * (Dd * Dd);
  const float4* Cv = (const float4*)Cf;
#pragma unroll
  for (int it = 0; it < 4; ++it) {
    int idx = tid + it * 256;   // 1024 float4
    *(float4*)&Sc[base + (size_t)idx * 4] = Cv[idx];
  }
}

// ---------------------------------------------------------------------------
// K3: exclusive prefix scan over chunks (unchanged).
// ---------------------------------------------------------------------------
__global__ __launch_bounds__(256) void k_scan(float* __restrict__ Sc,
                                              float* __restrict__ zc) {
  const int bh = blockIdx.x;
  const int o = blockIdx.y * 256 + threadIdx.x;
  const size_t base = (size_t)bh * NC * (Dd * Dd) + o;
  float v[NC];
#pragma unroll
  for (int c = 0; c < NC; ++c) v[c] = Sc[base + (size_t)c * (Dd * Dd)];
  float run = 0.f;
#pragma unroll
  for (int c = 0; c < NC; ++c) {
    Sc[base + (size_t)c * (Dd * Dd)] = run;
    run += v[c];
  }
  if (blockIdx.y == 0 && threadIdx.x < Dd) {
    float rz = 0.f;
    for (int c = 0; c < NC; ++c) {
      size_t oz = ((size_t)bh * NC + c) * Dd + threadIdx.x;
      float cur = zc[oz];
      zc[oz] = rz;
      rz += cur;
    }
  }
}

// ---------------------------------------------------------------------------
// K4 (MFMA): per-chunk output.
//   A = tril(Q K^T); O = [P|Q] @ [V; S_prev]; den = rowsum(A)+q.z (fp32).
// Q,K staged row-major swizzled via global_load_lds; V^T, S^T reg-staged.
// 4 waves x 16 rows. den via in-register shfl_xor reduce over lr.
// ---------------------------------------------------------------------------
__global__ __launch_bounds__(256) void k_out(
    const unsigned short* __restrict__ Q, const unsigned short* __restrict__ K,
    const unsigned short* __restrict__ V, const float* __restrict__ Sc,
    const float* __restrict__ zc, unsigned short* __restrict__ O) {
  __shared__ __align__(16) char smem[41216];
  short* Qs = (short*)smem;            // [64 t][64 d] swz
  short* Ks = (short*)(smem + 8192);   // [64 s][64 d] swz
  short* Vt = (short*)(smem + 16384);  // [64 e][64 s] swz
  short* St = (short*)(smem + 24576);  // [64 e][64 d] swz
  short* Ps = (short*)(smem + 32768);  // [64 t][64 s] swz; later out staging
  float* zs = (float*)(smem + 40960);
  const int c = blockIdx.x, h = blockIdx.y, b = blockIdx.z;
  const int tid = threadIdx.x;
  const int w = tid >> 6, l = tid & 63;
  const int lr = l & 15, lg = l >> 4;
  const size_t rowbase = ((size_t)(b * Tt + c * CH)) * DIM + h * Dd;

  // --- stage Q,K via global_load_lds (swizzled source columns) ---
  {
    const int c16 = (l & 7) ^ ((l >> 3) & 7);
#pragma unroll
    for (int i = 0; i < 2; ++i) {
      int row = i * 32 + w * 8 + (l >> 3);
      gload16((const short*)Q + rowbase + (size_t)row * DIM + c16 * 8,
              (char*)Qs + (i * 32 + w * 8) * 128);
      gload16((const short*)K + rowbase + (size_t)row * DIM + c16 * 8,
              (char*)Ks + (i * 32 + w * 8) * 128);
    }
  }
  // --- reg-stage V^T (bf16) and S^T (fp32->bf16), z ---
  const size_t sbase = ((size_t)(b * Hh + h) * NC + c) * (Dd * Dd);
  if (tid < Dd) zs[tid] = zc[((size_t)(b * Hh + h) * NC + c) * Dd + tid];
#pragma unroll
  for (int it = 0; it < 4; ++it) {
    int idx = tid + it * 256;
    int t = idx >> 4, d4 = idx & 15;
    short4 v4 = *(const short4*)((const short*)V + rowbase + (size_t)t * DIM + d4 * 4);
    const short* vv = (const short*)&v4;
#pragma unroll
    for (int j = 0; j < 4; ++j) {
      int e = d4 * 4 + j;
      *(short*)((char*)Vt + e * 128 + (((t >> 3) ^ (e & 7)) * 16) + (t & 7) * 2) = vv[j];
    }
    float4 s4 = *(const float4*)&Sc[sbase + (size_t)t * 64 + d4 * 4];
    const float* sv = (const float*)&s4;
#pragma unroll
    for (int j = 0; j < 4; ++j) {
      int e = d4 * 4 + j;  // t here is the d index of S
      *(short*)((char*)St + e * 128 + (((t >> 3) ^ (e & 7)) * 16) + (t & 7) * 2) =
          (short)f2bf(sv[j]);
    }
  }
  __syncthreads();

  // --- QK^T (MFMA): wave w owns rows w*16..+15 ---
  f32x4 a0[4];
#pragma unroll
  for (int nf = 0; nf < 4; ++nf) a0[nf] = (f32x4){0.f, 0.f, 0.f, 0.f};
  const int rq = w * 16 + lr;
#pragma unroll
  for (int ks = 0; ks < 2; ++ks) {
    bf16x8 af = *(const bf16x8*)((char*)Qs + rq * 128 +
                                 (((ks * 4 + lg) ^ (rq & 7)) * 16));
#pragma unroll
    for (int nf = 0; nf < 4; ++nf) {
      int rk = nf * 16 + lr;
      bf16x8 bf = *(const bf16x8*)((char*)Ks + rk * 128 +
                                   (((ks * 4 + lg) ^ (rk & 7)) * 16));
      a0[nf] = __builtin_amdgcn_mfma_f32_16x16x32_bf16(af, bf, a0[nf], 0, 0, 0);
    }
  }

  // --- mask + P(bf16) write + den partials (fp32) ---
  float part[4] = {0.f, 0.f, 0.f, 0.f};
#pragma unroll
  for (int nf = 0; nf < 4; ++nf) {
    int col = nf * 16 + lr;
#pragma unroll
    for (int r = 0; r < 4; ++r) {
      int row = w * 16 + lg * 4 + r;
      float av = (col <= row) ? a0[nf][r] : 0.f;
      part[r] += av;
      *(short*)((char*)Ps + row * 128 +
                ((((nf * 2) + (lr >> 3)) ^ (row & 7)) * 16) + (lr & 7) * 2) =
          (short)f2bf(av);
    }
  }
  // qz partials: lane covers d = lr, lr+16, lr+32, lr+48
#pragma unroll
  for (int r = 0; r < 4; ++r) {
    int row = w * 16 + lg * 4 + r;
#pragma unroll
    for (int j = 0; j < 4; ++j) {
      int d = lr + j * 16;
      unsigned short qu = *(const unsigned short*)(
          (char*)Qs + row * 128 + (((d >> 3) ^ (row & 7)) * 16) + (d & 7) * 2);
      part[r] += bf2f(qu) * zs[d];
    }
  }
  float inv[4];
#pragma unroll
  for (int r = 0; r < 4; ++r) {
    float s = part[r];
    s += __shfl_xor(s, 1);
    s += __shfl_xor(s, 2);
    s += __shfl_xor(s, 4);
    s += __shfl_xor(s, 8);
    inv[r] = 1.f / fmaxf(s, 1e-6f);
  }
  __syncthreads();

  // --- [P|Q] @ [V; S_prev] (K=128, MFMA) ---
  f32x4 a1[4];
#pragma unroll
  for (int nf = 0; nf < 4; ++nf) a1[nf] = (f32x4){0.f, 0.f, 0.f, 0.f};
#pragma unroll
  for (int ks = 0; ks < 4; ++ks) {
    const char* abase = (ks < 2) ? (const char*)Ps : (const char*)Qs;
    const char* bbase = (ks < 2) ? (const char*)Vt : (const char*)St;
    int kslot = (ks & 1) * 4 + lg;
    bf16x8 af = *(const bf16x8*)(abase + rq * 128 + ((kslot ^ (rq & 7)) * 16));
#pragma unroll
    for (int nf = 0; nf < 4; ++nf) {
      int re = nf * 16 + lr;
      bf16x8 bf = *(const bf16x8*)(bbase + re * 128 + ((kslot ^ (re & 7)) * 16));
      a1[nf] = __builtin_amdgcn_mfma_f32_16x16x32_bf16(af, bf, a1[nf], 0, 0, 0);
    }
  }
  __syncthreads();

  // --- epilogue: scale by inv, repack through Ps (linear), 16B stores ---
#pragma unroll
  for (int nf = 0; nf < 4; ++nf)
#pragma unroll
    for (int r = 0; r < 4; ++r) {
      int row = w * 16 + lg * 4 + r;
      Ps[row * 64 + nf * 16 + lr] = (short)f2bf(a1[nf][r] * inv[r]);
    }
  __syncthreads();
  const uint4* Pv = (const uint4*)Ps;
#pragma unroll
  for (int i = 0; i < 2; ++i) {
    int idx = tid + i * 256;  // 512 uint4 = 64x64 bf16
    int row = idx >> 3, uc = idx & 7;
    *(uint4*)((unsigned short*)O + rowbase + (size_t)row * DIM + uc * 8) = Pv[idx];
  }
}

// ---------------------------------------------------------------------------
// GEMM2 (unchanged, round 9).
// ---------------------------------------------------------------------------
__global__ __launch_bounds__(256, 4) void k_gemm2(
    const unsigned short* __restrict__ Ob, const unsigned short* __restrict__ WoT,
    const unsigned short* __restrict__ G, float* __restrict__ out) {
  __shared__ __align__(16) char smem[32768];
  short* As0 = (short*)smem;
  short* As1 = (short*)(smem + 8192);
  short* Bs0 = (short*)(smem + 16384);
  short* Bs1 = (short*)(smem + 24576);
  const int tid = threadIdx.x;
  const int w = tid >> 6, l = tid & 63;
  const int lr = l & 15, lg = l >> 4;
  const int wr = w >> 1, wc = w & 1;
  int mt, nt;
  xcd_tile(blockIdx.x, mt, nt);
  const int m0 = mt * 128, n0 = nt * 128;

  Stage32 st;
  st.init((const short*)Ob + (size_t)m0 * DIM, DIM,
          (const short*)WoT + (size_t)n0 * DIM, DIM, w, l);

  f32x4 acc[4][4];
#pragma unroll
  for (int i = 0; i < 4; ++i)
#pragma unroll
    for (int j = 0; j < 4; ++j) acc[i][j] = (f32x4){0.f, 0.f, 0.f, 0.f};

  kloop32<DIM / 32>(st, As0, As1, Bs0, Bs1, acc, wr, wc, lr, lg);

  float* Cf = (float*)smem;
#pragma unroll
  for (int half = 0; half < 2; ++half) {
    __syncthreads();
    if (wr == half) {
#pragma unroll
      for (int mi = 0; mi < 4; ++mi)
#pragma unroll
        for (int ni = 0; ni < 4; ++ni)
#pragma unroll
          for (int r = 0; r < 4; ++r)
            Cf[(mi * 16 + lg * 4 + r) * 128 + wc * 64 + ni * 16 + lr] =
                acc[mi][ni][r];
    }
    __syncthreads();
    const float4* Cv = (const float4*)Cf;
#pragma unroll
    for (int i = 0; i < 8; ++i) {
      int idx = tid + i * 256;
      int urow = idx >> 5, uc = idx & 31;
      float4 cv = Cv[idx];
      size_t go = (size_t)(m0 + half * 64 + urow) * DM + n0 + uc * 4;
      short4 g4 = *(const short4*)(G + go);
      float4 ov;
      ov.x = cv.x * bf2f(g4.x);
      ov.y = cv.y * bf2f(g4.y);
      ov.z = cv.z * bf2f(g4.z);
      ov.w = cv.w * bf2f(g4.w);
      *(float4*)(out + go) = ov;
    }
  }
}

// ---------------------------------------------------------------------------
extern "C" void kernel_launch(void* const* d_in, const int* in_sizes, int n_in,
                              void* d_out, int out_size, void* d_ws,
                              size_t ws_size, hipStream_t stream) {
  const float* x  = (const float*)d_in[0];
  const float* Wq = (const float*)d_in[1];
  const float* Wk = (const float*)d_in[2];
  const float* Wv = (const float*)d_in[3];
  const float* Wo = (const float*)d_in[4];
  const float* Wg = (const float*)d_in[5];
  float* out = (float*)d_out;

  char* p = (char*)d_ws;
  size_t off = 0;
  auto alloc = [&](size_t bytes) {
    void* r = p + off;
    off = (off + bytes + 255) & ~(size_t)255;
    return r;
  };
  unsigned short* xb  = (unsigned short*)alloc((size_t)BT * DM * 2);
  unsigned short* WT  = (unsigned short*)alloc((size_t)NQKVG * DM * 2);
  unsigned short* WoT = (unsigned short*)alloc((size_t)DM * DIM * 2);
  unsigned short* Q   = (unsigned short*)alloc((size_t)BT * DIM * 2);
  unsigned short* Kf  = (unsigned short*)alloc((size_t)BT * DIM * 2);
  unsigned short* Vf  = (unsigned short*)alloc((size_t)BT * DIM * 2);
  unsigned short* G   = (unsigned short*)alloc((size_t)BT * DM * 2);
  unsigned short* Ob  = (unsigned short*)alloc((size_t)BT * DIM * 2);
  float* Sc = (float*)alloc((size_t)Bb * Hh * NC * Dd * Dd * 4);
  float* zc = (float*)alloc((size_t)Bb * Hh * NC * Dd * 4);

  // 1. fused input cast + weight transposes
  k_prep<<<dim3(3072 + 1344), dim3(256), 0, stream>>>(x, Wq, Wk, Wv, Wg, Wo,
                                                      xb, WT, WoT);

  // 2. fused QKV + gate projection (MFMA), N=1536
  k_gemm1<<<dim3(MT * (NQKVG / 128)), dim3(256), 0, stream>>>(
      xb, WT, Q, Kf, Vf, G);

  // 3. chunked linear attention (MFMA middle kernels)
  k_chunksum<<<dim3(NC, Hh, Bb), dim3(256), 0, stream>>>(Kf, Vf, Sc, zc);
  k_scan<<<dim3(Bb * Hh, Dd * Dd / 256), dim3(256), 0, stream>>>(Sc, zc);
  k_out<<<dim3(NC, Hh, Bb), dim3(256), 0, stream>>>(Q, Kf, Vf, Sc, zc, Ob);

  // 4. output GEMM * gate (MFMA)
  k_gemm2<<<dim3(MT * (DM / 128)), dim3(256), 0, stream>>>(Ob, WoT, G, out);
}